// Round 4
// baseline (581.357 us; speedup 1.0000x reference)
//
#include <hip/hip_runtime.h>
#include <math.h>

#define N_ENT 100000
#define N_USR 50000
#define N_EDGE 1000000
#define TEMPC 0.2f
#define KG_BLOCKS (N_ENT / 4)   // 25000, exact
#define UI_BLOCKS (N_USR / 4)   // 12500, exact

// fused-kernel block ranges
#define TB_BLOCKS 6250   // ceil(N_ENT*64/4 / 256) : bf16 convert (float4 granules)
#define CNT_BLOCKS 1954  // ceil(N_EDGE/2 / 256) : count, 2 edges/thread (latency-bound: max parallelism)
#define SC_BLOCKS 196    // ceil(N_USR / 256)
#define BUILD_BLOCKS 1954 // ceil(N_EDGE/2 / 256) : build, 2 edges/thread
#define REL2_BLOCKS 391  // ceil(N_ENT / 256)

#define WLS 68   // padded stride for weight rows in LDS

typedef unsigned short ushort_t;

__device__ __forceinline__ float waveReduceSum(float x) {
#pragma unroll
  for (int d = 32; d > 0; d >>= 1) x += __shfl_xor(x, d);
  return x;
}
__device__ __forceinline__ float waveReduceMax(float x) {
#pragma unroll
  for (int d = 32; d > 0; d >>= 1) x = fmaxf(x, __shfl_xor(x, d));
  return x;
}
__device__ __forceinline__ int waveReduceSumI(int x) {
#pragma unroll
  for (int d = 32; d > 0; d >>= 1) x += __shfl_xor(x, d);
  return x;
}
__device__ __forceinline__ float bf2f(unsigned int u16) {
  union { unsigned int i; float f; } v;
  v.i = u16 << 16;
  return v.f;
}
__device__ __forceinline__ ushort_t f2bf(float f) {
  union { unsigned int i; float f; } v;
  v.f = f;
  unsigned int u = v.i;
  u = (u + 0x7FFFu + ((u >> 16) & 1u)) >> 16;
  return (ushort_t)u;
}
// wave-uniform broadcast via v_readlane -> SGPR (cheap scalar addressing downstream)
__device__ __forceinline__ int rl(int v, int l) { return __builtin_amdgcn_readlane(v, l); }
__device__ __forceinline__ float rlf(float v, int l) {
  return __int_as_float(__builtin_amdgcn_readlane(__float_as_int(v), l));
}

// column-partial reduce over g (masks 8/16/32) + 8x8 wave transpose:
// on entry lane holds partials for columns part*8+k; on exit lane l holds colsum[l].
__device__ __forceinline__ float colRT(float a0, float a1, float a2, float a3,
                                       float a4, float a5, float a6, float a7,
                                       int g, int part) {
#define RED3(x) x += __shfl_xor(x, 8); x += __shfl_xor(x, 16); x += __shfl_xor(x, 32);
  RED3(a0) RED3(a1) RED3(a2) RED3(a3) RED3(a4) RED3(a5) RED3(a6) RED3(a7)
#undef RED3
  float t0 = __shfl(a0, g), t1 = __shfl(a1, g), t2 = __shfl(a2, g), t3 = __shfl(a3, g);
  float t4 = __shfl(a4, g), t5 = __shfl(a5, g), t6 = __shfl(a6, g), t7 = __shfl(a7, g);
  float r = t0;
  r = (part == 1) ? t1 : r;
  r = (part == 2) ? t2 : r;
  r = (part == 3) ? t3 : r;
  r = (part == 4) ? t4 : r;
  r = (part == 5) ? t5 : r;
  r = (part == 6) ? t6 : r;
  r = (part == 7) ? t7 : r;
  return r;
}

// ============ K1: bf16 convert | edge count (2/thr) | prep | sc(user) ============
__global__ void k_pre(const float* __restrict__ ent0, ushort_t* __restrict__ ent0bf,
                      const int* __restrict__ head, const int* __restrict__ uir,
                      const int* __restrict__ etype,
                      int* __restrict__ cnt_u, int* __restrict__ cnt9,
                      const float* __restrict__ weight, const float* __restrict__ kgW,
                      const float* __restrict__ disen,
                      float* __restrict__ V, float* __restrict__ wsq,
                      float* __restrict__ dw, float* __restrict__ cor_out,
                      const float* __restrict__ user_emb, const float* __restrict__ latent,
                      float4* __restrict__ sc4a) {
  int bid = blockIdx.x;
  if (bid < TB_BLOCKS) {
    int i = bid * 256 + threadIdx.x;
    if (i < N_ENT * 16) {
      float4 v = ((const float4*)ent0)[i];
      ushort4 o;
      o.x = f2bf(v.x); o.y = f2bf(v.y); o.z = f2bf(v.z); o.w = f2bf(v.w);
      ((ushort4*)ent0bf)[i] = o;
    }
  } else if (bid < TB_BLOCKS + CNT_BLOCKS) {
    int i0 = ((bid - TB_BLOCKS) * 256 + threadIdx.x) * 2;
    if (i0 < N_EDGE) {
      int2 h = *(const int2*)(head + i0);
      int2 et = *(const int2*)(etype + i0);
      int2 u = *(const int2*)(uir + i0);
      atomicAdd(&cnt9[h.x * 9 + (et.x - 1)], 1);
      atomicAdd(&cnt9[h.y * 9 + (et.y - 1)], 1);
      atomicAdd(&cnt_u[u.x], 1);
      atomicAdd(&cnt_u[u.y], 1);
    }
  } else if (bid == TB_BLOCKS + CNT_BLOCKS) {
    // ---- prep: V=(W W^T)w_r via T-factorization, wsq, dw, cor ----
    __shared__ float T[9 * 64];
    __shared__ float sm[4 * 9];
    int tid = threadIdx.x;
    for (int e = tid; e < 9 * 64; e += 256) {
      int r = e >> 6, d = e & 63;
      float s = 0.f;
      for (int k = 0; k < 64; ++k) s += kgW[k * 64 + d] * weight[r * 64 + k];
      T[e] = s;
    }
    if (tid < 4) {
      float m = -INFINITY;
      for (int r = 0; r < 9; ++r) m = fmaxf(m, disen[tid * 9 + r]);
      float den = 0.f;
      float ex[9];
      for (int r = 0; r < 9; ++r) { ex[r] = expf(disen[tid * 9 + r] - m); den += ex[r]; }
      for (int r = 0; r < 9; ++r) sm[tid * 9 + r] = ex[r] / den;
    }
    __syncthreads();
    for (int e = tid; e < 9 * 64; e += 256) {
      int r = e >> 6, i = e & 63;
      float s = 0.f;
      for (int d = 0; d < 64; ++d) s += kgW[i * 64 + d] * T[r * 64 + d];
      V[e] = s;
    }
    if (tid < 9) {
      float s = 0.f;
      for (int c = 0; c < 64; ++c) { float w = weight[tid * 64 + c]; s += w * w; }
      wsq[tid] = s;
    }
    for (int e = tid; e < 4 * 64; e += 256) {
      int f = e >> 6, c = e & 63;
      float s = 0.f;
      for (int r = 0; r < 9; ++r) s += sm[f * 9 + r] * weight[r * 64 + c];
      dw[e] = s;
    }
    if (tid == 0) {
      float rowsum[4];
      for (int f = 0; f < 4; ++f) {
        float s = 0.f;
        for (int j = 0; j < 9; ++j) s += disen[f * 9 + j];
        rowsum[f] = s;
      }
      float cor = 0.f;
      for (int i = 0; i < 9; ++i) {
        float n2 = 0.f, ttl = 0.f;
        for (int f = 0; f < 4; ++f) {
          float v = disen[f * 9 + i];
          n2 += v * v;
          ttl += v * rowsum[f];
        }
        float nrm = sqrtf(n2);
        float pos = 0.f;
        for (int f = 0; f < 4; ++f) {
          float v = disen[f * 9 + i] / nrm;
          pos += v * v;
        }
        cor += (ttl - pos) / TEMPC;
      }
      *cor_out = cor;
    }
  } else {
    // ---- sc on user_emb -> sc4a ----
    __shared__ __align__(16) float lat[256];
    if (threadIdx.x < 256) lat[threadIdx.x] = latent[threadIdx.x];
    __syncthreads();
    int u = (bid - TB_BLOCKS - CNT_BLOCKS - 1) * 256 + threadIdx.x;
    if (u >= N_USR) return;
    float a0 = 0.f, a1 = 0.f, a2 = 0.f, a3 = 0.f;
    const float4* row = (const float4*)(user_emb + (size_t)u * 64);
#pragma unroll
    for (int q = 0; q < 16; ++q) {
      float4 v = row[q];
      float4 l0 = *(const float4*)(lat + 0 * 64 + q * 4);
      float4 l1 = *(const float4*)(lat + 1 * 64 + q * 4);
      float4 l2 = *(const float4*)(lat + 2 * 64 + q * 4);
      float4 l3 = *(const float4*)(lat + 3 * 64 + q * 4);
      a0 = fmaf(v.x, l0.x, a0); a0 = fmaf(v.y, l0.y, a0); a0 = fmaf(v.z, l0.z, a0); a0 = fmaf(v.w, l0.w, a0);
      a1 = fmaf(v.x, l1.x, a1); a1 = fmaf(v.y, l1.y, a1); a1 = fmaf(v.z, l1.z, a1); a1 = fmaf(v.w, l1.w, a1);
      a2 = fmaf(v.x, l2.x, a2); a2 = fmaf(v.y, l2.y, a2); a2 = fmaf(v.z, l2.z, a2); a2 = fmaf(v.w, l2.w, a2);
      a3 = fmaf(v.x, l3.x, a3); a3 = fmaf(v.y, l3.y, a3); a3 = fmaf(v.z, l3.z, a3); a3 = fmaf(v.w, l3.w, a3);
    }
    sc4a[u] = make_float4(a0, a1, a2, a3);
  }
}

// ============ K2: fused scan-reduce (head from cnt9 rowsums | ui) ============
__global__ void k_scanred(const int* __restrict__ cnt9, const int* __restrict__ cnt_u,
                          int* __restrict__ bsum_h, int* __restrict__ bsum_u, int nbh) {
  int b = blockIdx.x, tid = threadIdx.x;
  int s = 0;
  if (b < nbh) {
    int i0 = b * 1024 + tid * 4;
#pragma unroll
    for (int k = 0; k < 4; ++k)
      if (i0 + k < N_ENT) {
        int base = (i0 + k) * 9;
#pragma unroll
        for (int r = 0; r < 9; ++r) s += cnt9[base + r];
      }
  } else {
    int i0 = (b - nbh) * 1024 + tid * 4;
#pragma unroll
    for (int k = 0; k < 4; ++k)
      if (i0 + k < N_USR) s += cnt_u[i0 + k];
  }
  s = waveReduceSumI(s);
  __shared__ int l[4];
  int lane = tid & 63, wid = tid >> 6;
  if (lane == 0) l[wid] = s;
  __syncthreads();
  if (tid == 0) {
    int v = l[0] + l[1] + l[2] + l[3];
    if (b < nbh) bsum_h[b] = v; else bsum_u[b - nbh] = v;
  }
}

__global__ void k_scan_tops(int* bsA, int nA, int* bsB, int nB,
                            int* ptrA, int NA, int* ptrB, int NB, int total) {
  if (threadIdx.x == 0) {
    int a = 0;
    for (int i = 0; i < nA; ++i) { int t = bsA[i]; bsA[i] = a; a += t; }
    ptrA[NA] = total;
  }
  if (threadIdx.x == 1) {
    int a = 0;
    for (int i = 0; i < nB; ++i) { int t = bsB[i]; bsB[i] = a; a += t; }
    ptrB[NB] = total;
  }
}

// ============ K4: fused scan-final (head from cnt9 | ui) ============
__global__ void k_scanfin(const int* __restrict__ cnt9, const int* __restrict__ bsum_h,
                          const int* __restrict__ bsum_u,
                          int* __restrict__ head_ptr, int* __restrict__ head_cur,
                          int* __restrict__ ui_ptr, int* __restrict__ ui_cur, int nbh) {
  int b = blockIdx.x, tid = threadIdx.x;
  bool isH = (b < nbh);
  int bl = isH ? b : b - nbh;
  int n = isH ? N_ENT : N_USR;
  int i0 = bl * 1024 + tid * 4;
  int c[4];
  int s = 0;
  int loc[4];
#pragma unroll
  for (int k = 0; k < 4; ++k) {
    int v = 0;
    if (i0 + k < n) {
      if (isH) {
        int base = (i0 + k) * 9;
#pragma unroll
        for (int r = 0; r < 9; ++r) v += cnt9[base + r];
      } else {
        v = ui_cur[i0 + k];
      }
    }
    c[k] = v;
    loc[k] = s;
    s += v;
  }
  int lane = tid & 63, wid = tid >> 6;
  int x = s;
#pragma unroll
  for (int d = 1; d < 64; d <<= 1) {
    int y = __shfl_up(x, d);
    if (lane >= d) x += y;
  }
  __shared__ int l[4];
  if (lane == 63) l[wid] = x;
  __syncthreads();
  if (tid == 0) {
    int a = 0;
    for (int w = 0; w < 4; ++w) { int t = l[w]; l[w] = a; a += t; }
  }
  __syncthreads();
  int excl = x - s + l[wid] + (isH ? bsum_h[bl] : bsum_u[bl]);
#pragma unroll
  for (int k = 0; k < 4; ++k) {
    if (i0 + k < n) {
      int v = excl + loc[k];
      if (isH) {
        head_ptr[i0 + k] = v;
        head_cur[i0 + k] = v;
      } else {
        ui_ptr[i0 + k] = v;
        ui_cur[i0 + k] = v;
      }
    }
  }
}

// ============ K5: build (2/thr) | rel2 ============
__global__ void k_build_rel2(const int* __restrict__ head, const int* __restrict__ tail,
                             const int* __restrict__ etype,
                             const int* __restrict__ uir, const int* __restrict__ uic,
                             const float* __restrict__ uival,
                             int* __restrict__ cur_h, int* __restrict__ cur_u,
                             int* __restrict__ packed, int2* __restrict__ cv,
                             const ushort_t* __restrict__ ent0bf, const float* __restrict__ V,
                             const float* __restrict__ wsq, const int* __restrict__ cnt9,
                             float* __restrict__ rel2t) {
  if (blockIdx.x < BUILD_BLOCKS) {
    int i0 = (blockIdx.x * 256 + threadIdx.x) * 2;
    if (i0 >= N_EDGE) return;
    int2 h = *(const int2*)(head + i0);
    int2 t = *(const int2*)(tail + i0);
    int2 et = *(const int2*)(etype + i0);
    int2 ur = *(const int2*)(uir + i0);
    int2 uc = *(const int2*)(uic + i0);
    float2 uv = *(const float2*)(uival + i0);
    int p0 = atomicAdd(&cur_h[h.x], 1);
    int p1 = atomicAdd(&cur_h[h.y], 1);
    int q0 = atomicAdd(&cur_u[ur.x], 1);
    int q1 = atomicAdd(&cur_u[ur.y], 1);
    packed[p0] = (t.x & 0xFFFFF) | ((et.x - 1) << 20);
    packed[p1] = (t.y & 0xFFFFF) | ((et.y - 1) << 20);
    cv[q0] = make_int2(uc.x, __float_as_int(uv.x));
    cv[q1] = make_int2(uc.y, __float_as_int(uv.y));
  } else {
    // ---- rel2: dense per-entity relation softmax table ----
    __shared__ __align__(16) float Vl[576];
    __shared__ float wsql[9];
    for (int i = threadIdx.x; i < 576; i += 256) Vl[i] = V[i];
    if (threadIdx.x < 9) wsql[threadIdx.x] = wsq[threadIdx.x];
    __syncthreads();
    int ent = (blockIdx.x - BUILD_BLOCKS) * 256 + threadIdx.x;
    if (ent >= N_ENT) return;
    float a[9] = {0, 0, 0, 0, 0, 0, 0, 0, 0};
    const uint4* row = (const uint4*)(ent0bf + (ent << 6));
#pragma unroll
    for (int q = 0; q < 8; ++q) {
      uint4 b = row[q];
      float ch0 = bf2f(b.x & 0xFFFFu), ch1 = bf2f(b.x >> 16);
      float ch2 = bf2f(b.y & 0xFFFFu), ch3 = bf2f(b.y >> 16);
      float ch4 = bf2f(b.z & 0xFFFFu), ch5 = bf2f(b.z >> 16);
      float ch6 = bf2f(b.w & 0xFFFFu), ch7 = bf2f(b.w >> 16);
#pragma unroll
      for (int r = 0; r < 9; ++r) {
        const float4* vp = (const float4*)(Vl + r * 64 + q * 8);
        float4 v0 = vp[0], v1 = vp[1];
        float t = a[r];
        t = fmaf(ch0, v0.x, t); t = fmaf(ch1, v0.y, t);
        t = fmaf(ch2, v0.z, t); t = fmaf(ch3, v0.w, t);
        t = fmaf(ch4, v1.x, t); t = fmaf(ch5, v1.y, t);
        t = fmaf(ch6, v1.z, t); t = fmaf(ch7, v1.w, t);
        a[r] = t;
      }
    }
    const float inv2s = 0.08838834764831845f;  // 1/(2*sqrt(32))
    int cnt[9];
#pragma unroll
    for (int r = 0; r < 9; ++r) cnt[r] = cnt9[ent * 9 + r];
    float m1 = -INFINITY;
#pragma unroll
    for (int r = 0; r < 9; ++r)
      if (cnt[r] > 0) m1 = fmaxf(m1, a[r] * inv2s);
    if (m1 == -INFINITY) {
#pragma unroll
      for (int r = 0; r < 9; ++r) rel2t[ent * 9 + r] = 0.f;
      return;
    }
    float den1 = 1e-16f;
#pragma unroll
    for (int r = 0; r < 9; ++r)
      if (cnt[r] > 0) den1 += (float)cnt[r] * expf(a[r] * inv2s - m1);
#pragma unroll
    for (int r = 0; r < 9; ++r) {
      float rs = expf(a[r] * inv2s - m1) / den1;
      rel2t[ent * 9 + r] = rs * rs * wsql[r];
    }
  }
}

// KG aggregation inner (readlane broadcasts, 4 acc chains) — generic fallback
__device__ __forceinline__ float kg_agg64(int deg, int lane, int pk, float mk,
                                          const ushort_t* __restrict__ srcbf,
                                          const float* __restrict__ wl) {
  float a0 = 0.f, a1 = 0.f, a2 = 0.f, a3 = 0.f;
  int j = 0;
  for (; j + 4 <= deg; j += 4) {
    int p0 = rl(pk, j), p1 = rl(pk, j + 1), p2 = rl(pk, j + 2), p3 = rl(pk, j + 3);
    float k0 = rlf(mk, j), k1 = rlf(mk, j + 1), k2 = rlf(mk, j + 2), k3 = rlf(mk, j + 3);
    float r0 = bf2f(srcbf[((p0 & 0xFFFFF) << 6) + lane]);
    float r1 = bf2f(srcbf[((p1 & 0xFFFFF) << 6) + lane]);
    float r2 = bf2f(srcbf[((p2 & 0xFFFFF) << 6) + lane]);
    float r3 = bf2f(srcbf[((p3 & 0xFFFFF) << 6) + lane]);
    a0 = fmaf(r0 * wl[((p0 >> 20) & 15) * WLS + lane], k0, a0);
    a1 = fmaf(r1 * wl[((p1 >> 20) & 15) * WLS + lane], k1, a1);
    a2 = fmaf(r2 * wl[((p2 >> 20) & 15) * WLS + lane], k2, a2);
    a3 = fmaf(r3 * wl[((p3 >> 20) & 15) * WLS + lane], k3, a3);
  }
  for (; j < deg; ++j) {
    int pj = rl(pk, j);
    float kj = rlf(mk, j);
    a0 = fmaf(bf2f(srcbf[((pj & 0xFFFFF) << 6) + lane]) * wl[((pj >> 20) & 15) * WLS + lane], kj, a0);
  }
  return (a0 + a1) + (a2 + a3);
}

// ---------------- UI aggregation body (group-layout single-pass) ----------------
__device__ __forceinline__ void ui_body(int usr, int lane,
                                        const ushort_t* __restrict__ srcbf,
                                        const float4* __restrict__ sc4,
                                        const float* __restrict__ addb,
                                        float* __restrict__ outp, float* __restrict__ nxt,
                                        const int* __restrict__ uptr,
                                        const int2* __restrict__ cv,
                                        const float* __restrict__ dwl,
                                        const float* __restrict__ latl,
                                        float4* __restrict__ sc4out) {
  float4 s4 = sc4[usr];
  float m = fmaxf(fmaxf(s4.x, s4.y), fmaxf(s4.z, s4.w));
  float e0 = expf(s4.x - m), e1 = expf(s4.y - m), e2 = expf(s4.z - m), e3 = expf(s4.w - m);
  float den = e0 + e1 + e2 + e3;
  float mix = (e0 * dwl[lane] + e1 * dwl[64 + lane] + e2 * dwl[128 + lane] + e3 * dwl[192 + lane]) / den;
  int s = uptr[usr], e = uptr[usr + 1];
  int g = lane >> 3, part = lane & 7;
  float a0 = 0.f, a1 = 0.f, a2 = 0.f, a3 = 0.f;
  float a4 = 0.f, a5 = 0.f, a6 = 0.f, a7 = 0.f;
  for (int base = s; base < e; base += 64) {
    int c = min(64, e - base);
    int2 cvl = (lane < c) ? cv[base + lane] : make_int2(0, 0);
    int cl = cvl.x;
    float vl = __int_as_float(cvl.y);
    int nch = (c + 7) >> 3;
#pragma unroll
    for (int cc = 0; cc < 8; ++cc) {
      if (cc < nch) {
        int j = (cc << 3) + g;
        int cj = __shfl(cl, j);       // inactive rows broadcast 0 -> row 0, vj=0
        float vj = __shfl(vl, j);
        uint4 b = *((const uint4*)(srcbf + ((size_t)cj << 6)) + part);
        a0 = fmaf(bf2f(b.x & 0xFFFFu), vj, a0);
        a1 = fmaf(bf2f(b.x >> 16), vj, a1);
        a2 = fmaf(bf2f(b.y & 0xFFFFu), vj, a2);
        a3 = fmaf(bf2f(b.y >> 16), vj, a3);
        a4 = fmaf(bf2f(b.z & 0xFFFFu), vj, a4);
        a5 = fmaf(bf2f(b.z >> 16), vj, a5);
        a6 = fmaf(bf2f(b.w & 0xFFFFu), vj, a6);
        a7 = fmaf(bf2f(b.w >> 16), vj, a7);
      }
    }
  }
  float acc = colRT(a0, a1, a2, a3, a4, a5, a6, a7, g, part);
  float ua = acc * mix + acc;
  float nrm = sqrtf(waveReduceSum(ua * ua));
  float val = ua / fmaxf(nrm, 1e-12f);
  size_t o = (size_t)usr * 64 + lane;
  if (nxt) nxt[o] = val;
  outp[o] = addb[o] + val;
  if (sc4out) {
    // fused hop-2 factor scores: sc4b[usr] = val @ latent^T
    float s0 = waveReduceSum(val * latl[lane]);
    float s1 = waveReduceSum(val * latl[64 + lane]);
    float s2 = waveReduceSum(val * latl[128 + lane]);
    float s3 = waveReduceSum(val * latl[192 + lane]);
    if (lane == 0) sc4out[usr] = make_float4(s0, s1, s2, s3);
  }
}

// ---------------- D1: mask + fused KG hop-1  |  UI hop-1 (+sc4b) ----------------
__global__ void k_mask_kg_ui(const float* __restrict__ ent0,
                             const ushort_t* __restrict__ ent0bf,
                             const int* __restrict__ hptr, const int* __restrict__ packed,
                             const float* __restrict__ rel2t,
                             float* __restrict__ mask_s, const float* __restrict__ weight,
                             float* __restrict__ out_ent, ushort_t* __restrict__ ent1bf,
                             const float4* __restrict__ sc4,
                             float* __restrict__ out_usr,
                             float* __restrict__ usr1, const int* __restrict__ uptr,
                             const int2* __restrict__ cv,
                             const float* __restrict__ user_emb, const float* __restrict__ dw,
                             const float* __restrict__ latent, float4* __restrict__ sc4b) {
  int lane = threadIdx.x & 63, wid = threadIdx.x >> 6;
  if (blockIdx.x < KG_BLOCKS) {
    __shared__ __align__(16) float sh_eh[4][64];
    __shared__ __align__(16) float wl[9 * WLS];
    for (int i = threadIdx.x; i < 576; i += 256) wl[(i >> 6) * WLS + (i & 63)] = weight[i];
    int ent = blockIdx.x * 4 + wid;  // always < N_ENT
    int s = hptr[ent], e = hptr[ent + 1];
    float eh = ent0[(size_t)ent * 64 + lane];
    sh_eh[wid][lane] = eh;
    __syncthreads();
    size_t o = (size_t)ent * 64 + lane;
    int deg = e - s;
    if (deg == 0) {
      ent1bf[o] = f2bf(0.f);
      out_ent[o] = eh;
      return;
    }
    if (deg <= 64) {
      // ---- single-pass hot path: group-layout dot + DIRECT-EXP softmax.
      // Scores are bounded (|dot| ~ 0.1, rel2 < 1) so exp needs no max-shift. ----
      int pk = (lane < deg) ? packed[s + lane] : 0;
      int tb = (pk >> 20) & 15;
      float r2sel = rel2t[ent * 9 + ((lane < deg) ? tb : 0)];
      int g = lane >> 3, part = lane & 7;
      const float4* ehq = (const float4*)(sh_eh[wid] + (part << 3));
      float4 ef0 = ehq[0], ef1 = ehq[1];
      int nch = (deg + 7) >> 3;
      float den = 0.f;
      float acc0 = 0.f, acc1 = 0.f, acc2 = 0.f, acc3 = 0.f;
      float acc4 = 0.f, acc5 = 0.f, acc6 = 0.f, acc7 = 0.f;
      float ws8[8];
#pragma unroll
      for (int cc = 0; cc < 8; ++cc) {
        ws8[cc] = 0.f;
        if (cc < nch) {
          int j = (cc << 3) + g;  // row handled by this lane's group slot
          int pkj = __shfl(pk, j);  // inactive rows broadcast pk=0 -> row 0 (safe)
          uint4 b = *((const uint4*)(ent0bf + ((size_t)(pkj & 0xFFFFF) << 6)) + part);
          float r0 = bf2f(b.x & 0xFFFFu), r1 = bf2f(b.x >> 16);
          float r2 = bf2f(b.y & 0xFFFFu), r3 = bf2f(b.y >> 16);
          float r4 = bf2f(b.z & 0xFFFFu), r5 = bf2f(b.z >> 16);
          float r6 = bf2f(b.w & 0xFFFFu), r7 = bf2f(b.w >> 16);
          // partial dot over this lane's 8 columns, reduce over part (masks 1,2,4)
          float s0 = r0 * ef0.x, s1 = r2 * ef0.z, s2 = r4 * ef1.x, s3 = r6 * ef1.z;
          s0 = fmaf(r1, ef0.y, s0); s1 = fmaf(r3, ef0.w, s1);
          s2 = fmaf(r5, ef1.y, s2); s3 = fmaf(r7, ef1.w, s3);
          float sv = (s0 + s1) + (s2 + s3);
          sv += __shfl_xor(sv, 1);
          sv += __shfl_xor(sv, 2);
          sv += __shfl_xor(sv, 4);
          float r2j = __shfl(r2sel, j);
          float w = (j < deg) ? expf(sv + r2j) : 0.f;
          ws8[cc] = w;
          den += w;
          // weighted row accumulate into this lane's 8 columns
          const float4* wp = (const float4*)(wl + ((pkj >> 20) & 15) * WLS + (part << 3));
          float4 w0 = wp[0], w1 = wp[1];
          acc0 = fmaf(w * r0, w0.x, acc0);
          acc1 = fmaf(w * r1, w0.y, acc1);
          acc2 = fmaf(w * r2, w0.z, acc2);
          acc3 = fmaf(w * r3, w0.w, acc3);
          acc4 = fmaf(w * r4, w1.x, acc4);
          acc5 = fmaf(w * r5, w1.y, acc5);
          acc6 = fmaf(w * r6, w1.z, acc6);
          acc7 = fmaf(w * r7, w1.w, acc7);
        }
      }
      // full softmax denominator (sum over g: each row counted once per part-octet)
      float den2 = den;
      den2 += __shfl_xor(den2, 8);
      den2 += __shfl_xor(den2, 16);
      den2 += __shfl_xor(den2, 32);
      den2 += 1e-16f;
      float invden = 1.0f / den2;
      // write mask_s (per-chunk: lanes with part==0 write their group's row)
#pragma unroll
      for (int cc = 0; cc < 8; ++cc) {
        if (cc < nch) {
          int j = (cc << 3) + g;
          if (part == 0 && j < deg) mask_s[s + j] = ws8[cc] * invden;
        }
      }
      float aggv = colRT(acc0, acc1, acc2, acc3, acc4, acc5, acc6, acc7, g, part);
      float agg = aggv * invden / (float)deg;
      float nrm = sqrtf(waveReduceSum(agg * agg));
      float val = agg / fmaxf(nrm, 1e-12f);
      ent1bf[o] = f2bf(val);
      out_ent[o] = eh + val;
    } else {
      // ---- generic multi-chunk path (deg>64: essentially never at mean deg 10) ----
      float m2l = -INFINITY;
      for (int base = s; base < e; base += 64) {
        int c = min(64, e - base);
        int pk = (lane < c) ? packed[base + lane] : 0;
        int tb = (pk >> 20) & 15;
        float r2 = rel2t[ent * 9 + ((lane < c) ? tb : 0)];
        int tl = pk & 0xFFFFF;
        const uint4* row = (const uint4*)(ent0bf + (tl << 6));
        const float* ehp = sh_eh[wid];
        float d = 0.f;
#pragma unroll
        for (int q = 0; q < 8; ++q) {
          uint4 a = row[q];
          d += bf2f(a.x & 0xFFFF) * ehp[q * 8 + 0] + bf2f(a.x >> 16) * ehp[q * 8 + 1];
          d += bf2f(a.y & 0xFFFF) * ehp[q * 8 + 2] + bf2f(a.y >> 16) * ehp[q * 8 + 3];
          d += bf2f(a.z & 0xFFFF) * ehp[q * 8 + 4] + bf2f(a.z >> 16) * ehp[q * 8 + 5];
          d += bf2f(a.w & 0xFFFF) * ehp[q * 8 + 6] + bf2f(a.w >> 16) * ehp[q * 8 + 7];
        }
        float trip = d + r2;
        if (lane < c) {
          mask_s[base + lane] = trip;
          m2l = fmaxf(m2l, trip);
        }
      }
      float m2 = waveReduceMax(m2l);
      float denl = 0.f;
      for (int base = s; base < e; base += 64) {
        int c = min(64, e - base);
        denl += (lane < c) ? expf(mask_s[base + lane] - m2) : 0.f;
      }
      float den2 = waveReduceSum(denl) + 1e-16f;
      float acc = 0.f;
      for (int base = s; base < e; base += 64) {
        int c = min(64, e - base);
        int pk = (lane < c) ? packed[base + lane] : 0;
        float mk = 0.f;
        if (lane < c) {
          mk = expf(mask_s[base + lane] - m2) / den2;
          mask_s[base + lane] = mk;
        }
        acc += kg_agg64(c, lane, pk, mk, ent0bf, wl);
      }
      float agg = acc / (float)deg;
      float nrm = sqrtf(waveReduceSum(agg * agg));
      float val = agg / fmaxf(nrm, 1e-12f);
      ent1bf[o] = f2bf(val);
      out_ent[o] = eh + val;
    }
  } else {
    __shared__ float dwl[256];
    __shared__ float latl[256];
    if (threadIdx.x < 256) {
      dwl[threadIdx.x] = dw[threadIdx.x];
      latl[threadIdx.x] = latent[threadIdx.x];
    }
    __syncthreads();
    int usr = (blockIdx.x - KG_BLOCKS) * 4 + wid;  // always < N_USR
    ui_body(usr, lane, ent0bf, sc4, user_emb, out_usr, usr1,
            uptr, cv, dwl, latl, sc4b);
  }
}

// ---------------- D2: KG hop-2 + UI hop-2 (group-layout single-pass) ----------------
__global__ void k_hop2(const ushort_t* __restrict__ srcbf,
                       float* __restrict__ out_ent,
                       const int* __restrict__ hptr, const int* __restrict__ packed,
                       const float* __restrict__ mask_s, const float* __restrict__ weight,
                       const float* __restrict__ usr1, float* __restrict__ out_usr,
                       const int* __restrict__ uptr, const int2* __restrict__ cv,
                       const float4* __restrict__ sc4,
                       const float* __restrict__ dw) {
  int lane = threadIdx.x & 63, wid = threadIdx.x >> 6;
  if (blockIdx.x < KG_BLOCKS) {
    __shared__ __align__(16) float wl[9 * WLS];
    for (int i = threadIdx.x; i < 576; i += 256) wl[(i >> 6) * WLS + (i & 63)] = weight[i];
    __syncthreads();
    int ent = blockIdx.x * 4 + wid;
    int s = hptr[ent], e = hptr[ent + 1];
    int g = lane >> 3, part = lane & 7;
    float a0 = 0.f, a1 = 0.f, a2 = 0.f, a3 = 0.f;
    float a4 = 0.f, a5 = 0.f, a6 = 0.f, a7 = 0.f;
    for (int base = s; base < e; base += 64) {
      int c = min(64, e - base);
      int pk = (lane < c) ? packed[base + lane] : 0;
      float mk = (lane < c) ? mask_s[base + lane] : 0.f;
      int nch = (c + 7) >> 3;
#pragma unroll
      for (int cc = 0; cc < 8; ++cc) {
        if (cc < nch) {
          int j = (cc << 3) + g;
          int pkj = __shfl(pk, j);    // inactive rows: pk=0 -> row 0, mkj=0
          float mkj = __shfl(mk, j);
          uint4 b = *((const uint4*)(srcbf + ((size_t)(pkj & 0xFFFFF) << 6)) + part);
          float r0 = bf2f(b.x & 0xFFFFu), r1 = bf2f(b.x >> 16);
          float r2 = bf2f(b.y & 0xFFFFu), r3 = bf2f(b.y >> 16);
          float r4 = bf2f(b.z & 0xFFFFu), r5 = bf2f(b.z >> 16);
          float r6 = bf2f(b.w & 0xFFFFu), r7 = bf2f(b.w >> 16);
          const float4* wp = (const float4*)(wl + ((pkj >> 20) & 15) * WLS + (part << 3));
          float4 w0 = wp[0], w1 = wp[1];
          a0 = fmaf(mkj * r0, w0.x, a0);
          a1 = fmaf(mkj * r1, w0.y, a1);
          a2 = fmaf(mkj * r2, w0.z, a2);
          a3 = fmaf(mkj * r3, w0.w, a3);
          a4 = fmaf(mkj * r4, w1.x, a4);
          a5 = fmaf(mkj * r5, w1.y, a5);
          a6 = fmaf(mkj * r6, w1.z, a6);
          a7 = fmaf(mkj * r7, w1.w, a7);
        }
      }
    }
    float aggv = colRT(a0, a1, a2, a3, a4, a5, a6, a7, g, part);
    float n = (float)(e - s);
    float agg = aggv / fmaxf(n, 1.0f);
    float nrm = sqrtf(waveReduceSum(agg * agg));
    float val = agg / fmaxf(nrm, 1e-12f);
    size_t o = (size_t)ent * 64 + lane;
    out_ent[o] = out_ent[o] + val;
  } else {
    __shared__ float dwl[256];
    if (threadIdx.x < 256) dwl[threadIdx.x] = dw[threadIdx.x];
    __syncthreads();
    int usr = (blockIdx.x - KG_BLOCKS) * 4 + wid;
    ui_body(usr, lane, srcbf, sc4, out_usr, out_usr, nullptr,
            uptr, cv, dwl, nullptr, nullptr);
  }
}

extern "C" void kernel_launch(void* const* d_in, const int* in_sizes, int n_in,
                              void* d_out, int out_size, void* d_ws, size_t ws_size,
                              hipStream_t stream) {
  const float* user_emb = (const float*)d_in[0];
  const float* entity_emb = (const float*)d_in[1];
  const float* latent = (const float*)d_in[2];
  const float* weight = (const float*)d_in[3];
  const float* disen = (const float*)d_in[4];
  const float* kgW = (const float*)d_in[5];
  const float* ui_vals = (const float*)d_in[6];
  const int* edge_index = (const int*)d_in[7];
  const int* edge_type = (const int*)d_in[8];
  const int* ui_rows = (const int*)d_in[9];
  const int* ui_cols = (const int*)d_in[10];
  const int* head = edge_index;
  const int* tail = edge_index + N_EDGE;

  char* ws = (char*)d_ws;
  size_t o = 0;
  auto alloc = [&](size_t bytes) -> char* {
    char* p = ws + o;
    o += (bytes + 255) & ~(size_t)255;
    return p;
  };
  int* head_ptr = (int*)alloc((N_ENT + 1) * 4);
  int* head_cur = (int*)alloc((size_t)N_ENT * 4);
  int* ui_ptr = (int*)alloc((N_USR + 1) * 4);
  int* ui_cur = (int*)alloc((size_t)N_USR * 4);
  int* bsum_h = (int*)alloc(256 * 4);
  int* bsum_u = (int*)alloc(256 * 4);
  int* packed = (int*)alloc((size_t)N_EDGE * 4);
  int2* cv = (int2*)alloc((size_t)N_EDGE * 8);
  float* mask_s = (float*)alloc((size_t)N_EDGE * 4);
  ushort_t* ent0bf = (ushort_t*)alloc((size_t)N_ENT * 64 * 2);
  ushort_t* ent1bf = (ushort_t*)alloc((size_t)N_ENT * 64 * 2);
  float* usr1 = (float*)alloc((size_t)N_USR * 64 * 4);
  int* cnt9 = (int*)alloc((size_t)N_ENT * 9 * 4);
  float* rel2t = (float*)alloc((size_t)N_ENT * 9 * 4);
  float4* sc4a = (float4*)alloc((size_t)N_USR * 16);
  float4* sc4b = (float4*)alloc((size_t)N_USR * 16);
  float* V = (float*)alloc(9 * 64 * 4);
  float* wsq = (float*)alloc(16 * 4);
  float* dw = (float*)alloc(4 * 64 * 4);
  if (o > ws_size) return;

  float* out_ent = (float*)d_out;
  float* out_usr = out_ent + (size_t)N_ENT * 64;
  float* out_cor = out_ent + (size_t)N_ENT * 64 + (size_t)N_USR * 64;

  hipMemsetAsync(ui_cur, 0, (size_t)N_USR * 4, stream);
  hipMemsetAsync(cnt9, 0, (size_t)N_ENT * 9 * 4, stream);

  // K1: bf16 convert + count + prep + sc(user)
  k_pre<<<TB_BLOCKS + CNT_BLOCKS + 1 + SC_BLOCKS, 256, 0, stream>>>(
      entity_emb, ent0bf, head, ui_rows, edge_type, ui_cur, cnt9,
      weight, kgW, disen, V, wsq, dw, out_cor, user_emb, latent, sc4a);

  int nbh = (N_ENT + 1023) / 1024, nbu = (N_USR + 1023) / 1024;
  // K2: fused scan-reduce
  k_scanred<<<nbh + nbu, 256, 0, stream>>>(cnt9, ui_cur, bsum_h, bsum_u, nbh);
  // K3: block-sum exclusive scans
  k_scan_tops<<<1, 64, 0, stream>>>(bsum_h, nbh, bsum_u, nbu, head_ptr, N_ENT, ui_ptr, N_USR, N_EDGE);
  // K4: fused scan-final
  k_scanfin<<<nbh + nbu, 256, 0, stream>>>(cnt9, bsum_h, bsum_u,
                                           head_ptr, head_cur, ui_ptr, ui_cur, nbh);
  // K5: build + rel2
  k_build_rel2<<<BUILD_BLOCKS + REL2_BLOCKS, 256, 0, stream>>>(
      head, tail, edge_type, ui_rows, ui_cols, ui_vals,
      head_cur, ui_cur, packed, cv, ent0bf, V, wsq, cnt9, rel2t);

  // D1: mask + fused KG hop-1 + UI hop-1 (+ sc4b epilogue)
  k_mask_kg_ui<<<KG_BLOCKS + UI_BLOCKS, 256, 0, stream>>>(
      entity_emb, ent0bf, head_ptr, packed, rel2t, mask_s, weight,
      out_ent, ent1bf, sc4a, out_usr, usr1, ui_ptr, cv, user_emb, dw, latent, sc4b);

  // D2: KG hop-2 + UI hop-2
  k_hop2<<<KG_BLOCKS + UI_BLOCKS, 256, 0, stream>>>(
      ent1bf, out_ent, head_ptr, packed, mask_s, weight,
      usr1, out_usr, ui_ptr, cv, sc4b, dw);
}

// Round 5
// 575.312 us; speedup vs baseline: 1.0105x; 1.0105x over previous
//
#include <hip/hip_runtime.h>
#include <math.h>

#define N_ENT 100000
#define N_USR 50000
#define N_EDGE 1000000
#define B9 (N_ENT * 9)   // 900000 flat (ent,rel) buckets
#define TEMPC 0.2f
#define KG_BLOCKS (N_ENT / 4)   // 25000, exact
#define UI_BLOCKS (N_USR / 4)   // 12500, exact

// fused-kernel block ranges
#define TB_BLOCKS 6250   // ceil(N_ENT*64/4 / 256) : bf16 convert (float4 granules)
#define CNT_BLOCKS 1954  // ceil(N_EDGE/2 / 256) : count+rank, 2 edges/thread
#define SC_BLOCKS 196    // ceil(N_USR / 256)
#define BUILD_BLOCKS 977 // ceil(N_EDGE/4 / 256) : ATOMIC-FREE build, 4 edges/thread
#define REL2_BLOCKS 391  // ceil(N_ENT / 256)

#define WLS 68   // padded stride for weight rows in LDS

typedef unsigned short ushort_t;

__device__ __forceinline__ float waveReduceSum(float x) {
#pragma unroll
  for (int d = 32; d > 0; d >>= 1) x += __shfl_xor(x, d);
  return x;
}
__device__ __forceinline__ float waveReduceMax(float x) {
#pragma unroll
  for (int d = 32; d > 0; d >>= 1) x = fmaxf(x, __shfl_xor(x, d));
  return x;
}
__device__ __forceinline__ int waveReduceSumI(int x) {
#pragma unroll
  for (int d = 32; d > 0; d >>= 1) x += __shfl_xor(x, d);
  return x;
}
__device__ __forceinline__ float bf2f(unsigned int u16) {
  union { unsigned int i; float f; } v;
  v.i = u16 << 16;
  return v.f;
}
__device__ __forceinline__ ushort_t f2bf(float f) {
  union { unsigned int i; float f; } v;
  v.f = f;
  unsigned int u = v.i;
  u = (u + 0x7FFFu + ((u >> 16) & 1u)) >> 16;
  return (ushort_t)u;
}
// wave-uniform broadcast via v_readlane -> SGPR
__device__ __forceinline__ int rl(int v, int l) { return __builtin_amdgcn_readlane(v, l); }
__device__ __forceinline__ float rlf(float v, int l) {
  return __int_as_float(__builtin_amdgcn_readlane(__float_as_int(v), l));
}

// column-partial reduce over g (masks 8/16/32) + 8x8 wave transpose:
// on entry lane holds partials for columns part*8+k; on exit lane l holds colsum[l].
__device__ __forceinline__ float colRT(float a0, float a1, float a2, float a3,
                                       float a4, float a5, float a6, float a7,
                                       int g, int part) {
#define RED3(x) x += __shfl_xor(x, 8); x += __shfl_xor(x, 16); x += __shfl_xor(x, 32);
  RED3(a0) RED3(a1) RED3(a2) RED3(a3) RED3(a4) RED3(a5) RED3(a6) RED3(a7)
#undef RED3
  float t0 = __shfl(a0, g), t1 = __shfl(a1, g), t2 = __shfl(a2, g), t3 = __shfl(a3, g);
  float t4 = __shfl(a4, g), t5 = __shfl(a5, g), t6 = __shfl(a6, g), t7 = __shfl(a7, g);
  float r = t0;
  r = (part == 1) ? t1 : r;
  r = (part == 2) ? t2 : r;
  r = (part == 3) ? t3 : r;
  r = (part == 4) ? t4 : r;
  r = (part == 5) ? t5 : r;
  r = (part == 6) ? t6 : r;
  r = (part == 7) ? t7 : r;
  return r;
}

// ============ K1: bf16 convert | count+rank (2/thr) | prep | sc(user) ============
__global__ void k_pre(const float* __restrict__ ent0, ushort_t* __restrict__ ent0bf,
                      const int* __restrict__ head, const int* __restrict__ uir,
                      const int* __restrict__ etype,
                      int* __restrict__ cnt_u, int* __restrict__ cnt9,
                      int2* __restrict__ rank2,
                      const float* __restrict__ weight, const float* __restrict__ kgW,
                      const float* __restrict__ disen,
                      float* __restrict__ V, float* __restrict__ wsq,
                      float* __restrict__ dw, float* __restrict__ cor_out,
                      const float* __restrict__ user_emb, const float* __restrict__ latent,
                      float4* __restrict__ sc4a) {
  int bid = blockIdx.x;
  if (bid < TB_BLOCKS) {
    int i = bid * 256 + threadIdx.x;
    if (i < N_ENT * 16) {
      float4 v = ((const float4*)ent0)[i];
      ushort4 o;
      o.x = f2bf(v.x); o.y = f2bf(v.y); o.z = f2bf(v.z); o.w = f2bf(v.w);
      ((ushort4*)ent0bf)[i] = o;
    }
  } else if (bid < TB_BLOCKS + CNT_BLOCKS) {
    int i0 = ((bid - TB_BLOCKS) * 256 + threadIdx.x) * 2;
    if (i0 < N_EDGE) {
      int2 h = *(const int2*)(head + i0);
      int2 et = *(const int2*)(etype + i0);
      int2 u = *(const int2*)(uir + i0);
      // rank within (head,rel) bucket and within user row — captured here so the
      // build phase needs NO atomics (return-atomics + scattered stores collapsed
      // under concurrency; fire-and-forget-ish atomics + coalesced rank store don't).
      int r0 = atomicAdd(&cnt9[h.x * 9 + (et.x - 1)], 1);
      int r1 = atomicAdd(&cnt9[h.y * 9 + (et.y - 1)], 1);
      int u0 = atomicAdd(&cnt_u[u.x], 1);
      int u1 = atomicAdd(&cnt_u[u.y], 1);
      rank2[i0] = make_int2(r0, u0);
      rank2[i0 + 1] = make_int2(r1, u1);
    }
  } else if (bid == TB_BLOCKS + CNT_BLOCKS) {
    // ---- prep: V=(W W^T)w_r via T-factorization, wsq, dw, cor ----
    __shared__ float T[9 * 64];
    __shared__ float sm[4 * 9];
    int tid = threadIdx.x;
    for (int e = tid; e < 9 * 64; e += 256) {
      int r = e >> 6, d = e & 63;
      float s = 0.f;
      for (int k = 0; k < 64; ++k) s += kgW[k * 64 + d] * weight[r * 64 + k];
      T[e] = s;
    }
    if (tid < 4) {
      float m = -INFINITY;
      for (int r = 0; r < 9; ++r) m = fmaxf(m, disen[tid * 9 + r]);
      float den = 0.f;
      float ex[9];
      for (int r = 0; r < 9; ++r) { ex[r] = expf(disen[tid * 9 + r] - m); den += ex[r]; }
      for (int r = 0; r < 9; ++r) sm[tid * 9 + r] = ex[r] / den;
    }
    __syncthreads();
    for (int e = tid; e < 9 * 64; e += 256) {
      int r = e >> 6, i = e & 63;
      float s = 0.f;
      for (int d = 0; d < 64; ++d) s += kgW[i * 64 + d] * T[r * 64 + d];
      V[e] = s;
    }
    if (tid < 9) {
      float s = 0.f;
      for (int c = 0; c < 64; ++c) { float w = weight[tid * 64 + c]; s += w * w; }
      wsq[tid] = s;
    }
    for (int e = tid; e < 4 * 64; e += 256) {
      int f = e >> 6, c = e & 63;
      float s = 0.f;
      for (int r = 0; r < 9; ++r) s += sm[f * 9 + r] * weight[r * 64 + c];
      dw[e] = s;
    }
    if (tid == 0) {
      float rowsum[4];
      for (int f = 0; f < 4; ++f) {
        float s = 0.f;
        for (int j = 0; j < 9; ++j) s += disen[f * 9 + j];
        rowsum[f] = s;
      }
      float cor = 0.f;
      for (int i = 0; i < 9; ++i) {
        float n2 = 0.f, ttl = 0.f;
        for (int f = 0; f < 4; ++f) {
          float v = disen[f * 9 + i];
          n2 += v * v;
          ttl += v * rowsum[f];
        }
        float nrm = sqrtf(n2);
        float pos = 0.f;
        for (int f = 0; f < 4; ++f) {
          float v = disen[f * 9 + i] / nrm;
          pos += v * v;
        }
        cor += (ttl - pos) / TEMPC;
      }
      *cor_out = cor;
    }
  } else {
    // ---- sc on user_emb -> sc4a ----
    __shared__ __align__(16) float lat[256];
    if (threadIdx.x < 256) lat[threadIdx.x] = latent[threadIdx.x];
    __syncthreads();
    int u = (bid - TB_BLOCKS - CNT_BLOCKS - 1) * 256 + threadIdx.x;
    if (u >= N_USR) return;
    float a0 = 0.f, a1 = 0.f, a2 = 0.f, a3 = 0.f;
    const float4* row = (const float4*)(user_emb + (size_t)u * 64);
#pragma unroll
    for (int q = 0; q < 16; ++q) {
      float4 v = row[q];
      float4 l0 = *(const float4*)(lat + 0 * 64 + q * 4);
      float4 l1 = *(const float4*)(lat + 1 * 64 + q * 4);
      float4 l2 = *(const float4*)(lat + 2 * 64 + q * 4);
      float4 l3 = *(const float4*)(lat + 3 * 64 + q * 4);
      a0 = fmaf(v.x, l0.x, a0); a0 = fmaf(v.y, l0.y, a0); a0 = fmaf(v.z, l0.z, a0); a0 = fmaf(v.w, l0.w, a0);
      a1 = fmaf(v.x, l1.x, a1); a1 = fmaf(v.y, l1.y, a1); a1 = fmaf(v.z, l1.z, a1); a1 = fmaf(v.w, l1.w, a1);
      a2 = fmaf(v.x, l2.x, a2); a2 = fmaf(v.y, l2.y, a2); a2 = fmaf(v.z, l2.z, a2); a2 = fmaf(v.w, l2.w, a2);
      a3 = fmaf(v.x, l3.x, a3); a3 = fmaf(v.y, l3.y, a3); a3 = fmaf(v.z, l3.z, a3); a3 = fmaf(v.w, l3.w, a3);
    }
    sc4a[u] = make_float4(a0, a1, a2, a3);
  }
}

// ============ K2: fused scan-reduce (flat cnt9 | cnt_u) ============
__global__ void k_scanred(const int* __restrict__ cnt9, const int* __restrict__ cnt_u,
                          int* __restrict__ bsum_h, int* __restrict__ bsum_u, int nbh) {
  int b = blockIdx.x, tid = threadIdx.x;
  int s = 0;
  if (b < nbh) {
    int i0 = b * 1024 + tid * 4;
#pragma unroll
    for (int k = 0; k < 4; ++k)
      if (i0 + k < B9) s += cnt9[i0 + k];
  } else {
    int i0 = (b - nbh) * 1024 + tid * 4;
#pragma unroll
    for (int k = 0; k < 4; ++k)
      if (i0 + k < N_USR) s += cnt_u[i0 + k];
  }
  s = waveReduceSumI(s);
  __shared__ int l[4];
  int lane = tid & 63, wid = tid >> 6;
  if (lane == 0) l[wid] = s;
  __syncthreads();
  if (tid == 0) {
    int v = l[0] + l[1] + l[2] + l[3];
    if (b < nbh) bsum_h[b] = v; else bsum_u[b - nbh] = v;
  }
}

__global__ void k_scan_tops(int* bsA, int nA, int* bsB, int nB,
                            int* ptrA, int NA, int* ptrB, int NB, int total) {
  if (threadIdx.x == 0) {
    int a = 0;
    for (int i = 0; i < nA; ++i) { int t = bsA[i]; bsA[i] = a; a += t; }
    ptrA[NA] = total;
  }
  if (threadIdx.x == 1) {
    int a = 0;
    for (int i = 0; i < nB; ++i) { int t = bsB[i]; bsB[i] = a; a += t; }
    ptrB[NB] = total;
  }
}

// ============ K4: fused scan-final (flat cnt9 -> base9 + head_ptr | cnt_u -> ui_ptr) ============
__global__ void k_scanfin(const int* __restrict__ cnt9, const int* __restrict__ cnt_u,
                          const int* __restrict__ bsum_h, const int* __restrict__ bsum_u,
                          int* __restrict__ base9, int* __restrict__ head_ptr,
                          int* __restrict__ ui_ptr, int nbh) {
  int b = blockIdx.x, tid = threadIdx.x;
  bool isH = (b < nbh);
  int bl = isH ? b : b - nbh;
  int n = isH ? B9 : N_USR;
  int i0 = bl * 1024 + tid * 4;
  int s = 0;
  int loc[4];
#pragma unroll
  for (int k = 0; k < 4; ++k) {
    int v = 0;
    if (i0 + k < n) v = isH ? cnt9[i0 + k] : cnt_u[i0 + k];
    loc[k] = s;
    s += v;
  }
  int lane = tid & 63, wid = tid >> 6;
  int x = s;
#pragma unroll
  for (int d = 1; d < 64; d <<= 1) {
    int y = __shfl_up(x, d);
    if (lane >= d) x += y;
  }
  __shared__ int l[4];
  if (lane == 63) l[wid] = x;
  __syncthreads();
  if (tid == 0) {
    int a = 0;
    for (int w = 0; w < 4; ++w) { int t = l[w]; l[w] = a; a += t; }
  }
  __syncthreads();
  int excl = x - s + l[wid] + (isH ? bsum_h[bl] : bsum_u[bl]);
#pragma unroll
  for (int k = 0; k < 4; ++k) {
    int idx = i0 + k;
    if (idx < n) {
      int v = excl + loc[k];
      if (isH) {
        base9[idx] = v;
        int ent = idx / 9;
        if (idx - ent * 9 == 0) head_ptr[ent] = v;  // entity boundary
      } else {
        ui_ptr[idx] = v;
      }
    }
  }
}

// ============ K5: ATOMIC-FREE build (4/thr) | rel2 ============
__global__ void k_build_rel2(const int* __restrict__ head, const int* __restrict__ tail,
                             const int* __restrict__ etype,
                             const int* __restrict__ uir, const int* __restrict__ uic,
                             const float* __restrict__ uival,
                             const int* __restrict__ base9, const int* __restrict__ ui_ptr,
                             const int2* __restrict__ rank2,
                             int* __restrict__ packed, int2* __restrict__ cv,
                             const ushort_t* __restrict__ ent0bf, const float* __restrict__ V,
                             const float* __restrict__ wsq, const int* __restrict__ cnt9,
                             float* __restrict__ rel2t) {
  if (blockIdx.x < BUILD_BLOCKS) {
    int i0 = (blockIdx.x * 256 + threadIdx.x) * 4;
    if (i0 >= N_EDGE) return;
    int4 h = *(const int4*)(head + i0);
    int4 t = *(const int4*)(tail + i0);
    int4 et = *(const int4*)(etype + i0);
    int4 ur = *(const int4*)(uir + i0);
    int4 uc = *(const int4*)(uic + i0);
    float4 uv = *(const float4*)(uival + i0);
    int4 ra = *(const int4*)(rank2 + i0);      // (rh0,ru0, rh1,ru1)
    int4 rb = *(const int4*)(rank2 + i0 + 2);  // (rh2,ru2, rh3,ru3)
    // deterministic slots: bucket base + captured rank (no atomics)
    int s0 = base9[h.x * 9 + et.x - 1] + ra.x;
    int s1 = base9[h.y * 9 + et.y - 1] + ra.z;
    int s2 = base9[h.z * 9 + et.z - 1] + rb.x;
    int s3 = base9[h.w * 9 + et.w - 1] + rb.z;
    packed[s0] = (t.x & 0xFFFFF) | ((et.x - 1) << 20);
    packed[s1] = (t.y & 0xFFFFF) | ((et.y - 1) << 20);
    packed[s2] = (t.z & 0xFFFFF) | ((et.z - 1) << 20);
    packed[s3] = (t.w & 0xFFFFF) | ((et.w - 1) << 20);
    int q0 = ui_ptr[ur.x] + ra.y;
    int q1 = ui_ptr[ur.y] + ra.w;
    int q2 = ui_ptr[ur.z] + rb.y;
    int q3 = ui_ptr[ur.w] + rb.w;
    cv[q0] = make_int2(uc.x, __float_as_int(uv.x));
    cv[q1] = make_int2(uc.y, __float_as_int(uv.y));
    cv[q2] = make_int2(uc.z, __float_as_int(uv.z));
    cv[q3] = make_int2(uc.w, __float_as_int(uv.w));
  } else {
    // ---- rel2: dense per-entity relation softmax table ----
    __shared__ __align__(16) float Vl[576];
    __shared__ float wsql[9];
    for (int i = threadIdx.x; i < 576; i += 256) Vl[i] = V[i];
    if (threadIdx.x < 9) wsql[threadIdx.x] = wsq[threadIdx.x];
    __syncthreads();
    int ent = (blockIdx.x - BUILD_BLOCKS) * 256 + threadIdx.x;
    if (ent >= N_ENT) return;
    float a[9] = {0, 0, 0, 0, 0, 0, 0, 0, 0};
    const uint4* row = (const uint4*)(ent0bf + (ent << 6));
#pragma unroll
    for (int q = 0; q < 8; ++q) {
      uint4 b = row[q];
      float ch0 = bf2f(b.x & 0xFFFFu), ch1 = bf2f(b.x >> 16);
      float ch2 = bf2f(b.y & 0xFFFFu), ch3 = bf2f(b.y >> 16);
      float ch4 = bf2f(b.z & 0xFFFFu), ch5 = bf2f(b.z >> 16);
      float ch6 = bf2f(b.w & 0xFFFFu), ch7 = bf2f(b.w >> 16);
#pragma unroll
      for (int r = 0; r < 9; ++r) {
        const float4* vp = (const float4*)(Vl + r * 64 + q * 8);
        float4 v0 = vp[0], v1 = vp[1];
        float t = a[r];
        t = fmaf(ch0, v0.x, t); t = fmaf(ch1, v0.y, t);
        t = fmaf(ch2, v0.z, t); t = fmaf(ch3, v0.w, t);
        t = fmaf(ch4, v1.x, t); t = fmaf(ch5, v1.y, t);
        t = fmaf(ch6, v1.z, t); t = fmaf(ch7, v1.w, t);
        a[r] = t;
      }
    }
    const float inv2s = 0.08838834764831845f;  // 1/(2*sqrt(32))
    int cnt[9];
#pragma unroll
    for (int r = 0; r < 9; ++r) cnt[r] = cnt9[ent * 9 + r];
    float m1 = -INFINITY;
#pragma unroll
    for (int r = 0; r < 9; ++r)
      if (cnt[r] > 0) m1 = fmaxf(m1, a[r] * inv2s);
    if (m1 == -INFINITY) {
#pragma unroll
      for (int r = 0; r < 9; ++r) rel2t[ent * 9 + r] = 0.f;
      return;
    }
    float den1 = 1e-16f;
#pragma unroll
    for (int r = 0; r < 9; ++r)
      if (cnt[r] > 0) den1 += (float)cnt[r] * expf(a[r] * inv2s - m1);
#pragma unroll
    for (int r = 0; r < 9; ++r) {
      float rs = expf(a[r] * inv2s - m1) / den1;
      rel2t[ent * 9 + r] = rs * rs * wsql[r];
    }
  }
}

// KG aggregation inner (readlane broadcasts, 4 acc chains) — generic fallback
__device__ __forceinline__ float kg_agg64(int deg, int lane, int pk, float mk,
                                          const ushort_t* __restrict__ srcbf,
                                          const float* __restrict__ wl) {
  float a0 = 0.f, a1 = 0.f, a2 = 0.f, a3 = 0.f;
  int j = 0;
  for (; j + 4 <= deg; j += 4) {
    int p0 = rl(pk, j), p1 = rl(pk, j + 1), p2 = rl(pk, j + 2), p3 = rl(pk, j + 3);
    float k0 = rlf(mk, j), k1 = rlf(mk, j + 1), k2 = rlf(mk, j + 2), k3 = rlf(mk, j + 3);
    float r0 = bf2f(srcbf[((p0 & 0xFFFFF) << 6) + lane]);
    float r1 = bf2f(srcbf[((p1 & 0xFFFFF) << 6) + lane]);
    float r2 = bf2f(srcbf[((p2 & 0xFFFFF) << 6) + lane]);
    float r3 = bf2f(srcbf[((p3 & 0xFFFFF) << 6) + lane]);
    a0 = fmaf(r0 * wl[((p0 >> 20) & 15) * WLS + lane], k0, a0);
    a1 = fmaf(r1 * wl[((p1 >> 20) & 15) * WLS + lane], k1, a1);
    a2 = fmaf(r2 * wl[((p2 >> 20) & 15) * WLS + lane], k2, a2);
    a3 = fmaf(r3 * wl[((p3 >> 20) & 15) * WLS + lane], k3, a3);
  }
  for (; j < deg; ++j) {
    int pj = rl(pk, j);
    float kj = rlf(mk, j);
    a0 = fmaf(bf2f(srcbf[((pj & 0xFFFFF) << 6) + lane]) * wl[((pj >> 20) & 15) * WLS + lane], kj, a0);
  }
  return (a0 + a1) + (a2 + a3);
}

// ---------------- UI aggregation body (group-layout single-pass) ----------------
__device__ __forceinline__ void ui_body(int usr, int lane,
                                        const ushort_t* __restrict__ srcbf,
                                        const float4* __restrict__ sc4,
                                        const float* __restrict__ addb,
                                        float* __restrict__ outp, float* __restrict__ nxt,
                                        const int* __restrict__ uptr,
                                        const int2* __restrict__ cv,
                                        const float* __restrict__ dwl,
                                        const float* __restrict__ latl,
                                        float4* __restrict__ sc4out) {
  float4 s4 = sc4[usr];
  float m = fmaxf(fmaxf(s4.x, s4.y), fmaxf(s4.z, s4.w));
  float e0 = expf(s4.x - m), e1 = expf(s4.y - m), e2 = expf(s4.z - m), e3 = expf(s4.w - m);
  float den = e0 + e1 + e2 + e3;
  float mix = (e0 * dwl[lane] + e1 * dwl[64 + lane] + e2 * dwl[128 + lane] + e3 * dwl[192 + lane]) / den;
  int s = uptr[usr], e = uptr[usr + 1];
  int g = lane >> 3, part = lane & 7;
  float a0 = 0.f, a1 = 0.f, a2 = 0.f, a3 = 0.f;
  float a4 = 0.f, a5 = 0.f, a6 = 0.f, a7 = 0.f;
  for (int base = s; base < e; base += 64) {
    int c = min(64, e - base);
    int2 cvl = (lane < c) ? cv[base + lane] : make_int2(0, 0);
    int cl = cvl.x;
    float vl = __int_as_float(cvl.y);
    int nch = (c + 7) >> 3;
#pragma unroll
    for (int cc = 0; cc < 8; ++cc) {
      if (cc < nch) {
        int j = (cc << 3) + g;
        int cj = __shfl(cl, j);       // inactive rows broadcast 0 -> row 0, vj=0
        float vj = __shfl(vl, j);
        uint4 b = *((const uint4*)(srcbf + ((size_t)cj << 6)) + part);
        a0 = fmaf(bf2f(b.x & 0xFFFFu), vj, a0);
        a1 = fmaf(bf2f(b.x >> 16), vj, a1);
        a2 = fmaf(bf2f(b.y & 0xFFFFu), vj, a2);
        a3 = fmaf(bf2f(b.y >> 16), vj, a3);
        a4 = fmaf(bf2f(b.z & 0xFFFFu), vj, a4);
        a5 = fmaf(bf2f(b.z >> 16), vj, a5);
        a6 = fmaf(bf2f(b.w & 0xFFFFu), vj, a6);
        a7 = fmaf(bf2f(b.w >> 16), vj, a7);
      }
    }
  }
  float acc = colRT(a0, a1, a2, a3, a4, a5, a6, a7, g, part);
  float ua = acc * mix + acc;
  float nrm = sqrtf(waveReduceSum(ua * ua));
  float val = ua / fmaxf(nrm, 1e-12f);
  size_t o = (size_t)usr * 64 + lane;
  if (nxt) nxt[o] = val;
  outp[o] = addb[o] + val;
  if (sc4out) {
    // fused hop-2 factor scores: sc4b[usr] = val @ latent^T
    float s0 = waveReduceSum(val * latl[lane]);
    float s1 = waveReduceSum(val * latl[64 + lane]);
    float s2 = waveReduceSum(val * latl[128 + lane]);
    float s3 = waveReduceSum(val * latl[192 + lane]);
    if (lane == 0) sc4out[usr] = make_float4(s0, s1, s2, s3);
  }
}

// ---------------- D1: mask + fused KG hop-1  |  UI hop-1 (+sc4b) ----------------
__global__ void k_mask_kg_ui(const float* __restrict__ ent0,
                             const ushort_t* __restrict__ ent0bf,
                             const int* __restrict__ hptr, const int* __restrict__ packed,
                             const float* __restrict__ rel2t,
                             float* __restrict__ mask_s, const float* __restrict__ weight,
                             float* __restrict__ out_ent, ushort_t* __restrict__ ent1bf,
                             const float4* __restrict__ sc4,
                             float* __restrict__ out_usr,
                             float* __restrict__ usr1, const int* __restrict__ uptr,
                             const int2* __restrict__ cv,
                             const float* __restrict__ user_emb, const float* __restrict__ dw,
                             const float* __restrict__ latent, float4* __restrict__ sc4b) {
  int lane = threadIdx.x & 63, wid = threadIdx.x >> 6;
  if (blockIdx.x < KG_BLOCKS) {
    __shared__ __align__(16) float sh_eh[4][64];
    __shared__ __align__(16) float wl[9 * WLS];
    for (int i = threadIdx.x; i < 576; i += 256) wl[(i >> 6) * WLS + (i & 63)] = weight[i];
    int ent = blockIdx.x * 4 + wid;  // always < N_ENT
    int s = hptr[ent], e = hptr[ent + 1];
    float eh = ent0[(size_t)ent * 64 + lane];
    sh_eh[wid][lane] = eh;
    __syncthreads();
    size_t o = (size_t)ent * 64 + lane;
    int deg = e - s;
    if (deg == 0) {
      ent1bf[o] = f2bf(0.f);
      out_ent[o] = eh;
      return;
    }
    if (deg <= 64) {
      // ---- single-pass hot path: group-layout dot + DIRECT-EXP softmax. ----
      int pk = (lane < deg) ? packed[s + lane] : 0;
      int tb = (pk >> 20) & 15;
      float r2sel = rel2t[ent * 9 + ((lane < deg) ? tb : 0)];
      int g = lane >> 3, part = lane & 7;
      const float4* ehq = (const float4*)(sh_eh[wid] + (part << 3));
      float4 ef0 = ehq[0], ef1 = ehq[1];
      int nch = (deg + 7) >> 3;
      float den = 0.f;
      float acc0 = 0.f, acc1 = 0.f, acc2 = 0.f, acc3 = 0.f;
      float acc4 = 0.f, acc5 = 0.f, acc6 = 0.f, acc7 = 0.f;
      float ws8[8];
#pragma unroll
      for (int cc = 0; cc < 8; ++cc) {
        ws8[cc] = 0.f;
        if (cc < nch) {
          int j = (cc << 3) + g;  // row handled by this lane's group slot
          int pkj = __shfl(pk, j);  // inactive rows broadcast pk=0 -> row 0 (safe)
          uint4 b = *((const uint4*)(ent0bf + ((size_t)(pkj & 0xFFFFF) << 6)) + part);
          float r0 = bf2f(b.x & 0xFFFFu), r1 = bf2f(b.x >> 16);
          float r2 = bf2f(b.y & 0xFFFFu), r3 = bf2f(b.y >> 16);
          float r4 = bf2f(b.z & 0xFFFFu), r5 = bf2f(b.z >> 16);
          float r6 = bf2f(b.w & 0xFFFFu), r7 = bf2f(b.w >> 16);
          // partial dot over this lane's 8 columns, reduce over part (masks 1,2,4)
          float s0 = r0 * ef0.x, s1 = r2 * ef0.z, s2 = r4 * ef1.x, s3 = r6 * ef1.z;
          s0 = fmaf(r1, ef0.y, s0); s1 = fmaf(r3, ef0.w, s1);
          s2 = fmaf(r5, ef1.y, s2); s3 = fmaf(r7, ef1.w, s3);
          float sv = (s0 + s1) + (s2 + s3);
          sv += __shfl_xor(sv, 1);
          sv += __shfl_xor(sv, 2);
          sv += __shfl_xor(sv, 4);
          float r2j = __shfl(r2sel, j);
          float w = (j < deg) ? expf(sv + r2j) : 0.f;
          ws8[cc] = w;
          den += w;
          // weighted row accumulate into this lane's 8 columns
          const float4* wp = (const float4*)(wl + ((pkj >> 20) & 15) * WLS + (part << 3));
          float4 w0 = wp[0], w1 = wp[1];
          acc0 = fmaf(w * r0, w0.x, acc0);
          acc1 = fmaf(w * r1, w0.y, acc1);
          acc2 = fmaf(w * r2, w0.z, acc2);
          acc3 = fmaf(w * r3, w0.w, acc3);
          acc4 = fmaf(w * r4, w1.x, acc4);
          acc5 = fmaf(w * r5, w1.y, acc5);
          acc6 = fmaf(w * r6, w1.z, acc6);
          acc7 = fmaf(w * r7, w1.w, acc7);
        }
      }
      // full softmax denominator (sum over g: each row counted once per part-octet)
      float den2 = den;
      den2 += __shfl_xor(den2, 8);
      den2 += __shfl_xor(den2, 16);
      den2 += __shfl_xor(den2, 32);
      den2 += 1e-16f;
      float invden = 1.0f / den2;
      // write mask_s (per-chunk: lanes with part==0 write their group's row)
#pragma unroll
      for (int cc = 0; cc < 8; ++cc) {
        if (cc < nch) {
          int j = (cc << 3) + g;
          if (part == 0 && j < deg) mask_s[s + j] = ws8[cc] * invden;
        }
      }
      float aggv = colRT(acc0, acc1, acc2, acc3, acc4, acc5, acc6, acc7, g, part);
      float agg = aggv * invden / (float)deg;
      float nrm = sqrtf(waveReduceSum(agg * agg));
      float val = agg / fmaxf(nrm, 1e-12f);
      ent1bf[o] = f2bf(val);
      out_ent[o] = eh + val;
    } else {
      // ---- generic multi-chunk path (deg>64) ----
      float m2l = -INFINITY;
      for (int base = s; base < e; base += 64) {
        int c = min(64, e - base);
        int pk = (lane < c) ? packed[base + lane] : 0;
        int tb = (pk >> 20) & 15;
        float r2 = rel2t[ent * 9 + ((lane < c) ? tb : 0)];
        int tl = pk & 0xFFFFF;
        const uint4* row = (const uint4*)(ent0bf + (tl << 6));
        const float* ehp = sh_eh[wid];
        float d = 0.f;
#pragma unroll
        for (int q = 0; q < 8; ++q) {
          uint4 a = row[q];
          d += bf2f(a.x & 0xFFFF) * ehp[q * 8 + 0] + bf2f(a.x >> 16) * ehp[q * 8 + 1];
          d += bf2f(a.y & 0xFFFF) * ehp[q * 8 + 2] + bf2f(a.y >> 16) * ehp[q * 8 + 3];
          d += bf2f(a.z & 0xFFFF) * ehp[q * 8 + 4] + bf2f(a.z >> 16) * ehp[q * 8 + 5];
          d += bf2f(a.w & 0xFFFF) * ehp[q * 8 + 6] + bf2f(a.w >> 16) * ehp[q * 8 + 7];
        }
        float trip = d + r2;
        if (lane < c) {
          mask_s[base + lane] = trip;
          m2l = fmaxf(m2l, trip);
        }
      }
      float m2 = waveReduceMax(m2l);
      float denl = 0.f;
      for (int base = s; base < e; base += 64) {
        int c = min(64, e - base);
        denl += (lane < c) ? expf(mask_s[base + lane] - m2) : 0.f;
      }
      float den2 = waveReduceSum(denl) + 1e-16f;
      float acc = 0.f;
      for (int base = s; base < e; base += 64) {
        int c = min(64, e - base);
        int pk = (lane < c) ? packed[base + lane] : 0;
        float mk = 0.f;
        if (lane < c) {
          mk = expf(mask_s[base + lane] - m2) / den2;
          mask_s[base + lane] = mk;
        }
        acc += kg_agg64(c, lane, pk, mk, ent0bf, wl);
      }
      float agg = acc / (float)deg;
      float nrm = sqrtf(waveReduceSum(agg * agg));
      float val = agg / fmaxf(nrm, 1e-12f);
      ent1bf[o] = f2bf(val);
      out_ent[o] = eh + val;
    }
  } else {
    __shared__ float dwl[256];
    __shared__ float latl[256];
    if (threadIdx.x < 256) {
      dwl[threadIdx.x] = dw[threadIdx.x];
      latl[threadIdx.x] = latent[threadIdx.x];
    }
    __syncthreads();
    int usr = (blockIdx.x - KG_BLOCKS) * 4 + wid;  // always < N_USR
    ui_body(usr, lane, ent0bf, sc4, user_emb, out_usr, usr1,
            uptr, cv, dwl, latl, sc4b);
  }
}

// ---------------- D2: KG hop-2 + UI hop-2 (group-layout single-pass) ----------------
__global__ void k_hop2(const ushort_t* __restrict__ srcbf,
                       float* __restrict__ out_ent,
                       const int* __restrict__ hptr, const int* __restrict__ packed,
                       const float* __restrict__ mask_s, const float* __restrict__ weight,
                       const float* __restrict__ usr1, float* __restrict__ out_usr,
                       const int* __restrict__ uptr, const int2* __restrict__ cv,
                       const float4* __restrict__ sc4,
                       const float* __restrict__ dw) {
  int lane = threadIdx.x & 63, wid = threadIdx.x >> 6;
  if (blockIdx.x < KG_BLOCKS) {
    __shared__ __align__(16) float wl[9 * WLS];
    for (int i = threadIdx.x; i < 576; i += 256) wl[(i >> 6) * WLS + (i & 63)] = weight[i];
    __syncthreads();
    int ent = blockIdx.x * 4 + wid;
    int s = hptr[ent], e = hptr[ent + 1];
    int g = lane >> 3, part = lane & 7;
    float a0 = 0.f, a1 = 0.f, a2 = 0.f, a3 = 0.f;
    float a4 = 0.f, a5 = 0.f, a6 = 0.f, a7 = 0.f;
    for (int base = s; base < e; base += 64) {
      int c = min(64, e - base);
      int pk = (lane < c) ? packed[base + lane] : 0;
      float mk = (lane < c) ? mask_s[base + lane] : 0.f;
      int nch = (c + 7) >> 3;
#pragma unroll
      for (int cc = 0; cc < 8; ++cc) {
        if (cc < nch) {
          int j = (cc << 3) + g;
          int pkj = __shfl(pk, j);    // inactive rows: pk=0 -> row 0, mkj=0
          float mkj = __shfl(mk, j);
          uint4 b = *((const uint4*)(srcbf + ((size_t)(pkj & 0xFFFFF) << 6)) + part);
          float r0 = bf2f(b.x & 0xFFFFu), r1 = bf2f(b.x >> 16);
          float r2 = bf2f(b.y & 0xFFFFu), r3 = bf2f(b.y >> 16);
          float r4 = bf2f(b.z & 0xFFFFu), r5 = bf2f(b.z >> 16);
          float r6 = bf2f(b.w & 0xFFFFu), r7 = bf2f(b.w >> 16);
          const float4* wp = (const float4*)(wl + ((pkj >> 20) & 15) * WLS + (part << 3));
          float4 w0 = wp[0], w1 = wp[1];
          a0 = fmaf(mkj * r0, w0.x, a0);
          a1 = fmaf(mkj * r1, w0.y, a1);
          a2 = fmaf(mkj * r2, w0.z, a2);
          a3 = fmaf(mkj * r3, w0.w, a3);
          a4 = fmaf(mkj * r4, w1.x, a4);
          a5 = fmaf(mkj * r5, w1.y, a5);
          a6 = fmaf(mkj * r6, w1.z, a6);
          a7 = fmaf(mkj * r7, w1.w, a7);
        }
      }
    }
    float aggv = colRT(a0, a1, a2, a3, a4, a5, a6, a7, g, part);
    float n = (float)(e - s);
    float agg = aggv / fmaxf(n, 1.0f);
    float nrm = sqrtf(waveReduceSum(agg * agg));
    float val = agg / fmaxf(nrm, 1e-12f);
    size_t o = (size_t)ent * 64 + lane;
    out_ent[o] = out_ent[o] + val;
  } else {
    __shared__ float dwl[256];
    if (threadIdx.x < 256) dwl[threadIdx.x] = dw[threadIdx.x];
    __syncthreads();
    int usr = (blockIdx.x - KG_BLOCKS) * 4 + wid;
    ui_body(usr, lane, srcbf, sc4, out_usr, out_usr, nullptr,
            uptr, cv, dwl, nullptr, nullptr);
  }
}

extern "C" void kernel_launch(void* const* d_in, const int* in_sizes, int n_in,
                              void* d_out, int out_size, void* d_ws, size_t ws_size,
                              hipStream_t stream) {
  const float* user_emb = (const float*)d_in[0];
  const float* entity_emb = (const float*)d_in[1];
  const float* latent = (const float*)d_in[2];
  const float* weight = (const float*)d_in[3];
  const float* disen = (const float*)d_in[4];
  const float* kgW = (const float*)d_in[5];
  const float* ui_vals = (const float*)d_in[6];
  const int* edge_index = (const int*)d_in[7];
  const int* edge_type = (const int*)d_in[8];
  const int* ui_rows = (const int*)d_in[9];
  const int* ui_cols = (const int*)d_in[10];
  const int* head = edge_index;
  const int* tail = edge_index + N_EDGE;

  char* ws = (char*)d_ws;
  size_t o = 0;
  auto alloc = [&](size_t bytes) -> char* {
    char* p = ws + o;
    o += (bytes + 255) & ~(size_t)255;
    return p;
  };
  int* head_ptr = (int*)alloc((N_ENT + 1) * 4);
  int* ui_ptr = (int*)alloc((N_USR + 1) * 4);
  int* cnt_u = (int*)alloc((size_t)N_USR * 4);
  int* bsum_h = (int*)alloc(1024 * 4);
  int* bsum_u = (int*)alloc(64 * 4);
  int* packed = (int*)alloc((size_t)N_EDGE * 4);
  int2* cv = (int2*)alloc((size_t)N_EDGE * 8);
  float* mask_s = (float*)alloc((size_t)N_EDGE * 4);
  ushort_t* ent0bf = (ushort_t*)alloc((size_t)N_ENT * 64 * 2);
  ushort_t* ent1bf = (ushort_t*)alloc((size_t)N_ENT * 64 * 2);
  float* usr1 = (float*)alloc((size_t)N_USR * 64 * 4);
  int* cnt9 = (int*)alloc((size_t)B9 * 4);
  int* base9 = (int*)alloc((size_t)B9 * 4);
  int2* rank2 = (int2*)alloc((size_t)N_EDGE * 8);
  float* rel2t = (float*)alloc((size_t)N_ENT * 9 * 4);
  float4* sc4a = (float4*)alloc((size_t)N_USR * 16);
  float4* sc4b = (float4*)alloc((size_t)N_USR * 16);
  float* V = (float*)alloc(9 * 64 * 4);
  float* wsq = (float*)alloc(16 * 4);
  float* dw = (float*)alloc(4 * 64 * 4);
  if (o > ws_size) return;

  float* out_ent = (float*)d_out;
  float* out_usr = out_ent + (size_t)N_ENT * 64;
  float* out_cor = out_ent + (size_t)N_ENT * 64 + (size_t)N_USR * 64;

  hipMemsetAsync(cnt_u, 0, (size_t)N_USR * 4, stream);
  hipMemsetAsync(cnt9, 0, (size_t)B9 * 4, stream);

  // K1: bf16 convert + count+rank + prep + sc(user)
  k_pre<<<TB_BLOCKS + CNT_BLOCKS + 1 + SC_BLOCKS, 256, 0, stream>>>(
      entity_emb, ent0bf, head, ui_rows, edge_type, cnt_u, cnt9, rank2,
      weight, kgW, disen, V, wsq, dw, out_cor, user_emb, latent, sc4a);

  int nbh = (B9 + 1023) / 1024;       // 879
  int nbu = (N_USR + 1023) / 1024;    // 49
  // K2: fused scan-reduce over flat cnt9 | cnt_u
  k_scanred<<<nbh + nbu, 256, 0, stream>>>(cnt9, cnt_u, bsum_h, bsum_u, nbh);
  // K3: block-sum exclusive scans (+ sentinel ptr entries)
  k_scan_tops<<<1, 64, 0, stream>>>(bsum_h, nbh, bsum_u, nbu, head_ptr, N_ENT, ui_ptr, N_USR, N_EDGE);
  // K4: fused scan-final -> base9 + head_ptr | ui_ptr
  k_scanfin<<<nbh + nbu, 256, 0, stream>>>(cnt9, cnt_u, bsum_h, bsum_u,
                                           base9, head_ptr, ui_ptr, nbh);
  // K5: atomic-free build + rel2
  k_build_rel2<<<BUILD_BLOCKS + REL2_BLOCKS, 256, 0, stream>>>(
      head, tail, edge_type, ui_rows, ui_cols, ui_vals,
      base9, ui_ptr, rank2, packed, cv, ent0bf, V, wsq, cnt9, rel2t);

  // D1: mask + fused KG hop-1 + UI hop-1 (+ sc4b epilogue)
  k_mask_kg_ui<<<KG_BLOCKS + UI_BLOCKS, 256, 0, stream>>>(
      entity_emb, ent0bf, head_ptr, packed, rel2t, mask_s, weight,
      out_ent, ent1bf, sc4a, out_usr, usr1, ui_ptr, cv, user_emb, dw, latent, sc4b);

  // D2: KG hop-2 + UI hop-2
  k_hop2<<<KG_BLOCKS + UI_BLOCKS, 256, 0, stream>>>(
      ent1bf, out_ent, head_ptr, packed, mask_s, weight,
      usr1, out_usr, ui_ptr, cv, sc4b, dw);
}

// Round 6
// 566.945 us; speedup vs baseline: 1.0254x; 1.0148x over previous
//
#include <hip/hip_runtime.h>
#include <math.h>

#define N_ENT 100000
#define N_USR 50000
#define N_EDGE 1000000
#define B9 (N_ENT * 9)   // 900000 flat (ent,rel) buckets
#define TEMPC 0.2f
#define KG_BLOCKS (N_ENT / 4)   // 25000, exact
#define UI_BLOCKS (N_USR / 4)   // 12500, exact

// fused-kernel block ranges
#define TB_BLOCKS 6250   // ceil(N_ENT*64/4 / 256) : bf16 convert (float4 granules)
#define CNT_BLOCKS 489   // ceil(N_EDGE/8 / 256) : fire-and-forget count, 8 edges/thread
#define SC_BLOCKS 196    // ceil(N_USR / 256)
#define REL2_BLOCKS 391  // ceil(N_ENT / 256)

// counting-sort phases
#define BIN_BLOCKS 245   // ceil(N_EDGE / (1024*4))
#define NCK 391          // KG coarse buckets: head >> 8
#define NCU 196          // UI coarse buckets: user >> 8
#define FINEK_BLOCKS NCK
#define FINEU_BLOCKS NCU

#define WLS 68   // padded stride for weight rows in LDS

typedef unsigned short ushort_t;

__device__ __forceinline__ float waveReduceSum(float x) {
#pragma unroll
  for (int d = 32; d > 0; d >>= 1) x += __shfl_xor(x, d);
  return x;
}
__device__ __forceinline__ float waveReduceMax(float x) {
#pragma unroll
  for (int d = 32; d > 0; d >>= 1) x = fmaxf(x, __shfl_xor(x, d));
  return x;
}
__device__ __forceinline__ int waveReduceSumI(int x) {
#pragma unroll
  for (int d = 32; d > 0; d >>= 1) x += __shfl_xor(x, d);
  return x;
}
__device__ __forceinline__ float bf2f(unsigned int u16) {
  union { unsigned int i; float f; } v;
  v.i = u16 << 16;
  return v.f;
}
__device__ __forceinline__ ushort_t f2bf(float f) {
  union { unsigned int i; float f; } v;
  v.f = f;
  unsigned int u = v.i;
  u = (u + 0x7FFFu + ((u >> 16) & 1u)) >> 16;
  return (ushort_t)u;
}
// wave-uniform broadcast via v_readlane -> SGPR
__device__ __forceinline__ int rl(int v, int l) { return __builtin_amdgcn_readlane(v, l); }
__device__ __forceinline__ float rlf(float v, int l) {
  return __int_as_float(__builtin_amdgcn_readlane(__float_as_int(v), l));
}

// column-partial reduce over g (masks 8/16/32) + 8x8 wave transpose
__device__ __forceinline__ float colRT(float a0, float a1, float a2, float a3,
                                       float a4, float a5, float a6, float a7,
                                       int g, int part) {
#define RED3(x) x += __shfl_xor(x, 8); x += __shfl_xor(x, 16); x += __shfl_xor(x, 32);
  RED3(a0) RED3(a1) RED3(a2) RED3(a3) RED3(a4) RED3(a5) RED3(a6) RED3(a7)
#undef RED3
  float t0 = __shfl(a0, g), t1 = __shfl(a1, g), t2 = __shfl(a2, g), t3 = __shfl(a3, g);
  float t4 = __shfl(a4, g), t5 = __shfl(a5, g), t6 = __shfl(a6, g), t7 = __shfl(a7, g);
  float r = t0;
  r = (part == 1) ? t1 : r;
  r = (part == 2) ? t2 : r;
  r = (part == 3) ? t3 : r;
  r = (part == 4) ? t4 : r;
  r = (part == 5) ? t5 : r;
  r = (part == 6) ? t6 : r;
  r = (part == 7) ? t7 : r;
  return r;
}

// ============ K1: bf16 convert | f&f count (8/thr) | prep | sc(user) ============
__global__ void k_pre(const float* __restrict__ ent0, ushort_t* __restrict__ ent0bf,
                      const int* __restrict__ head, const int* __restrict__ uir,
                      const int* __restrict__ etype,
                      int* __restrict__ cnt_u, int* __restrict__ cnt9,
                      const float* __restrict__ weight, const float* __restrict__ kgW,
                      const float* __restrict__ disen,
                      float* __restrict__ V, float* __restrict__ wsq,
                      float* __restrict__ dw, float* __restrict__ cor_out,
                      const float* __restrict__ user_emb, const float* __restrict__ latent,
                      float4* __restrict__ sc4a) {
  int bid = blockIdx.x;
  if (bid < TB_BLOCKS) {
    int i = bid * 256 + threadIdx.x;
    if (i < N_ENT * 16) {
      float4 v = ((const float4*)ent0)[i];
      ushort4 o;
      o.x = f2bf(v.x); o.y = f2bf(v.y); o.z = f2bf(v.z); o.w = f2bf(v.w);
      ((ushort4*)ent0bf)[i] = o;
    }
  } else if (bid < TB_BLOCKS + CNT_BLOCKS) {
    // fire-and-forget counting only (no return values -> atomics pipeline freely)
    int i0 = ((bid - TB_BLOCKS) * 256 + threadIdx.x) * 8;
    if (i0 < N_EDGE) {
      int4 ha = *(const int4*)(head + i0), hb = *(const int4*)(head + i0 + 4);
      int4 ea = *(const int4*)(etype + i0), eb = *(const int4*)(etype + i0 + 4);
      int4 ua = *(const int4*)(uir + i0), ub = *(const int4*)(uir + i0 + 4);
      atomicAdd(&cnt9[ha.x * 9 + (ea.x - 1)], 1);
      atomicAdd(&cnt9[ha.y * 9 + (ea.y - 1)], 1);
      atomicAdd(&cnt9[ha.z * 9 + (ea.z - 1)], 1);
      atomicAdd(&cnt9[ha.w * 9 + (ea.w - 1)], 1);
      atomicAdd(&cnt9[hb.x * 9 + (eb.x - 1)], 1);
      atomicAdd(&cnt9[hb.y * 9 + (eb.y - 1)], 1);
      atomicAdd(&cnt9[hb.z * 9 + (eb.z - 1)], 1);
      atomicAdd(&cnt9[hb.w * 9 + (eb.w - 1)], 1);
      atomicAdd(&cnt_u[ua.x], 1);
      atomicAdd(&cnt_u[ua.y], 1);
      atomicAdd(&cnt_u[ua.z], 1);
      atomicAdd(&cnt_u[ua.w], 1);
      atomicAdd(&cnt_u[ub.x], 1);
      atomicAdd(&cnt_u[ub.y], 1);
      atomicAdd(&cnt_u[ub.z], 1);
      atomicAdd(&cnt_u[ub.w], 1);
    }
  } else if (bid == TB_BLOCKS + CNT_BLOCKS) {
    // ---- prep: V=(W W^T)w_r via T-factorization, wsq, dw, cor ----
    __shared__ float T[9 * 64];
    __shared__ float sm[4 * 9];
    int tid = threadIdx.x;
    for (int e = tid; e < 9 * 64; e += 256) {
      int r = e >> 6, d = e & 63;
      float s = 0.f;
      for (int k = 0; k < 64; ++k) s += kgW[k * 64 + d] * weight[r * 64 + k];
      T[e] = s;
    }
    if (tid < 4) {
      float m = -INFINITY;
      for (int r = 0; r < 9; ++r) m = fmaxf(m, disen[tid * 9 + r]);
      float den = 0.f;
      float ex[9];
      for (int r = 0; r < 9; ++r) { ex[r] = expf(disen[tid * 9 + r] - m); den += ex[r]; }
      for (int r = 0; r < 9; ++r) sm[tid * 9 + r] = ex[r] / den;
    }
    __syncthreads();
    for (int e = tid; e < 9 * 64; e += 256) {
      int r = e >> 6, i = e & 63;
      float s = 0.f;
      for (int d = 0; d < 64; ++d) s += kgW[i * 64 + d] * T[r * 64 + d];
      V[e] = s;
    }
    if (tid < 9) {
      float s = 0.f;
      for (int c = 0; c < 64; ++c) { float w = weight[tid * 64 + c]; s += w * w; }
      wsq[tid] = s;
    }
    for (int e = tid; e < 4 * 64; e += 256) {
      int f = e >> 6, c = e & 63;
      float s = 0.f;
      for (int r = 0; r < 9; ++r) s += sm[f * 9 + r] * weight[r * 64 + c];
      dw[e] = s;
    }
    if (tid == 0) {
      float rowsum[4];
      for (int f = 0; f < 4; ++f) {
        float s = 0.f;
        for (int j = 0; j < 9; ++j) s += disen[f * 9 + j];
        rowsum[f] = s;
      }
      float cor = 0.f;
      for (int i = 0; i < 9; ++i) {
        float n2 = 0.f, ttl = 0.f;
        for (int f = 0; f < 4; ++f) {
          float v = disen[f * 9 + i];
          n2 += v * v;
          ttl += v * rowsum[f];
        }
        float nrm = sqrtf(n2);
        float pos = 0.f;
        for (int f = 0; f < 4; ++f) {
          float v = disen[f * 9 + i] / nrm;
          pos += v * v;
        }
        cor += (ttl - pos) / TEMPC;
      }
      *cor_out = cor;
    }
  } else {
    // ---- sc on user_emb -> sc4a ----
    __shared__ __align__(16) float lat[256];
    if (threadIdx.x < 256) lat[threadIdx.x] = latent[threadIdx.x];
    __syncthreads();
    int u = (bid - TB_BLOCKS - CNT_BLOCKS - 1) * 256 + threadIdx.x;
    if (u >= N_USR) return;
    float a0 = 0.f, a1 = 0.f, a2 = 0.f, a3 = 0.f;
    const float4* row = (const float4*)(user_emb + (size_t)u * 64);
#pragma unroll
    for (int q = 0; q < 16; ++q) {
      float4 v = row[q];
      float4 l0 = *(const float4*)(lat + 0 * 64 + q * 4);
      float4 l1 = *(const float4*)(lat + 1 * 64 + q * 4);
      float4 l2 = *(const float4*)(lat + 2 * 64 + q * 4);
      float4 l3 = *(const float4*)(lat + 3 * 64 + q * 4);
      a0 = fmaf(v.x, l0.x, a0); a0 = fmaf(v.y, l0.y, a0); a0 = fmaf(v.z, l0.z, a0); a0 = fmaf(v.w, l0.w, a0);
      a1 = fmaf(v.x, l1.x, a1); a1 = fmaf(v.y, l1.y, a1); a1 = fmaf(v.z, l1.z, a1); a1 = fmaf(v.w, l1.w, a1);
      a2 = fmaf(v.x, l2.x, a2); a2 = fmaf(v.y, l2.y, a2); a2 = fmaf(v.z, l2.z, a2); a2 = fmaf(v.w, l2.w, a2);
      a3 = fmaf(v.x, l3.x, a3); a3 = fmaf(v.y, l3.y, a3); a3 = fmaf(v.z, l3.z, a3); a3 = fmaf(v.w, l3.w, a3);
    }
    sc4a[u] = make_float4(a0, a1, a2, a3);
  }
}

// ============ K2: fused scan-reduce (flat cnt9 | cnt_u) ============
__global__ void k_scanred(const int* __restrict__ cnt9, const int* __restrict__ cnt_u,
                          int* __restrict__ bsum_h, int* __restrict__ bsum_u, int nbh) {
  int b = blockIdx.x, tid = threadIdx.x;
  int s = 0;
  if (b < nbh) {
    int i0 = b * 1024 + tid * 4;
#pragma unroll
    for (int k = 0; k < 4; ++k)
      if (i0 + k < B9) s += cnt9[i0 + k];
  } else {
    int i0 = (b - nbh) * 1024 + tid * 4;
#pragma unroll
    for (int k = 0; k < 4; ++k)
      if (i0 + k < N_USR) s += cnt_u[i0 + k];
  }
  s = waveReduceSumI(s);
  __shared__ int l[4];
  int lane = tid & 63, wid = tid >> 6;
  if (lane == 0) l[wid] = s;
  __syncthreads();
  if (tid == 0) {
    int v = l[0] + l[1] + l[2] + l[3];
    if (b < nbh) bsum_h[b] = v; else bsum_u[b - nbh] = v;
  }
}

__global__ void k_scan_tops(int* bsA, int nA, int* bsB, int nB,
                            int* ptrA, int NA, int* ptrB, int NB, int total) {
  if (threadIdx.x == 0) {
    int a = 0;
    for (int i = 0; i < nA; ++i) { int t = bsA[i]; bsA[i] = a; a += t; }
    ptrA[NA] = total;
  }
  if (threadIdx.x == 1) {
    int a = 0;
    for (int i = 0; i < nB; ++i) { int t = bsB[i]; bsB[i] = a; a += t; }
    ptrB[NB] = total;
  }
}

// ============ K4: scan-final -> base9 + head_ptr + coarse cursors | ui_ptr ============
__global__ void k_scanfin(const int* __restrict__ cnt9, const int* __restrict__ cnt_u,
                          const int* __restrict__ bsum_h, const int* __restrict__ bsum_u,
                          int* __restrict__ base9, int* __restrict__ head_ptr,
                          int* __restrict__ ui_ptr,
                          int* __restrict__ coarse_kg_cur, int* __restrict__ coarse_ui_cur,
                          int nbh) {
  int b = blockIdx.x, tid = threadIdx.x;
  bool isH = (b < nbh);
  int bl = isH ? b : b - nbh;
  int n = isH ? B9 : N_USR;
  int i0 = bl * 1024 + tid * 4;
  int s = 0;
  int loc[4];
#pragma unroll
  for (int k = 0; k < 4; ++k) {
    int v = 0;
    if (i0 + k < n) v = isH ? cnt9[i0 + k] : cnt_u[i0 + k];
    loc[k] = s;
    s += v;
  }
  int lane = tid & 63, wid = tid >> 6;
  int x = s;
#pragma unroll
  for (int d = 1; d < 64; d <<= 1) {
    int y = __shfl_up(x, d);
    if (lane >= d) x += y;
  }
  __shared__ int l[4];
  if (lane == 63) l[wid] = x;
  __syncthreads();
  if (tid == 0) {
    int a = 0;
    for (int w = 0; w < 4; ++w) { int t = l[w]; l[w] = a; a += t; }
  }
  __syncthreads();
  int excl = x - s + l[wid] + (isH ? bsum_h[bl] : bsum_u[bl]);
#pragma unroll
  for (int k = 0; k < 4; ++k) {
    int idx = i0 + k;
    if (idx < n) {
      int v = excl + loc[k];
      if (isH) {
        base9[idx] = v;
        int ent = idx / 9;
        if (idx - ent * 9 == 0) {
          head_ptr[ent] = v;
          if ((ent & 255) == 0) coarse_kg_cur[ent >> 8] = v;  // coarse bucket start
        }
      } else {
        ui_ptr[idx] = v;
        if ((idx & 255) == 0) coarse_ui_cur[idx >> 8] = v;
      }
    }
  }
}

// ============ K5a: coarse binning (block-level reservations, NO per-edge return-atomics) ============
__global__ void __launch_bounds__(1024) k_bin(
    const int* __restrict__ head, const int* __restrict__ tail,
    const int* __restrict__ etype,
    const int* __restrict__ uir, const int* __restrict__ uic,
    const float* __restrict__ uival,
    int* __restrict__ coarse_kg_cur, int* __restrict__ coarse_ui_cur,
    unsigned int* __restrict__ stage_kg, int2* __restrict__ stage_ui) {
  __shared__ int histK[NCK], histU[NCU];
  int tid = threadIdx.x;
  for (int i = tid; i < NCK; i += 1024) histK[i] = 0;
  for (int i = tid; i < NCU; i += 1024) histU[i] = 0;
  __syncthreads();
  int i0 = (blockIdx.x * 1024 + tid) * 4;
  bool valid = (i0 < N_EDGE);
  int4 h4, t4v, e4, r4, c4;
  float4 v4;
  int k0 = 0, k1 = 0, k2 = 0, k3 = 0, u0 = 0, u1 = 0, u2 = 0, u3 = 0;
  if (valid) {
    h4 = *(const int4*)(head + i0);
    t4v = *(const int4*)(tail + i0);
    e4 = *(const int4*)(etype + i0);
    r4 = *(const int4*)(uir + i0);
    c4 = *(const int4*)(uic + i0);
    v4 = *(const float4*)(uival + i0);
    // local ranks via LDS atomics (cheap, block-local)
    k0 = atomicAdd(&histK[h4.x >> 8], 1);
    k1 = atomicAdd(&histK[h4.y >> 8], 1);
    k2 = atomicAdd(&histK[h4.z >> 8], 1);
    k3 = atomicAdd(&histK[h4.w >> 8], 1);
    u0 = atomicAdd(&histU[r4.x >> 8], 1);
    u1 = atomicAdd(&histU[r4.y >> 8], 1);
    u2 = atomicAdd(&histU[r4.z >> 8], 1);
    u3 = atomicAdd(&histU[r4.w >> 8], 1);
  }
  __syncthreads();
  // block-level reservation: ONE global return-atomic per (block, nonempty bucket)
  if (tid < NCK) {
    int c = histK[tid];
    histK[tid] = (c > 0) ? atomicAdd(&coarse_kg_cur[tid], c) : 0;
  } else if (tid >= 512 && tid < 512 + NCU) {
    int bu = tid - 512;
    int c = histU[bu];
    histU[bu] = (c > 0) ? atomicAdd(&coarse_ui_cur[bu], c) : 0;
  }
  __syncthreads();
  if (valid) {
    // staged KG word: tail(0:19) | rel(20:23) | head&255(24:31)
    stage_kg[histK[h4.x >> 8] + k0] =
        (unsigned int)(t4v.x | ((e4.x - 1) << 20) | ((h4.x & 255) << 24));
    stage_kg[histK[h4.y >> 8] + k1] =
        (unsigned int)(t4v.y | ((e4.y - 1) << 20) | ((h4.y & 255) << 24));
    stage_kg[histK[h4.z >> 8] + k2] =
        (unsigned int)(t4v.z | ((e4.z - 1) << 20) | ((h4.z & 255) << 24));
    stage_kg[histK[h4.w >> 8] + k3] =
        (unsigned int)(t4v.w | ((e4.w - 1) << 20) | ((h4.w & 255) << 24));
    // staged UI: {col(0:23) | user&255(24:31), val}
    stage_ui[histU[r4.x >> 8] + u0] = make_int2(c4.x | ((r4.x & 255) << 24), __float_as_int(v4.x));
    stage_ui[histU[r4.y >> 8] + u1] = make_int2(c4.y | ((r4.y & 255) << 24), __float_as_int(v4.y));
    stage_ui[histU[r4.z >> 8] + u2] = make_int2(c4.z | ((r4.z & 255) << 24), __float_as_int(v4.z));
    stage_ui[histU[r4.w >> 8] + u3] = make_int2(c4.w | ((r4.w & 255) << 24), __float_as_int(v4.w));
  }
}

// ============ K5b: fine placement within coarse buckets (LDS ranks, region-local stores) | rel2 ============
__global__ void k_fine_rel2(const unsigned int* __restrict__ stage_kg,
                            const int2* __restrict__ stage_ui,
                            const int* __restrict__ base9, const int* __restrict__ ui_ptr,
                            int* __restrict__ packed, int2* __restrict__ cv,
                            const ushort_t* __restrict__ ent0bf, const float* __restrict__ V,
                            const float* __restrict__ wsq, const int* __restrict__ cnt9,
                            float* __restrict__ rel2t) {
  int tid = threadIdx.x;
  if (blockIdx.x < FINEK_BLOCKS) {
    int b = blockIdx.x;
    __shared__ int lbase[2304];  // 256 heads x 9 rels
    __shared__ int lcnt[2304];
    int gb = (b << 8) * 9;
    for (int i = tid; i < 2304; i += 256) {
      int gi = gb + i;
      lbase[i] = (gi < B9) ? base9[gi] : N_EDGE;
      lcnt[i] = 0;
    }
    __syncthreads();
    int start = base9[gb];
    int end = (b < FINEK_BLOCKS - 1) ? base9[gb + 2304] : N_EDGE;
    for (int i = start + tid; i < end; i += 256) {
      unsigned int w = stage_kg[i];
      int key = (int)((w >> 24) & 255u) * 9 + (int)((w >> 20) & 15u);
      int r = atomicAdd(&lcnt[key], 1);
      packed[lbase[key] + r] = (int)(w & 0xFFFFFFu);  // tail | rel<<20
    }
  } else if (blockIdx.x < FINEK_BLOCKS + FINEU_BLOCKS) {
    int b = blockIdx.x - FINEK_BLOCKS;
    __shared__ int lbu[256];
    __shared__ int lcu[256];
    int gb = b << 8;
    lbu[tid] = (gb + tid < N_USR) ? ui_ptr[gb + tid] : N_EDGE;
    lcu[tid] = 0;
    __syncthreads();
    int start = ui_ptr[gb];
    int nxt = gb + 256;
    int end = ui_ptr[(nxt < N_USR) ? nxt : N_USR];  // ui_ptr[N_USR] = N_EDGE sentinel
    for (int i = start + tid; i < end; i += 256) {
      int2 d = stage_ui[i];
      int key = (d.x >> 24) & 255;
      int r = atomicAdd(&lcu[key], 1);
      cv[lbu[key] + r] = make_int2(d.x & 0xFFFFFF, d.y);
    }
  } else {
    // ---- rel2: dense per-entity relation softmax table ----
    __shared__ __align__(16) float Vl[576];
    __shared__ float wsql[9];
    for (int i = tid; i < 576; i += 256) Vl[i] = V[i];
    if (tid < 9) wsql[tid] = wsq[tid];
    __syncthreads();
    int ent = (blockIdx.x - FINEK_BLOCKS - FINEU_BLOCKS) * 256 + tid;
    if (ent >= N_ENT) return;
    float a[9] = {0, 0, 0, 0, 0, 0, 0, 0, 0};
    const uint4* row = (const uint4*)(ent0bf + (ent << 6));
#pragma unroll
    for (int q = 0; q < 8; ++q) {
      uint4 b = row[q];
      float ch0 = bf2f(b.x & 0xFFFFu), ch1 = bf2f(b.x >> 16);
      float ch2 = bf2f(b.y & 0xFFFFu), ch3 = bf2f(b.y >> 16);
      float ch4 = bf2f(b.z & 0xFFFFu), ch5 = bf2f(b.z >> 16);
      float ch6 = bf2f(b.w & 0xFFFFu), ch7 = bf2f(b.w >> 16);
#pragma unroll
      for (int r = 0; r < 9; ++r) {
        const float4* vp = (const float4*)(Vl + r * 64 + q * 8);
        float4 v0 = vp[0], v1 = vp[1];
        float t = a[r];
        t = fmaf(ch0, v0.x, t); t = fmaf(ch1, v0.y, t);
        t = fmaf(ch2, v0.z, t); t = fmaf(ch3, v0.w, t);
        t = fmaf(ch4, v1.x, t); t = fmaf(ch5, v1.y, t);
        t = fmaf(ch6, v1.z, t); t = fmaf(ch7, v1.w, t);
        a[r] = t;
      }
    }
    const float inv2s = 0.08838834764831845f;  // 1/(2*sqrt(32))
    int cnt[9];
#pragma unroll
    for (int r = 0; r < 9; ++r) cnt[r] = cnt9[ent * 9 + r];
    float m1 = -INFINITY;
#pragma unroll
    for (int r = 0; r < 9; ++r)
      if (cnt[r] > 0) m1 = fmaxf(m1, a[r] * inv2s);
    if (m1 == -INFINITY) {
#pragma unroll
      for (int r = 0; r < 9; ++r) rel2t[ent * 9 + r] = 0.f;
      return;
    }
    float den1 = 1e-16f;
#pragma unroll
    for (int r = 0; r < 9; ++r)
      if (cnt[r] > 0) den1 += (float)cnt[r] * expf(a[r] * inv2s - m1);
#pragma unroll
    for (int r = 0; r < 9; ++r) {
      float rs = expf(a[r] * inv2s - m1) / den1;
      rel2t[ent * 9 + r] = rs * rs * wsql[r];
    }
  }
}

// KG aggregation inner (readlane broadcasts, 4 acc chains) — generic fallback
__device__ __forceinline__ float kg_agg64(int deg, int lane, int pk, float mk,
                                          const ushort_t* __restrict__ srcbf,
                                          const float* __restrict__ wl) {
  float a0 = 0.f, a1 = 0.f, a2 = 0.f, a3 = 0.f;
  int j = 0;
  for (; j + 4 <= deg; j += 4) {
    int p0 = rl(pk, j), p1 = rl(pk, j + 1), p2 = rl(pk, j + 2), p3 = rl(pk, j + 3);
    float k0 = rlf(mk, j), k1 = rlf(mk, j + 1), k2 = rlf(mk, j + 2), k3 = rlf(mk, j + 3);
    float r0 = bf2f(srcbf[((p0 & 0xFFFFF) << 6) + lane]);
    float r1 = bf2f(srcbf[((p1 & 0xFFFFF) << 6) + lane]);
    float r2 = bf2f(srcbf[((p2 & 0xFFFFF) << 6) + lane]);
    float r3 = bf2f(srcbf[((p3 & 0xFFFFF) << 6) + lane]);
    a0 = fmaf(r0 * wl[((p0 >> 20) & 15) * WLS + lane], k0, a0);
    a1 = fmaf(r1 * wl[((p1 >> 20) & 15) * WLS + lane], k1, a1);
    a2 = fmaf(r2 * wl[((p2 >> 20) & 15) * WLS + lane], k2, a2);
    a3 = fmaf(r3 * wl[((p3 >> 20) & 15) * WLS + lane], k3, a3);
  }
  for (; j < deg; ++j) {
    int pj = rl(pk, j);
    float kj = rlf(mk, j);
    a0 = fmaf(bf2f(srcbf[((pj & 0xFFFFF) << 6) + lane]) * wl[((pj >> 20) & 15) * WLS + lane], kj, a0);
  }
  return (a0 + a1) + (a2 + a3);
}

// ---------------- UI aggregation body (group-layout single-pass) ----------------
__device__ __forceinline__ void ui_body(int usr, int lane,
                                        const ushort_t* __restrict__ srcbf,
                                        const float4* __restrict__ sc4,
                                        const float* __restrict__ addb,
                                        float* __restrict__ outp, float* __restrict__ nxt,
                                        const int* __restrict__ uptr,
                                        const int2* __restrict__ cv,
                                        const float* __restrict__ dwl,
                                        const float* __restrict__ latl,
                                        float4* __restrict__ sc4out) {
  float4 s4 = sc4[usr];
  float m = fmaxf(fmaxf(s4.x, s4.y), fmaxf(s4.z, s4.w));
  float e0 = expf(s4.x - m), e1 = expf(s4.y - m), e2 = expf(s4.z - m), e3 = expf(s4.w - m);
  float den = e0 + e1 + e2 + e3;
  float mix = (e0 * dwl[lane] + e1 * dwl[64 + lane] + e2 * dwl[128 + lane] + e3 * dwl[192 + lane]) / den;
  int s = uptr[usr], e = uptr[usr + 1];
  int g = lane >> 3, part = lane & 7;
  float a0 = 0.f, a1 = 0.f, a2 = 0.f, a3 = 0.f;
  float a4 = 0.f, a5 = 0.f, a6 = 0.f, a7 = 0.f;
  for (int base = s; base < e; base += 64) {
    int c = min(64, e - base);
    int2 cvl = (lane < c) ? cv[base + lane] : make_int2(0, 0);
    int cl = cvl.x;
    float vl = __int_as_float(cvl.y);
    int nch = (c + 7) >> 3;
#pragma unroll
    for (int cc = 0; cc < 8; ++cc) {
      if (cc < nch) {
        int j = (cc << 3) + g;
        int cj = __shfl(cl, j);       // inactive rows broadcast 0 -> row 0, vj=0
        float vj = __shfl(vl, j);
        uint4 b = *((const uint4*)(srcbf + ((size_t)cj << 6)) + part);
        a0 = fmaf(bf2f(b.x & 0xFFFFu), vj, a0);
        a1 = fmaf(bf2f(b.x >> 16), vj, a1);
        a2 = fmaf(bf2f(b.y & 0xFFFFu), vj, a2);
        a3 = fmaf(bf2f(b.y >> 16), vj, a3);
        a4 = fmaf(bf2f(b.z & 0xFFFFu), vj, a4);
        a5 = fmaf(bf2f(b.z >> 16), vj, a5);
        a6 = fmaf(bf2f(b.w & 0xFFFFu), vj, a6);
        a7 = fmaf(bf2f(b.w >> 16), vj, a7);
      }
    }
  }
  float acc = colRT(a0, a1, a2, a3, a4, a5, a6, a7, g, part);
  float ua = acc * mix + acc;
  float nrm = sqrtf(waveReduceSum(ua * ua));
  float val = ua / fmaxf(nrm, 1e-12f);
  size_t o = (size_t)usr * 64 + lane;
  if (nxt) nxt[o] = val;
  outp[o] = addb[o] + val;
  if (sc4out) {
    // fused hop-2 factor scores: sc4b[usr] = val @ latent^T
    float s0 = waveReduceSum(val * latl[lane]);
    float s1 = waveReduceSum(val * latl[64 + lane]);
    float s2 = waveReduceSum(val * latl[128 + lane]);
    float s3 = waveReduceSum(val * latl[192 + lane]);
    if (lane == 0) sc4out[usr] = make_float4(s0, s1, s2, s3);
  }
}

// ---------------- D1: mask + fused KG hop-1  |  UI hop-1 (+sc4b) ----------------
__global__ void k_mask_kg_ui(const float* __restrict__ ent0,
                             const ushort_t* __restrict__ ent0bf,
                             const int* __restrict__ hptr, const int* __restrict__ packed,
                             const float* __restrict__ rel2t,
                             float* __restrict__ mask_s, const float* __restrict__ weight,
                             float* __restrict__ out_ent, ushort_t* __restrict__ ent1bf,
                             const float4* __restrict__ sc4,
                             float* __restrict__ out_usr,
                             float* __restrict__ usr1, const int* __restrict__ uptr,
                             const int2* __restrict__ cv,
                             const float* __restrict__ user_emb, const float* __restrict__ dw,
                             const float* __restrict__ latent, float4* __restrict__ sc4b) {
  int lane = threadIdx.x & 63, wid = threadIdx.x >> 6;
  if (blockIdx.x < KG_BLOCKS) {
    __shared__ __align__(16) float sh_eh[4][64];
    __shared__ __align__(16) float wl[9 * WLS];
    for (int i = threadIdx.x; i < 576; i += 256) wl[(i >> 6) * WLS + (i & 63)] = weight[i];
    int ent = blockIdx.x * 4 + wid;  // always < N_ENT
    int s = hptr[ent], e = hptr[ent + 1];
    float eh = ent0[(size_t)ent * 64 + lane];
    sh_eh[wid][lane] = eh;
    __syncthreads();
    size_t o = (size_t)ent * 64 + lane;
    int deg = e - s;
    if (deg == 0) {
      ent1bf[o] = f2bf(0.f);
      out_ent[o] = eh;
      return;
    }
    if (deg <= 64) {
      // ---- single-pass hot path: group-layout dot + DIRECT-EXP softmax. ----
      int pk = (lane < deg) ? packed[s + lane] : 0;
      int tb = (pk >> 20) & 15;
      float r2sel = rel2t[ent * 9 + ((lane < deg) ? tb : 0)];
      int g = lane >> 3, part = lane & 7;
      const float4* ehq = (const float4*)(sh_eh[wid] + (part << 3));
      float4 ef0 = ehq[0], ef1 = ehq[1];
      int nch = (deg + 7) >> 3;
      float den = 0.f;
      float acc0 = 0.f, acc1 = 0.f, acc2 = 0.f, acc3 = 0.f;
      float acc4 = 0.f, acc5 = 0.f, acc6 = 0.f, acc7 = 0.f;
      float ws8[8];
#pragma unroll
      for (int cc = 0; cc < 8; ++cc) {
        ws8[cc] = 0.f;
        if (cc < nch) {
          int j = (cc << 3) + g;  // row handled by this lane's group slot
          int pkj = __shfl(pk, j);  // inactive rows broadcast pk=0 -> row 0 (safe)
          uint4 b = *((const uint4*)(ent0bf + ((size_t)(pkj & 0xFFFFF) << 6)) + part);
          float r0 = bf2f(b.x & 0xFFFFu), r1 = bf2f(b.x >> 16);
          float r2 = bf2f(b.y & 0xFFFFu), r3 = bf2f(b.y >> 16);
          float r4 = bf2f(b.z & 0xFFFFu), r5 = bf2f(b.z >> 16);
          float r6 = bf2f(b.w & 0xFFFFu), r7 = bf2f(b.w >> 16);
          // partial dot over this lane's 8 columns, reduce over part (masks 1,2,4)
          float s0 = r0 * ef0.x, s1 = r2 * ef0.z, s2 = r4 * ef1.x, s3 = r6 * ef1.z;
          s0 = fmaf(r1, ef0.y, s0); s1 = fmaf(r3, ef0.w, s1);
          s2 = fmaf(r5, ef1.y, s2); s3 = fmaf(r7, ef1.w, s3);
          float sv = (s0 + s1) + (s2 + s3);
          sv += __shfl_xor(sv, 1);
          sv += __shfl_xor(sv, 2);
          sv += __shfl_xor(sv, 4);
          float r2j = __shfl(r2sel, j);
          float w = (j < deg) ? expf(sv + r2j) : 0.f;
          ws8[cc] = w;
          den += w;
          // weighted row accumulate into this lane's 8 columns
          const float4* wp = (const float4*)(wl + ((pkj >> 20) & 15) * WLS + (part << 3));
          float4 w0 = wp[0], w1 = wp[1];
          acc0 = fmaf(w * r0, w0.x, acc0);
          acc1 = fmaf(w * r1, w0.y, acc1);
          acc2 = fmaf(w * r2, w0.z, acc2);
          acc3 = fmaf(w * r3, w0.w, acc3);
          acc4 = fmaf(w * r4, w1.x, acc4);
          acc5 = fmaf(w * r5, w1.y, acc5);
          acc6 = fmaf(w * r6, w1.z, acc6);
          acc7 = fmaf(w * r7, w1.w, acc7);
        }
      }
      // full softmax denominator (sum over g: each row counted once per part-octet)
      float den2 = den;
      den2 += __shfl_xor(den2, 8);
      den2 += __shfl_xor(den2, 16);
      den2 += __shfl_xor(den2, 32);
      den2 += 1e-16f;
      float invden = 1.0f / den2;
      // write mask_s (per-chunk: lanes with part==0 write their group's row)
#pragma unroll
      for (int cc = 0; cc < 8; ++cc) {
        if (cc < nch) {
          int j = (cc << 3) + g;
          if (part == 0 && j < deg) mask_s[s + j] = ws8[cc] * invden;
        }
      }
      float aggv = colRT(acc0, acc1, acc2, acc3, acc4, acc5, acc6, acc7, g, part);
      float agg = aggv * invden / (float)deg;
      float nrm = sqrtf(waveReduceSum(agg * agg));
      float val = agg / fmaxf(nrm, 1e-12f);
      ent1bf[o] = f2bf(val);
      out_ent[o] = eh + val;
    } else {
      // ---- generic multi-chunk path (deg>64) ----
      float m2l = -INFINITY;
      for (int base = s; base < e; base += 64) {
        int c = min(64, e - base);
        int pk = (lane < c) ? packed[base + lane] : 0;
        int tb = (pk >> 20) & 15;
        float r2 = rel2t[ent * 9 + ((lane < c) ? tb : 0)];
        int tl = pk & 0xFFFFF;
        const uint4* row = (const uint4*)(ent0bf + (tl << 6));
        const float* ehp = sh_eh[wid];
        float d = 0.f;
#pragma unroll
        for (int q = 0; q < 8; ++q) {
          uint4 a = row[q];
          d += bf2f(a.x & 0xFFFF) * ehp[q * 8 + 0] + bf2f(a.x >> 16) * ehp[q * 8 + 1];
          d += bf2f(a.y & 0xFFFF) * ehp[q * 8 + 2] + bf2f(a.y >> 16) * ehp[q * 8 + 3];
          d += bf2f(a.z & 0xFFFF) * ehp[q * 8 + 4] + bf2f(a.z >> 16) * ehp[q * 8 + 5];
          d += bf2f(a.w & 0xFFFF) * ehp[q * 8 + 6] + bf2f(a.w >> 16) * ehp[q * 8 + 7];
        }
        float trip = d + r2;
        if (lane < c) {
          mask_s[base + lane] = trip;
          m2l = fmaxf(m2l, trip);
        }
      }
      float m2 = waveReduceMax(m2l);
      float denl = 0.f;
      for (int base = s; base < e; base += 64) {
        int c = min(64, e - base);
        denl += (lane < c) ? expf(mask_s[base + lane] - m2) : 0.f;
      }
      float den2 = waveReduceSum(denl) + 1e-16f;
      float acc = 0.f;
      for (int base = s; base < e; base += 64) {
        int c = min(64, e - base);
        int pk = (lane < c) ? packed[base + lane] : 0;
        float mk = 0.f;
        if (lane < c) {
          mk = expf(mask_s[base + lane] - m2) / den2;
          mask_s[base + lane] = mk;
        }
        acc += kg_agg64(c, lane, pk, mk, ent0bf, wl);
      }
      float agg = acc / (float)deg;
      float nrm = sqrtf(waveReduceSum(agg * agg));
      float val = agg / fmaxf(nrm, 1e-12f);
      ent1bf[o] = f2bf(val);
      out_ent[o] = eh + val;
    }
  } else {
    __shared__ float dwl[256];
    __shared__ float latl[256];
    if (threadIdx.x < 256) {
      dwl[threadIdx.x] = dw[threadIdx.x];
      latl[threadIdx.x] = latent[threadIdx.x];
    }
    __syncthreads();
    int usr = (blockIdx.x - KG_BLOCKS) * 4 + wid;  // always < N_USR
    ui_body(usr, lane, ent0bf, sc4, user_emb, out_usr, usr1,
            uptr, cv, dwl, latl, sc4b);
  }
}

// ---------------- D2: KG hop-2 + UI hop-2 (group-layout single-pass) ----------------
__global__ void k_hop2(const ushort_t* __restrict__ srcbf,
                       float* __restrict__ out_ent,
                       const int* __restrict__ hptr, const int* __restrict__ packed,
                       const float* __restrict__ mask_s, const float* __restrict__ weight,
                       const float* __restrict__ usr1, float* __restrict__ out_usr,
                       const int* __restrict__ uptr, const int2* __restrict__ cv,
                       const float4* __restrict__ sc4,
                       const float* __restrict__ dw) {
  int lane = threadIdx.x & 63, wid = threadIdx.x >> 6;
  if (blockIdx.x < KG_BLOCKS) {
    __shared__ __align__(16) float wl[9 * WLS];
    for (int i = threadIdx.x; i < 576; i += 256) wl[(i >> 6) * WLS + (i & 63)] = weight[i];
    __syncthreads();
    int ent = blockIdx.x * 4 + wid;
    int s = hptr[ent], e = hptr[ent + 1];
    int g = lane >> 3, part = lane & 7;
    float a0 = 0.f, a1 = 0.f, a2 = 0.f, a3 = 0.f;
    float a4 = 0.f, a5 = 0.f, a6 = 0.f, a7 = 0.f;
    for (int base = s; base < e; base += 64) {
      int c = min(64, e - base);
      int pk = (lane < c) ? packed[base + lane] : 0;
      float mk = (lane < c) ? mask_s[base + lane] : 0.f;
      int nch = (c + 7) >> 3;
#pragma unroll
      for (int cc = 0; cc < 8; ++cc) {
        if (cc < nch) {
          int j = (cc << 3) + g;
          int pkj = __shfl(pk, j);    // inactive rows: pk=0 -> row 0, mkj=0
          float mkj = __shfl(mk, j);
          uint4 b = *((const uint4*)(srcbf + ((size_t)(pkj & 0xFFFFF) << 6)) + part);
          float r0 = bf2f(b.x & 0xFFFFu), r1 = bf2f(b.x >> 16);
          float r2 = bf2f(b.y & 0xFFFFu), r3 = bf2f(b.y >> 16);
          float r4 = bf2f(b.z & 0xFFFFu), r5 = bf2f(b.z >> 16);
          float r6 = bf2f(b.w & 0xFFFFu), r7 = bf2f(b.w >> 16);
          const float4* wp = (const float4*)(wl + ((pkj >> 20) & 15) * WLS + (part << 3));
          float4 w0 = wp[0], w1 = wp[1];
          a0 = fmaf(mkj * r0, w0.x, a0);
          a1 = fmaf(mkj * r1, w0.y, a1);
          a2 = fmaf(mkj * r2, w0.z, a2);
          a3 = fmaf(mkj * r3, w0.w, a3);
          a4 = fmaf(mkj * r4, w1.x, a4);
          a5 = fmaf(mkj * r5, w1.y, a5);
          a6 = fmaf(mkj * r6, w1.z, a6);
          a7 = fmaf(mkj * r7, w1.w, a7);
        }
      }
    }
    float aggv = colRT(a0, a1, a2, a3, a4, a5, a6, a7, g, part);
    float n = (float)(e - s);
    float agg = aggv / fmaxf(n, 1.0f);
    float nrm = sqrtf(waveReduceSum(agg * agg));
    float val = agg / fmaxf(nrm, 1e-12f);
    size_t o = (size_t)ent * 64 + lane;
    out_ent[o] = out_ent[o] + val;
  } else {
    __shared__ float dwl[256];
    if (threadIdx.x < 256) dwl[threadIdx.x] = dw[threadIdx.x];
    __syncthreads();
    int usr = (blockIdx.x - KG_BLOCKS) * 4 + wid;
    ui_body(usr, lane, srcbf, sc4, out_usr, out_usr, nullptr,
            uptr, cv, dwl, nullptr, nullptr);
  }
}

extern "C" void kernel_launch(void* const* d_in, const int* in_sizes, int n_in,
                              void* d_out, int out_size, void* d_ws, size_t ws_size,
                              hipStream_t stream) {
  const float* user_emb = (const float*)d_in[0];
  const float* entity_emb = (const float*)d_in[1];
  const float* latent = (const float*)d_in[2];
  const float* weight = (const float*)d_in[3];
  const float* disen = (const float*)d_in[4];
  const float* kgW = (const float*)d_in[5];
  const float* ui_vals = (const float*)d_in[6];
  const int* edge_index = (const int*)d_in[7];
  const int* edge_type = (const int*)d_in[8];
  const int* ui_rows = (const int*)d_in[9];
  const int* ui_cols = (const int*)d_in[10];
  const int* head = edge_index;
  const int* tail = edge_index + N_EDGE;

  char* ws = (char*)d_ws;
  size_t o = 0;
  auto alloc = [&](size_t bytes) -> char* {
    char* p = ws + o;
    o += (bytes + 255) & ~(size_t)255;
    return p;
  };
  int* head_ptr = (int*)alloc((N_ENT + 1) * 4);
  int* ui_ptr = (int*)alloc((N_USR + 1) * 4);
  int* cnt_u = (int*)alloc((size_t)N_USR * 4);
  int* bsum_h = (int*)alloc(1024 * 4);
  int* bsum_u = (int*)alloc(64 * 4);
  int* packed = (int*)alloc((size_t)N_EDGE * 4);
  int2* cv = (int2*)alloc((size_t)N_EDGE * 8);
  float* mask_s = (float*)alloc((size_t)N_EDGE * 4);
  ushort_t* ent0bf = (ushort_t*)alloc((size_t)N_ENT * 64 * 2);
  ushort_t* ent1bf = (ushort_t*)alloc((size_t)N_ENT * 64 * 2);
  float* usr1 = (float*)alloc((size_t)N_USR * 64 * 4);
  int* cnt9 = (int*)alloc((size_t)B9 * 4);
  int* base9 = (int*)alloc((size_t)B9 * 4);
  unsigned int* stage_kg = (unsigned int*)alloc((size_t)N_EDGE * 4);
  int2* stage_ui = (int2*)alloc((size_t)N_EDGE * 8);
  int* coarse_kg_cur = (int*)alloc(NCK * 4);
  int* coarse_ui_cur = (int*)alloc(NCU * 4);
  float* rel2t = (float*)alloc((size_t)N_ENT * 9 * 4);
  float4* sc4a = (float4*)alloc((size_t)N_USR * 16);
  float4* sc4b = (float4*)alloc((size_t)N_USR * 16);
  float* V = (float*)alloc(9 * 64 * 4);
  float* wsq = (float*)alloc(16 * 4);
  float* dw = (float*)alloc(4 * 64 * 4);
  if (o > ws_size) return;

  float* out_ent = (float*)d_out;
  float* out_usr = out_ent + (size_t)N_ENT * 64;
  float* out_cor = out_ent + (size_t)N_ENT * 64 + (size_t)N_USR * 64;

  hipMemsetAsync(cnt_u, 0, (size_t)N_USR * 4, stream);
  hipMemsetAsync(cnt9, 0, (size_t)B9 * 4, stream);

  // K1: bf16 convert + fire-and-forget count + prep + sc(user)
  k_pre<<<TB_BLOCKS + CNT_BLOCKS + 1 + SC_BLOCKS, 256, 0, stream>>>(
      entity_emb, ent0bf, head, ui_rows, edge_type, cnt_u, cnt9,
      weight, kgW, disen, V, wsq, dw, out_cor, user_emb, latent, sc4a);

  int nbh = (B9 + 1023) / 1024;       // 879
  int nbu = (N_USR + 1023) / 1024;    // 49
  // K2: fused scan-reduce over flat cnt9 | cnt_u
  k_scanred<<<nbh + nbu, 256, 0, stream>>>(cnt9, cnt_u, bsum_h, bsum_u, nbh);
  // K3: block-sum exclusive scans (+ sentinel ptr entries)
  k_scan_tops<<<1, 64, 0, stream>>>(bsum_h, nbh, bsum_u, nbu, head_ptr, N_ENT, ui_ptr, N_USR, N_EDGE);
  // K4: fused scan-final -> base9 + head_ptr + coarse cursors | ui_ptr
  k_scanfin<<<nbh + nbu, 256, 0, stream>>>(cnt9, cnt_u, bsum_h, bsum_u,
                                           base9, head_ptr, ui_ptr,
                                           coarse_kg_cur, coarse_ui_cur, nbh);
  // K5a: coarse binning (block-level reservations)
  k_bin<<<BIN_BLOCKS, 1024, 0, stream>>>(
      head, tail, edge_type, ui_rows, ui_cols, ui_vals,
      coarse_kg_cur, coarse_ui_cur, stage_kg, stage_ui);
  // K5b: fine placement (LDS ranks, region-local stores) + rel2
  k_fine_rel2<<<FINEK_BLOCKS + FINEU_BLOCKS + REL2_BLOCKS, 256, 0, stream>>>(
      stage_kg, stage_ui, base9, ui_ptr, packed, cv,
      ent0bf, V, wsq, cnt9, rel2t);

  // D1: mask + fused KG hop-1 + UI hop-1 (+ sc4b epilogue)
  k_mask_kg_ui<<<KG_BLOCKS + UI_BLOCKS, 256, 0, stream>>>(
      entity_emb, ent0bf, head_ptr, packed, rel2t, mask_s, weight,
      out_ent, ent1bf, sc4a, out_usr, usr1, ui_ptr, cv, user_emb, dw, latent, sc4b);

  // D2: KG hop-2 + UI hop-2
  k_hop2<<<KG_BLOCKS + UI_BLOCKS, 256, 0, stream>>>(
      ent1bf, out_ent, head_ptr, packed, mask_s, weight,
      usr1, out_usr, ui_ptr, cv, sc4b, dw);
}

// Round 7
// 478.393 us; speedup vs baseline: 1.2152x; 1.1851x over previous
//
#include <hip/hip_runtime.h>
#include <math.h>

#define N_ENT 100000
#define N_USR 50000
#define N_EDGE 1000000
#define B9 (N_ENT * 9)   // 900000 flat (ent,rel) buckets
#define TEMPC 0.2f
#define KG_BLOCKS (N_ENT / 4)   // 25000, exact
#define UI_BLOCKS (N_USR / 4)   // 12500, exact

// fused-kernel block ranges
#define TB_BLOCKS 6250   // ceil(N_ENT*64/4 / 256) : bf16 convert (float4 granules)
#define CNT_BLOCKS 489   // ceil(N_EDGE/8 / 256) : fire-and-forget count, 8 edges/thread
#define SC_BLOCKS 196    // ceil(N_USR / 256)
#define REL2_BLOCKS 391  // ceil(N_ENT / 256)

// counting-sort phases
#define BIN_BLOCKS 245   // ceil(N_EDGE / (1024*4))
#define NCK 391          // KG coarse buckets: head >> 8
#define NCU 196          // UI coarse buckets: user >> 8
#define FINEK_BLOCKS NCK
#define FINEU_BLOCKS NCU

#define WLS 68   // padded stride for weight rows in LDS

typedef unsigned short ushort_t;

__device__ __forceinline__ float waveReduceSum(float x) {
#pragma unroll
  for (int d = 32; d > 0; d >>= 1) x += __shfl_xor(x, d);
  return x;
}
__device__ __forceinline__ float waveReduceMax(float x) {
#pragma unroll
  for (int d = 32; d > 0; d >>= 1) x = fmaxf(x, __shfl_xor(x, d));
  return x;
}
__device__ __forceinline__ int waveReduceSumI(int x) {
#pragma unroll
  for (int d = 32; d > 0; d >>= 1) x += __shfl_xor(x, d);
  return x;
}
__device__ __forceinline__ float bf2f(unsigned int u16) {
  union { unsigned int i; float f; } v;
  v.i = u16 << 16;
  return v.f;
}
__device__ __forceinline__ ushort_t f2bf(float f) {
  union { unsigned int i; float f; } v;
  v.f = f;
  unsigned int u = v.i;
  u = (u + 0x7FFFu + ((u >> 16) & 1u)) >> 16;
  return (ushort_t)u;
}
// wave-uniform broadcast via v_readlane -> SGPR
__device__ __forceinline__ int rl(int v, int l) { return __builtin_amdgcn_readlane(v, l); }
__device__ __forceinline__ float rlf(float v, int l) {
  return __int_as_float(__builtin_amdgcn_readlane(__float_as_int(v), l));
}

// column-partial reduce over g (masks 8/16/32) + 8x8 wave transpose
__device__ __forceinline__ float colRT(float a0, float a1, float a2, float a3,
                                       float a4, float a5, float a6, float a7,
                                       int g, int part) {
#define RED3(x) x += __shfl_xor(x, 8); x += __shfl_xor(x, 16); x += __shfl_xor(x, 32);
  RED3(a0) RED3(a1) RED3(a2) RED3(a3) RED3(a4) RED3(a5) RED3(a6) RED3(a7)
#undef RED3
  float t0 = __shfl(a0, g), t1 = __shfl(a1, g), t2 = __shfl(a2, g), t3 = __shfl(a3, g);
  float t4 = __shfl(a4, g), t5 = __shfl(a5, g), t6 = __shfl(a6, g), t7 = __shfl(a7, g);
  float r = t0;
  r = (part == 1) ? t1 : r;
  r = (part == 2) ? t2 : r;
  r = (part == 3) ? t3 : r;
  r = (part == 4) ? t4 : r;
  r = (part == 5) ? t5 : r;
  r = (part == 6) ? t6 : r;
  r = (part == 7) ? t7 : r;
  return r;
}

// ============ K1: bf16 convert | f&f count (8/thr) | prep | sc(user) ============
__global__ void k_pre(const float* __restrict__ ent0, ushort_t* __restrict__ ent0bf,
                      const int* __restrict__ head, const int* __restrict__ uir,
                      const int* __restrict__ etype,
                      int* __restrict__ cnt_u, int* __restrict__ cnt9,
                      const float* __restrict__ weight, const float* __restrict__ kgW,
                      const float* __restrict__ disen,
                      float* __restrict__ V, float* __restrict__ wsq,
                      float* __restrict__ dw, float* __restrict__ cor_out,
                      const float* __restrict__ user_emb, const float* __restrict__ latent,
                      float4* __restrict__ sc4a) {
  int bid = blockIdx.x;
  if (bid < TB_BLOCKS) {
    int i = bid * 256 + threadIdx.x;
    if (i < N_ENT * 16) {
      float4 v = ((const float4*)ent0)[i];
      ushort4 o;
      o.x = f2bf(v.x); o.y = f2bf(v.y); o.z = f2bf(v.z); o.w = f2bf(v.w);
      ((ushort4*)ent0bf)[i] = o;
    }
  } else if (bid < TB_BLOCKS + CNT_BLOCKS) {
    // fire-and-forget counting only (no return values -> atomics pipeline freely)
    int i0 = ((bid - TB_BLOCKS) * 256 + threadIdx.x) * 8;
    if (i0 < N_EDGE) {
      int4 ha = *(const int4*)(head + i0), hb = *(const int4*)(head + i0 + 4);
      int4 ea = *(const int4*)(etype + i0), eb = *(const int4*)(etype + i0 + 4);
      int4 ua = *(const int4*)(uir + i0), ub = *(const int4*)(uir + i0 + 4);
      atomicAdd(&cnt9[ha.x * 9 + (ea.x - 1)], 1);
      atomicAdd(&cnt9[ha.y * 9 + (ea.y - 1)], 1);
      atomicAdd(&cnt9[ha.z * 9 + (ea.z - 1)], 1);
      atomicAdd(&cnt9[ha.w * 9 + (ea.w - 1)], 1);
      atomicAdd(&cnt9[hb.x * 9 + (eb.x - 1)], 1);
      atomicAdd(&cnt9[hb.y * 9 + (eb.y - 1)], 1);
      atomicAdd(&cnt9[hb.z * 9 + (eb.z - 1)], 1);
      atomicAdd(&cnt9[hb.w * 9 + (eb.w - 1)], 1);
      atomicAdd(&cnt_u[ua.x], 1);
      atomicAdd(&cnt_u[ua.y], 1);
      atomicAdd(&cnt_u[ua.z], 1);
      atomicAdd(&cnt_u[ua.w], 1);
      atomicAdd(&cnt_u[ub.x], 1);
      atomicAdd(&cnt_u[ub.y], 1);
      atomicAdd(&cnt_u[ub.z], 1);
      atomicAdd(&cnt_u[ub.w], 1);
    }
  } else if (bid == TB_BLOCKS + CNT_BLOCKS) {
    // ---- prep: V=(W W^T)w_r via T-factorization, wsq, dw, cor ----
    __shared__ float T[9 * 64];
    __shared__ float sm[4 * 9];
    int tid = threadIdx.x;
    for (int e = tid; e < 9 * 64; e += 256) {
      int r = e >> 6, d = e & 63;
      float s = 0.f;
      for (int k = 0; k < 64; ++k) s += kgW[k * 64 + d] * weight[r * 64 + k];
      T[e] = s;
    }
    if (tid < 4) {
      float m = -INFINITY;
      for (int r = 0; r < 9; ++r) m = fmaxf(m, disen[tid * 9 + r]);
      float den = 0.f;
      float ex[9];
      for (int r = 0; r < 9; ++r) { ex[r] = expf(disen[tid * 9 + r] - m); den += ex[r]; }
      for (int r = 0; r < 9; ++r) sm[tid * 9 + r] = ex[r] / den;
    }
    __syncthreads();
    for (int e = tid; e < 9 * 64; e += 256) {
      int r = e >> 6, i = e & 63;
      float s = 0.f;
      for (int d = 0; d < 64; ++d) s += kgW[i * 64 + d] * T[r * 64 + d];
      V[e] = s;
    }
    if (tid < 9) {
      float s = 0.f;
      for (int c = 0; c < 64; ++c) { float w = weight[tid * 64 + c]; s += w * w; }
      wsq[tid] = s;
    }
    for (int e = tid; e < 4 * 64; e += 256) {
      int f = e >> 6, c = e & 63;
      float s = 0.f;
      for (int r = 0; r < 9; ++r) s += sm[f * 9 + r] * weight[r * 64 + c];
      dw[e] = s;
    }
    if (tid == 0) {
      float rowsum[4];
      for (int f = 0; f < 4; ++f) {
        float s = 0.f;
        for (int j = 0; j < 9; ++j) s += disen[f * 9 + j];
        rowsum[f] = s;
      }
      float cor = 0.f;
      for (int i = 0; i < 9; ++i) {
        float n2 = 0.f, ttl = 0.f;
        for (int f = 0; f < 4; ++f) {
          float v = disen[f * 9 + i];
          n2 += v * v;
          ttl += v * rowsum[f];
        }
        float nrm = sqrtf(n2);
        float pos = 0.f;
        for (int f = 0; f < 4; ++f) {
          float v = disen[f * 9 + i] / nrm;
          pos += v * v;
        }
        cor += (ttl - pos) / TEMPC;
      }
      *cor_out = cor;
    }
  } else {
    // ---- sc on user_emb -> sc4a ----
    __shared__ __align__(16) float lat[256];
    if (threadIdx.x < 256) lat[threadIdx.x] = latent[threadIdx.x];
    __syncthreads();
    int u = (bid - TB_BLOCKS - CNT_BLOCKS - 1) * 256 + threadIdx.x;
    if (u >= N_USR) return;
    float a0 = 0.f, a1 = 0.f, a2 = 0.f, a3 = 0.f;
    const float4* row = (const float4*)(user_emb + (size_t)u * 64);
#pragma unroll
    for (int q = 0; q < 16; ++q) {
      float4 v = row[q];
      float4 l0 = *(const float4*)(lat + 0 * 64 + q * 4);
      float4 l1 = *(const float4*)(lat + 1 * 64 + q * 4);
      float4 l2 = *(const float4*)(lat + 2 * 64 + q * 4);
      float4 l3 = *(const float4*)(lat + 3 * 64 + q * 4);
      a0 = fmaf(v.x, l0.x, a0); a0 = fmaf(v.y, l0.y, a0); a0 = fmaf(v.z, l0.z, a0); a0 = fmaf(v.w, l0.w, a0);
      a1 = fmaf(v.x, l1.x, a1); a1 = fmaf(v.y, l1.y, a1); a1 = fmaf(v.z, l1.z, a1); a1 = fmaf(v.w, l1.w, a1);
      a2 = fmaf(v.x, l2.x, a2); a2 = fmaf(v.y, l2.y, a2); a2 = fmaf(v.z, l2.z, a2); a2 = fmaf(v.w, l2.w, a2);
      a3 = fmaf(v.x, l3.x, a3); a3 = fmaf(v.y, l3.y, a3); a3 = fmaf(v.z, l3.z, a3); a3 = fmaf(v.w, l3.w, a3);
    }
    sc4a[u] = make_float4(a0, a1, a2, a3);
  }
}

// ============ K2: fused scan-reduce (flat cnt9 | cnt_u) ============
__global__ void k_scanred(const int* __restrict__ cnt9, const int* __restrict__ cnt_u,
                          int* __restrict__ bsum_h, int* __restrict__ bsum_u, int nbh) {
  int b = blockIdx.x, tid = threadIdx.x;
  int s = 0;
  if (b < nbh) {
    int i0 = b * 1024 + tid * 4;
#pragma unroll
    for (int k = 0; k < 4; ++k)
      if (i0 + k < B9) s += cnt9[i0 + k];
  } else {
    int i0 = (b - nbh) * 1024 + tid * 4;
#pragma unroll
    for (int k = 0; k < 4; ++k)
      if (i0 + k < N_USR) s += cnt_u[i0 + k];
  }
  s = waveReduceSumI(s);
  __shared__ int l[4];
  int lane = tid & 63, wid = tid >> 6;
  if (lane == 0) l[wid] = s;
  __syncthreads();
  if (tid == 0) {
    int v = l[0] + l[1] + l[2] + l[3];
    if (b < nbh) bsum_h[b] = v; else bsum_u[b - nbh] = v;
  }
}

// ============ K3: PARALLEL top-level scans (was 1-thread serial over 879 elems
// at ~300 dependent-latency cycles each ≈ 100 µs hidden; now one 1024-thr block) ============
__global__ void __launch_bounds__(1024) k_scan_tops(
    int* bsA, int nA, int* bsB, int nB,
    int* ptrA, int NA, int* ptrB, int NB, int total) {
  __shared__ int wsum[16];
  int tid = threadIdx.x, lane = tid & 63, wid = tid >> 6;
  // ---- exclusive scan A (nA <= 1024) ----
  int v = (tid < nA) ? bsA[tid] : 0;
  int x = v;
#pragma unroll
  for (int d = 1; d < 64; d <<= 1) {
    int y = __shfl_up(x, d);
    if (lane >= d) x += y;
  }
  if (lane == 63) wsum[wid] = x;
  __syncthreads();
  if (tid == 0) {
    int a = 0;
    for (int w = 0; w < 16; ++w) { int t = wsum[w]; wsum[w] = a; a += t; }
  }
  __syncthreads();
  if (tid < nA) bsA[tid] = x - v + wsum[wid];
  if (tid == 0) ptrA[NA] = total;
  __syncthreads();
  // ---- exclusive scan B (nB <= 1024) ----
  int vb = (tid < nB) ? bsB[tid] : 0;
  int xb = vb;
#pragma unroll
  for (int d = 1; d < 64; d <<= 1) {
    int y = __shfl_up(xb, d);
    if (lane >= d) xb += y;
  }
  if (lane == 63) wsum[wid] = xb;
  __syncthreads();
  if (tid == 0) {
    int a = 0;
    for (int w = 0; w < 16; ++w) { int t = wsum[w]; wsum[w] = a; a += t; }
  }
  __syncthreads();
  if (tid < nB) bsB[tid] = xb - vb + wsum[wid];
  if (tid == 0) ptrB[NB] = total;
}

// ============ K4: scan-final -> base9 + head_ptr + coarse cursors | ui_ptr ============
__global__ void k_scanfin(const int* __restrict__ cnt9, const int* __restrict__ cnt_u,
                          const int* __restrict__ bsum_h, const int* __restrict__ bsum_u,
                          int* __restrict__ base9, int* __restrict__ head_ptr,
                          int* __restrict__ ui_ptr,
                          int* __restrict__ coarse_kg_cur, int* __restrict__ coarse_ui_cur,
                          int nbh) {
  int b = blockIdx.x, tid = threadIdx.x;
  bool isH = (b < nbh);
  int bl = isH ? b : b - nbh;
  int n = isH ? B9 : N_USR;
  int i0 = bl * 1024 + tid * 4;
  int s = 0;
  int loc[4];
#pragma unroll
  for (int k = 0; k < 4; ++k) {
    int v = 0;
    if (i0 + k < n) v = isH ? cnt9[i0 + k] : cnt_u[i0 + k];
    loc[k] = s;
    s += v;
  }
  int lane = tid & 63, wid = tid >> 6;
  int x = s;
#pragma unroll
  for (int d = 1; d < 64; d <<= 1) {
    int y = __shfl_up(x, d);
    if (lane >= d) x += y;
  }
  __shared__ int l[4];
  if (lane == 63) l[wid] = x;
  __syncthreads();
  if (tid == 0) {
    int a = 0;
    for (int w = 0; w < 4; ++w) { int t = l[w]; l[w] = a; a += t; }
  }
  __syncthreads();
  int excl = x - s + l[wid] + (isH ? bsum_h[bl] : bsum_u[bl]);
#pragma unroll
  for (int k = 0; k < 4; ++k) {
    int idx = i0 + k;
    if (idx < n) {
      int v = excl + loc[k];
      if (isH) {
        base9[idx] = v;
        int ent = idx / 9;
        if (idx - ent * 9 == 0) {
          head_ptr[ent] = v;
          if ((ent & 255) == 0) coarse_kg_cur[ent >> 8] = v;  // coarse bucket start
        }
      } else {
        ui_ptr[idx] = v;
        if ((idx & 255) == 0) coarse_ui_cur[idx >> 8] = v;
      }
    }
  }
}

// ============ K5a: coarse binning (block-level reservations, NO per-edge return-atomics) ============
__global__ void __launch_bounds__(1024) k_bin(
    const int* __restrict__ head, const int* __restrict__ tail,
    const int* __restrict__ etype,
    const int* __restrict__ uir, const int* __restrict__ uic,
    const float* __restrict__ uival,
    int* __restrict__ coarse_kg_cur, int* __restrict__ coarse_ui_cur,
    unsigned int* __restrict__ stage_kg, int2* __restrict__ stage_ui) {
  __shared__ int histK[NCK], histU[NCU];
  int tid = threadIdx.x;
  for (int i = tid; i < NCK; i += 1024) histK[i] = 0;
  for (int i = tid; i < NCU; i += 1024) histU[i] = 0;
  __syncthreads();
  int i0 = (blockIdx.x * 1024 + tid) * 4;
  bool valid = (i0 < N_EDGE);
  int4 h4, t4v, e4, r4, c4;
  float4 v4;
  int k0 = 0, k1 = 0, k2 = 0, k3 = 0, u0 = 0, u1 = 0, u2 = 0, u3 = 0;
  if (valid) {
    h4 = *(const int4*)(head + i0);
    t4v = *(const int4*)(tail + i0);
    e4 = *(const int4*)(etype + i0);
    r4 = *(const int4*)(uir + i0);
    c4 = *(const int4*)(uic + i0);
    v4 = *(const float4*)(uival + i0);
    // local ranks via LDS atomics (cheap, block-local)
    k0 = atomicAdd(&histK[h4.x >> 8], 1);
    k1 = atomicAdd(&histK[h4.y >> 8], 1);
    k2 = atomicAdd(&histK[h4.z >> 8], 1);
    k3 = atomicAdd(&histK[h4.w >> 8], 1);
    u0 = atomicAdd(&histU[r4.x >> 8], 1);
    u1 = atomicAdd(&histU[r4.y >> 8], 1);
    u2 = atomicAdd(&histU[r4.z >> 8], 1);
    u3 = atomicAdd(&histU[r4.w >> 8], 1);
  }
  __syncthreads();
  // block-level reservation: ONE global return-atomic per (block, nonempty bucket)
  if (tid < NCK) {
    int c = histK[tid];
    histK[tid] = (c > 0) ? atomicAdd(&coarse_kg_cur[tid], c) : 0;
  } else if (tid >= 512 && tid < 512 + NCU) {
    int bu = tid - 512;
    int c = histU[bu];
    histU[bu] = (c > 0) ? atomicAdd(&coarse_ui_cur[bu], c) : 0;
  }
  __syncthreads();
  if (valid) {
    // staged KG word: tail(0:19) | rel(20:23) | head&255(24:31)
    stage_kg[histK[h4.x >> 8] + k0] =
        (unsigned int)(t4v.x | ((e4.x - 1) << 20) | ((h4.x & 255) << 24));
    stage_kg[histK[h4.y >> 8] + k1] =
        (unsigned int)(t4v.y | ((e4.y - 1) << 20) | ((h4.y & 255) << 24));
    stage_kg[histK[h4.z >> 8] + k2] =
        (unsigned int)(t4v.z | ((e4.z - 1) << 20) | ((h4.z & 255) << 24));
    stage_kg[histK[h4.w >> 8] + k3] =
        (unsigned int)(t4v.w | ((e4.w - 1) << 20) | ((h4.w & 255) << 24));
    // staged UI: {col(0:23) | user&255(24:31), val}
    stage_ui[histU[r4.x >> 8] + u0] = make_int2(c4.x | ((r4.x & 255) << 24), __float_as_int(v4.x));
    stage_ui[histU[r4.y >> 8] + u1] = make_int2(c4.y | ((r4.y & 255) << 24), __float_as_int(v4.y));
    stage_ui[histU[r4.z >> 8] + u2] = make_int2(c4.z | ((r4.z & 255) << 24), __float_as_int(v4.z));
    stage_ui[histU[r4.w >> 8] + u3] = make_int2(c4.w | ((r4.w & 255) << 24), __float_as_int(v4.w));
  }
}

// ============ K5b: fine placement within coarse buckets (LDS ranks, region-local stores) | rel2 ============
__global__ void k_fine_rel2(const unsigned int* __restrict__ stage_kg,
                            const int2* __restrict__ stage_ui,
                            const int* __restrict__ base9, const int* __restrict__ ui_ptr,
                            int* __restrict__ packed, int2* __restrict__ cv,
                            const ushort_t* __restrict__ ent0bf, const float* __restrict__ V,
                            const float* __restrict__ wsq, const int* __restrict__ cnt9,
                            float* __restrict__ rel2t) {
  int tid = threadIdx.x;
  if (blockIdx.x < FINEK_BLOCKS) {
    int b = blockIdx.x;
    __shared__ int lbase[2304];  // 256 heads x 9 rels
    __shared__ int lcnt[2304];
    int gb = (b << 8) * 9;
    for (int i = tid; i < 2304; i += 256) {
      int gi = gb + i;
      lbase[i] = (gi < B9) ? base9[gi] : N_EDGE;
      lcnt[i] = 0;
    }
    __syncthreads();
    int start = base9[gb];
    int end = (b < FINEK_BLOCKS - 1) ? base9[gb + 2304] : N_EDGE;
    for (int i = start + tid; i < end; i += 256) {
      unsigned int w = stage_kg[i];
      int key = (int)((w >> 24) & 255u) * 9 + (int)((w >> 20) & 15u);
      int r = atomicAdd(&lcnt[key], 1);
      packed[lbase[key] + r] = (int)(w & 0xFFFFFFu);  // tail | rel<<20
    }
  } else if (blockIdx.x < FINEK_BLOCKS + FINEU_BLOCKS) {
    int b = blockIdx.x - FINEK_BLOCKS;
    __shared__ int lbu[256];
    __shared__ int lcu[256];
    int gb = b << 8;
    lbu[tid] = (gb + tid < N_USR) ? ui_ptr[gb + tid] : N_EDGE;
    lcu[tid] = 0;
    __syncthreads();
    int start = ui_ptr[gb];
    int nxt = gb + 256;
    int end = ui_ptr[(nxt < N_USR) ? nxt : N_USR];  // ui_ptr[N_USR] = N_EDGE sentinel
    for (int i = start + tid; i < end; i += 256) {
      int2 d = stage_ui[i];
      int key = (d.x >> 24) & 255;
      int r = atomicAdd(&lcu[key], 1);
      cv[lbu[key] + r] = make_int2(d.x & 0xFFFFFF, d.y);
    }
  } else {
    // ---- rel2: dense per-entity relation softmax table ----
    __shared__ __align__(16) float Vl[576];
    __shared__ float wsql[9];
    for (int i = tid; i < 576; i += 256) Vl[i] = V[i];
    if (tid < 9) wsql[tid] = wsq[tid];
    __syncthreads();
    int ent = (blockIdx.x - FINEK_BLOCKS - FINEU_BLOCKS) * 256 + tid;
    if (ent >= N_ENT) return;
    float a[9] = {0, 0, 0, 0, 0, 0, 0, 0, 0};
    const uint4* row = (const uint4*)(ent0bf + (ent << 6));
#pragma unroll
    for (int q = 0; q < 8; ++q) {
      uint4 b = row[q];
      float ch0 = bf2f(b.x & 0xFFFFu), ch1 = bf2f(b.x >> 16);
      float ch2 = bf2f(b.y & 0xFFFFu), ch3 = bf2f(b.y >> 16);
      float ch4 = bf2f(b.z & 0xFFFFu), ch5 = bf2f(b.z >> 16);
      float ch6 = bf2f(b.w & 0xFFFFu), ch7 = bf2f(b.w >> 16);
#pragma unroll
      for (int r = 0; r < 9; ++r) {
        const float4* vp = (const float4*)(Vl + r * 64 + q * 8);
        float4 v0 = vp[0], v1 = vp[1];
        float t = a[r];
        t = fmaf(ch0, v0.x, t); t = fmaf(ch1, v0.y, t);
        t = fmaf(ch2, v0.z, t); t = fmaf(ch3, v0.w, t);
        t = fmaf(ch4, v1.x, t); t = fmaf(ch5, v1.y, t);
        t = fmaf(ch6, v1.z, t); t = fmaf(ch7, v1.w, t);
        a[r] = t;
      }
    }
    const float inv2s = 0.08838834764831845f;  // 1/(2*sqrt(32))
    int cnt[9];
#pragma unroll
    for (int r = 0; r < 9; ++r) cnt[r] = cnt9[ent * 9 + r];
    float m1 = -INFINITY;
#pragma unroll
    for (int r = 0; r < 9; ++r)
      if (cnt[r] > 0) m1 = fmaxf(m1, a[r] * inv2s);
    if (m1 == -INFINITY) {
#pragma unroll
      for (int r = 0; r < 9; ++r) rel2t[ent * 9 + r] = 0.f;
      return;
    }
    float den1 = 1e-16f;
#pragma unroll
    for (int r = 0; r < 9; ++r)
      if (cnt[r] > 0) den1 += (float)cnt[r] * expf(a[r] * inv2s - m1);
#pragma unroll
    for (int r = 0; r < 9; ++r) {
      float rs = expf(a[r] * inv2s - m1) / den1;
      rel2t[ent * 9 + r] = rs * rs * wsql[r];
    }
  }
}

// KG aggregation inner (readlane broadcasts, 4 acc chains) — generic fallback
__device__ __forceinline__ float kg_agg64(int deg, int lane, int pk, float mk,
                                          const ushort_t* __restrict__ srcbf,
                                          const float* __restrict__ wl) {
  float a0 = 0.f, a1 = 0.f, a2 = 0.f, a3 = 0.f;
  int j = 0;
  for (; j + 4 <= deg; j += 4) {
    int p0 = rl(pk, j), p1 = rl(pk, j + 1), p2 = rl(pk, j + 2), p3 = rl(pk, j + 3);
    float k0 = rlf(mk, j), k1 = rlf(mk, j + 1), k2 = rlf(mk, j + 2), k3 = rlf(mk, j + 3);
    float r0 = bf2f(srcbf[((p0 & 0xFFFFF) << 6) + lane]);
    float r1 = bf2f(srcbf[((p1 & 0xFFFFF) << 6) + lane]);
    float r2 = bf2f(srcbf[((p2 & 0xFFFFF) << 6) + lane]);
    float r3 = bf2f(srcbf[((p3 & 0xFFFFF) << 6) + lane]);
    a0 = fmaf(r0 * wl[((p0 >> 20) & 15) * WLS + lane], k0, a0);
    a1 = fmaf(r1 * wl[((p1 >> 20) & 15) * WLS + lane], k1, a1);
    a2 = fmaf(r2 * wl[((p2 >> 20) & 15) * WLS + lane], k2, a2);
    a3 = fmaf(r3 * wl[((p3 >> 20) & 15) * WLS + lane], k3, a3);
  }
  for (; j < deg; ++j) {
    int pj = rl(pk, j);
    float kj = rlf(mk, j);
    a0 = fmaf(bf2f(srcbf[((pj & 0xFFFFF) << 6) + lane]) * wl[((pj >> 20) & 15) * WLS + lane], kj, a0);
  }
  return (a0 + a1) + (a2 + a3);
}

// ---------------- UI aggregation body (group-layout single-pass) ----------------
__device__ __forceinline__ void ui_body(int usr, int lane,
                                        const ushort_t* __restrict__ srcbf,
                                        const float4* __restrict__ sc4,
                                        const float* __restrict__ addb,
                                        float* __restrict__ outp, float* __restrict__ nxt,
                                        const int* __restrict__ uptr,
                                        const int2* __restrict__ cv,
                                        const float* __restrict__ dwl,
                                        const float* __restrict__ latl,
                                        float4* __restrict__ sc4out) {
  float4 s4 = sc4[usr];
  float m = fmaxf(fmaxf(s4.x, s4.y), fmaxf(s4.z, s4.w));
  float e0 = expf(s4.x - m), e1 = expf(s4.y - m), e2 = expf(s4.z - m), e3 = expf(s4.w - m);
  float den = e0 + e1 + e2 + e3;
  float mix = (e0 * dwl[lane] + e1 * dwl[64 + lane] + e2 * dwl[128 + lane] + e3 * dwl[192 + lane]) / den;
  int s = uptr[usr], e = uptr[usr + 1];
  int g = lane >> 3, part = lane & 7;
  float a0 = 0.f, a1 = 0.f, a2 = 0.f, a3 = 0.f;
  float a4 = 0.f, a5 = 0.f, a6 = 0.f, a7 = 0.f;
  for (int base = s; base < e; base += 64) {
    int c = min(64, e - base);
    int2 cvl = (lane < c) ? cv[base + lane] : make_int2(0, 0);
    int cl = cvl.x;
    float vl = __int_as_float(cvl.y);
    int nch = (c + 7) >> 3;
#pragma unroll
    for (int cc = 0; cc < 8; ++cc) {
      if (cc < nch) {
        int j = (cc << 3) + g;
        int cj = __shfl(cl, j);       // inactive rows broadcast 0 -> row 0, vj=0
        float vj = __shfl(vl, j);
        uint4 b = *((const uint4*)(srcbf + ((size_t)cj << 6)) + part);
        a0 = fmaf(bf2f(b.x & 0xFFFFu), vj, a0);
        a1 = fmaf(bf2f(b.x >> 16), vj, a1);
        a2 = fmaf(bf2f(b.y & 0xFFFFu), vj, a2);
        a3 = fmaf(bf2f(b.y >> 16), vj, a3);
        a4 = fmaf(bf2f(b.z & 0xFFFFu), vj, a4);
        a5 = fmaf(bf2f(b.z >> 16), vj, a5);
        a6 = fmaf(bf2f(b.w & 0xFFFFu), vj, a6);
        a7 = fmaf(bf2f(b.w >> 16), vj, a7);
      }
    }
  }
  float acc = colRT(a0, a1, a2, a3, a4, a5, a6, a7, g, part);
  float ua = acc * mix + acc;
  float nrm = sqrtf(waveReduceSum(ua * ua));
  float val = ua / fmaxf(nrm, 1e-12f);
  size_t o = (size_t)usr * 64 + lane;
  if (nxt) nxt[o] = val;
  outp[o] = addb[o] + val;
  if (sc4out) {
    // fused hop-2 factor scores: sc4b[usr] = val @ latent^T
    float s0 = waveReduceSum(val * latl[lane]);
    float s1 = waveReduceSum(val * latl[64 + lane]);
    float s2 = waveReduceSum(val * latl[128 + lane]);
    float s3 = waveReduceSum(val * latl[192 + lane]);
    if (lane == 0) sc4out[usr] = make_float4(s0, s1, s2, s3);
  }
}

// ---------------- D1: mask + fused KG hop-1  |  UI hop-1 (+sc4b) ----------------
__global__ void k_mask_kg_ui(const float* __restrict__ ent0,
                             const ushort_t* __restrict__ ent0bf,
                             const int* __restrict__ hptr, const int* __restrict__ packed,
                             const float* __restrict__ rel2t,
                             float* __restrict__ mask_s, const float* __restrict__ weight,
                             float* __restrict__ out_ent, ushort_t* __restrict__ ent1bf,
                             const float4* __restrict__ sc4,
                             float* __restrict__ out_usr,
                             float* __restrict__ usr1, const int* __restrict__ uptr,
                             const int2* __restrict__ cv,
                             const float* __restrict__ user_emb, const float* __restrict__ dw,
                             const float* __restrict__ latent, float4* __restrict__ sc4b) {
  int lane = threadIdx.x & 63, wid = threadIdx.x >> 6;
  if (blockIdx.x < KG_BLOCKS) {
    __shared__ __align__(16) float sh_eh[4][64];
    __shared__ __align__(16) float wl[9 * WLS];
    for (int i = threadIdx.x; i < 576; i += 256) wl[(i >> 6) * WLS + (i & 63)] = weight[i];
    int ent = blockIdx.x * 4 + wid;  // always < N_ENT
    int s = hptr[ent], e = hptr[ent + 1];
    float eh = ent0[(size_t)ent * 64 + lane];
    sh_eh[wid][lane] = eh;
    __syncthreads();
    size_t o = (size_t)ent * 64 + lane;
    int deg = e - s;
    if (deg == 0) {
      ent1bf[o] = f2bf(0.f);
      out_ent[o] = eh;
      return;
    }
    if (deg <= 64) {
      // ---- single-pass hot path: group-layout dot + DIRECT-EXP softmax. ----
      int pk = (lane < deg) ? packed[s + lane] : 0;
      int tb = (pk >> 20) & 15;
      float r2sel = rel2t[ent * 9 + ((lane < deg) ? tb : 0)];
      int g = lane >> 3, part = lane & 7;
      const float4* ehq = (const float4*)(sh_eh[wid] + (part << 3));
      float4 ef0 = ehq[0], ef1 = ehq[1];
      int nch = (deg + 7) >> 3;
      float den = 0.f;
      float acc0 = 0.f, acc1 = 0.f, acc2 = 0.f, acc3 = 0.f;
      float acc4 = 0.f, acc5 = 0.f, acc6 = 0.f, acc7 = 0.f;
      float ws8[8];
#pragma unroll
      for (int cc = 0; cc < 8; ++cc) {
        ws8[cc] = 0.f;
        if (cc < nch) {
          int j = (cc << 3) + g;  // row handled by this lane's group slot
          int pkj = __shfl(pk, j);  // inactive rows broadcast pk=0 -> row 0 (safe)
          uint4 b = *((const uint4*)(ent0bf + ((size_t)(pkj & 0xFFFFF) << 6)) + part);
          float r0 = bf2f(b.x & 0xFFFFu), r1 = bf2f(b.x >> 16);
          float r2 = bf2f(b.y & 0xFFFFu), r3 = bf2f(b.y >> 16);
          float r4 = bf2f(b.z & 0xFFFFu), r5 = bf2f(b.z >> 16);
          float r6 = bf2f(b.w & 0xFFFFu), r7 = bf2f(b.w >> 16);
          // partial dot over this lane's 8 columns, reduce over part (masks 1,2,4)
          float s0 = r0 * ef0.x, s1 = r2 * ef0.z, s2 = r4 * ef1.x, s3 = r6 * ef1.z;
          s0 = fmaf(r1, ef0.y, s0); s1 = fmaf(r3, ef0.w, s1);
          s2 = fmaf(r5, ef1.y, s2); s3 = fmaf(r7, ef1.w, s3);
          float sv = (s0 + s1) + (s2 + s3);
          sv += __shfl_xor(sv, 1);
          sv += __shfl_xor(sv, 2);
          sv += __shfl_xor(sv, 4);
          float r2j = __shfl(r2sel, j);
          float w = (j < deg) ? expf(sv + r2j) : 0.f;
          ws8[cc] = w;
          den += w;
          // weighted row accumulate into this lane's 8 columns
          const float4* wp = (const float4*)(wl + ((pkj >> 20) & 15) * WLS + (part << 3));
          float4 w0 = wp[0], w1 = wp[1];
          acc0 = fmaf(w * r0, w0.x, acc0);
          acc1 = fmaf(w * r1, w0.y, acc1);
          acc2 = fmaf(w * r2, w0.z, acc2);
          acc3 = fmaf(w * r3, w0.w, acc3);
          acc4 = fmaf(w * r4, w1.x, acc4);
          acc5 = fmaf(w * r5, w1.y, acc5);
          acc6 = fmaf(w * r6, w1.z, acc6);
          acc7 = fmaf(w * r7, w1.w, acc7);
        }
      }
      // full softmax denominator (sum over g: each row counted once per part-octet)
      float den2 = den;
      den2 += __shfl_xor(den2, 8);
      den2 += __shfl_xor(den2, 16);
      den2 += __shfl_xor(den2, 32);
      den2 += 1e-16f;
      float invden = 1.0f / den2;
      // write mask_s (per-chunk: lanes with part==0 write their group's row)
#pragma unroll
      for (int cc = 0; cc < 8; ++cc) {
        if (cc < nch) {
          int j = (cc << 3) + g;
          if (part == 0 && j < deg) mask_s[s + j] = ws8[cc] * invden;
        }
      }
      float aggv = colRT(acc0, acc1, acc2, acc3, acc4, acc5, acc6, acc7, g, part);
      float agg = aggv * invden / (float)deg;
      float nrm = sqrtf(waveReduceSum(agg * agg));
      float val = agg / fmaxf(nrm, 1e-12f);
      ent1bf[o] = f2bf(val);
      out_ent[o] = eh + val;
    } else {
      // ---- generic multi-chunk path (deg>64) ----
      float m2l = -INFINITY;
      for (int base = s; base < e; base += 64) {
        int c = min(64, e - base);
        int pk = (lane < c) ? packed[base + lane] : 0;
        int tb = (pk >> 20) & 15;
        float r2 = rel2t[ent * 9 + ((lane < c) ? tb : 0)];
        int tl = pk & 0xFFFFF;
        const uint4* row = (const uint4*)(ent0bf + (tl << 6));
        const float* ehp = sh_eh[wid];
        float d = 0.f;
#pragma unroll
        for (int q = 0; q < 8; ++q) {
          uint4 a = row[q];
          d += bf2f(a.x & 0xFFFF) * ehp[q * 8 + 0] + bf2f(a.x >> 16) * ehp[q * 8 + 1];
          d += bf2f(a.y & 0xFFFF) * ehp[q * 8 + 2] + bf2f(a.y >> 16) * ehp[q * 8 + 3];
          d += bf2f(a.z & 0xFFFF) * ehp[q * 8 + 4] + bf2f(a.z >> 16) * ehp[q * 8 + 5];
          d += bf2f(a.w & 0xFFFF) * ehp[q * 8 + 6] + bf2f(a.w >> 16) * ehp[q * 8 + 7];
        }
        float trip = d + r2;
        if (lane < c) {
          mask_s[base + lane] = trip;
          m2l = fmaxf(m2l, trip);
        }
      }
      float m2 = waveReduceMax(m2l);
      float denl = 0.f;
      for (int base = s; base < e; base += 64) {
        int c = min(64, e - base);
        denl += (lane < c) ? expf(mask_s[base + lane] - m2) : 0.f;
      }
      float den2 = waveReduceSum(denl) + 1e-16f;
      float acc = 0.f;
      for (int base = s; base < e; base += 64) {
        int c = min(64, e - base);
        int pk = (lane < c) ? packed[base + lane] : 0;
        float mk = 0.f;
        if (lane < c) {
          mk = expf(mask_s[base + lane] - m2) / den2;
          mask_s[base + lane] = mk;
        }
        acc += kg_agg64(c, lane, pk, mk, ent0bf, wl);
      }
      float agg = acc / (float)deg;
      float nrm = sqrtf(waveReduceSum(agg * agg));
      float val = agg / fmaxf(nrm, 1e-12f);
      ent1bf[o] = f2bf(val);
      out_ent[o] = eh + val;
    }
  } else {
    __shared__ float dwl[256];
    __shared__ float latl[256];
    if (threadIdx.x < 256) {
      dwl[threadIdx.x] = dw[threadIdx.x];
      latl[threadIdx.x] = latent[threadIdx.x];
    }
    __syncthreads();
    int usr = (blockIdx.x - KG_BLOCKS) * 4 + wid;  // always < N_USR
    ui_body(usr, lane, ent0bf, sc4, user_emb, out_usr, usr1,
            uptr, cv, dwl, latl, sc4b);
  }
}

// ---------------- D2: KG hop-2 + UI hop-2 (group-layout single-pass) ----------------
__global__ void k_hop2(const ushort_t* __restrict__ srcbf,
                       float* __restrict__ out_ent,
                       const int* __restrict__ hptr, const int* __restrict__ packed,
                       const float* __restrict__ mask_s, const float* __restrict__ weight,
                       const float* __restrict__ usr1, float* __restrict__ out_usr,
                       const int* __restrict__ uptr, const int2* __restrict__ cv,
                       const float4* __restrict__ sc4,
                       const float* __restrict__ dw) {
  int lane = threadIdx.x & 63, wid = threadIdx.x >> 6;
  if (blockIdx.x < KG_BLOCKS) {
    __shared__ __align__(16) float wl[9 * WLS];
    for (int i = threadIdx.x; i < 576; i += 256) wl[(i >> 6) * WLS + (i & 63)] = weight[i];
    __syncthreads();
    int ent = blockIdx.x * 4 + wid;
    int s = hptr[ent], e = hptr[ent + 1];
    int g = lane >> 3, part = lane & 7;
    float a0 = 0.f, a1 = 0.f, a2 = 0.f, a3 = 0.f;
    float a4 = 0.f, a5 = 0.f, a6 = 0.f, a7 = 0.f;
    for (int base = s; base < e; base += 64) {
      int c = min(64, e - base);
      int pk = (lane < c) ? packed[base + lane] : 0;
      float mk = (lane < c) ? mask_s[base + lane] : 0.f;
      int nch = (c + 7) >> 3;
#pragma unroll
      for (int cc = 0; cc < 8; ++cc) {
        if (cc < nch) {
          int j = (cc << 3) + g;
          int pkj = __shfl(pk, j);    // inactive rows: pk=0 -> row 0, mkj=0
          float mkj = __shfl(mk, j);
          uint4 b = *((const uint4*)(srcbf + ((size_t)(pkj & 0xFFFFF) << 6)) + part);
          float r0 = bf2f(b.x & 0xFFFFu), r1 = bf2f(b.x >> 16);
          float r2 = bf2f(b.y & 0xFFFFu), r3 = bf2f(b.y >> 16);
          float r4 = bf2f(b.z & 0xFFFFu), r5 = bf2f(b.z >> 16);
          float r6 = bf2f(b.w & 0xFFFFu), r7 = bf2f(b.w >> 16);
          const float4* wp = (const float4*)(wl + ((pkj >> 20) & 15) * WLS + (part << 3));
          float4 w0 = wp[0], w1 = wp[1];
          a0 = fmaf(mkj * r0, w0.x, a0);
          a1 = fmaf(mkj * r1, w0.y, a1);
          a2 = fmaf(mkj * r2, w0.z, a2);
          a3 = fmaf(mkj * r3, w0.w, a3);
          a4 = fmaf(mkj * r4, w1.x, a4);
          a5 = fmaf(mkj * r5, w1.y, a5);
          a6 = fmaf(mkj * r6, w1.z, a6);
          a7 = fmaf(mkj * r7, w1.w, a7);
        }
      }
    }
    float aggv = colRT(a0, a1, a2, a3, a4, a5, a6, a7, g, part);
    float n = (float)(e - s);
    float agg = aggv / fmaxf(n, 1.0f);
    float nrm = sqrtf(waveReduceSum(agg * agg));
    float val = agg / fmaxf(nrm, 1e-12f);
    size_t o = (size_t)ent * 64 + lane;
    out_ent[o] = out_ent[o] + val;
  } else {
    __shared__ float dwl[256];
    if (threadIdx.x < 256) dwl[threadIdx.x] = dw[threadIdx.x];
    __syncthreads();
    int usr = (blockIdx.x - KG_BLOCKS) * 4 + wid;
    ui_body(usr, lane, srcbf, sc4, out_usr, out_usr, nullptr,
            uptr, cv, dwl, nullptr, nullptr);
  }
}

extern "C" void kernel_launch(void* const* d_in, const int* in_sizes, int n_in,
                              void* d_out, int out_size, void* d_ws, size_t ws_size,
                              hipStream_t stream) {
  const float* user_emb = (const float*)d_in[0];
  const float* entity_emb = (const float*)d_in[1];
  const float* latent = (const float*)d_in[2];
  const float* weight = (const float*)d_in[3];
  const float* disen = (const float*)d_in[4];
  const float* kgW = (const float*)d_in[5];
  const float* ui_vals = (const float*)d_in[6];
  const int* edge_index = (const int*)d_in[7];
  const int* edge_type = (const int*)d_in[8];
  const int* ui_rows = (const int*)d_in[9];
  const int* ui_cols = (const int*)d_in[10];
  const int* head = edge_index;
  const int* tail = edge_index + N_EDGE;

  char* ws = (char*)d_ws;
  size_t o = 0;
  auto alloc = [&](size_t bytes) -> char* {
    char* p = ws + o;
    o += (bytes + 255) & ~(size_t)255;
    return p;
  };
  int* head_ptr = (int*)alloc((N_ENT + 1) * 4);
  int* ui_ptr = (int*)alloc((N_USR + 1) * 4);
  int* cnt_u = (int*)alloc((size_t)N_USR * 4);
  int* bsum_h = (int*)alloc(1024 * 4);
  int* bsum_u = (int*)alloc(64 * 4);
  int* packed = (int*)alloc((size_t)N_EDGE * 4);
  int2* cv = (int2*)alloc((size_t)N_EDGE * 8);
  float* mask_s = (float*)alloc((size_t)N_EDGE * 4);
  ushort_t* ent0bf = (ushort_t*)alloc((size_t)N_ENT * 64 * 2);
  ushort_t* ent1bf = (ushort_t*)alloc((size_t)N_ENT * 64 * 2);
  float* usr1 = (float*)alloc((size_t)N_USR * 64 * 4);
  int* cnt9 = (int*)alloc((size_t)B9 * 4);
  int* base9 = (int*)alloc((size_t)B9 * 4);
  unsigned int* stage_kg = (unsigned int*)alloc((size_t)N_EDGE * 4);
  int2* stage_ui = (int2*)alloc((size_t)N_EDGE * 8);
  int* coarse_kg_cur = (int*)alloc(NCK * 4);
  int* coarse_ui_cur = (int*)alloc(NCU * 4);
  float* rel2t = (float*)alloc((size_t)N_ENT * 9 * 4);
  float4* sc4a = (float4*)alloc((size_t)N_USR * 16);
  float4* sc4b = (float4*)alloc((size_t)N_USR * 16);
  float* V = (float*)alloc(9 * 64 * 4);
  float* wsq = (float*)alloc(16 * 4);
  float* dw = (float*)alloc(4 * 64 * 4);
  if (o > ws_size) return;

  float* out_ent = (float*)d_out;
  float* out_usr = out_ent + (size_t)N_ENT * 64;
  float* out_cor = out_ent + (size_t)N_ENT * 64 + (size_t)N_USR * 64;

  hipMemsetAsync(cnt_u, 0, (size_t)N_USR * 4, stream);
  hipMemsetAsync(cnt9, 0, (size_t)B9 * 4, stream);

  // K1: bf16 convert + fire-and-forget count + prep + sc(user)
  k_pre<<<TB_BLOCKS + CNT_BLOCKS + 1 + SC_BLOCKS, 256, 0, stream>>>(
      entity_emb, ent0bf, head, ui_rows, edge_type, cnt_u, cnt9,
      weight, kgW, disen, V, wsq, dw, out_cor, user_emb, latent, sc4a);

  int nbh = (B9 + 1023) / 1024;       // 879
  int nbu = (N_USR + 1023) / 1024;    // 49
  // K2: fused scan-reduce over flat cnt9 | cnt_u
  k_scanred<<<nbh + nbu, 256, 0, stream>>>(cnt9, cnt_u, bsum_h, bsum_u, nbh);
  // K3: PARALLEL block-sum exclusive scans (+ sentinel ptr entries)
  k_scan_tops<<<1, 1024, 0, stream>>>(bsum_h, nbh, bsum_u, nbu, head_ptr, N_ENT, ui_ptr, N_USR, N_EDGE);
  // K4: fused scan-final -> base9 + head_ptr + coarse cursors | ui_ptr
  k_scanfin<<<nbh + nbu, 256, 0, stream>>>(cnt9, cnt_u, bsum_h, bsum_u,
                                           base9, head_ptr, ui_ptr,
                                           coarse_kg_cur, coarse_ui_cur, nbh);
  // K5a: coarse binning (block-level reservations)
  k_bin<<<BIN_BLOCKS, 1024, 0, stream>>>(
      head, tail, edge_type, ui_rows, ui_cols, ui_vals,
      coarse_kg_cur, coarse_ui_cur, stage_kg, stage_ui);
  // K5b: fine placement (LDS ranks, region-local stores) + rel2
  k_fine_rel2<<<FINEK_BLOCKS + FINEU_BLOCKS + REL2_BLOCKS, 256, 0, stream>>>(
      stage_kg, stage_ui, base9, ui_ptr, packed, cv,
      ent0bf, V, wsq, cnt9, rel2t);

  // D1: mask + fused KG hop-1 + UI hop-1 (+ sc4b epilogue)
  k_mask_kg_ui<<<KG_BLOCKS + UI_BLOCKS, 256, 0, stream>>>(
      entity_emb, ent0bf, head_ptr, packed, rel2t, mask_s, weight,
      out_ent, ent1bf, sc4a, out_usr, usr1, ui_ptr, cv, user_emb, dw, latent, sc4b);

  // D2: KG hop-2 + UI hop-2
  k_hop2<<<KG_BLOCKS + UI_BLOCKS, 256, 0, stream>>>(
      ent1bf, out_ent, head_ptr, packed, mask_s, weight,
      usr1, out_usr, ui_ptr, cv, sc4b, dw);
}

// Round 8
// 405.439 us; speedup vs baseline: 1.4339x; 1.1799x over previous
//
#include <hip/hip_runtime.h>
#include <math.h>

#define N_ENT 100000
#define N_USR 50000
#define N_EDGE 1000000
#define TEMPC 0.2f
#define KG_BLOCKS (N_ENT / 4)   // 25000, exact
#define UI_BLOCKS (N_USR / 4)   // 12500, exact

// fused-kernel block ranges
#define TB_BLOCKS 6250   // ceil(N_ENT*64/4 / 256) : bf16 convert (float4 granules)
#define CNT_BLOCKS 489   // ceil(N_EDGE/8 / 256) : coarse LDS-hist count, 8 edges/thread
#define SC_BLOCKS 196    // ceil(N_USR / 256)

// counting-sort phases
#define BIN_BLOCKS 245   // ceil(N_EDGE / (1024*4))
#define NCK 391          // KG coarse buckets: head >> 8
#define NCU 196          // UI coarse buckets: user >> 8
#define FINEK_BLOCKS NCK
#define FINEU_BLOCKS NCU

#define WLS 68   // padded stride for weight rows in LDS

typedef unsigned short ushort_t;

__device__ __forceinline__ float waveReduceSum(float x) {
#pragma unroll
  for (int d = 32; d > 0; d >>= 1) x += __shfl_xor(x, d);
  return x;
}
__device__ __forceinline__ float waveReduceMax(float x) {
#pragma unroll
  for (int d = 32; d > 0; d >>= 1) x = fmaxf(x, __shfl_xor(x, d));
  return x;
}
__device__ __forceinline__ int waveReduceSumI(int x) {
#pragma unroll
  for (int d = 32; d > 0; d >>= 1) x += __shfl_xor(x, d);
  return x;
}
__device__ __forceinline__ float bf2f(unsigned int u16) {
  union { unsigned int i; float f; } v;
  v.i = u16 << 16;
  return v.f;
}
__device__ __forceinline__ ushort_t f2bf(float f) {
  union { unsigned int i; float f; } v;
  v.f = f;
  unsigned int u = v.i;
  u = (u + 0x7FFFu + ((u >> 16) & 1u)) >> 16;
  return (ushort_t)u;
}
// wave-uniform broadcast via v_readlane -> SGPR
__device__ __forceinline__ int rl(int v, int l) { return __builtin_amdgcn_readlane(v, l); }
__device__ __forceinline__ float rlf(float v, int l) {
  return __int_as_float(__builtin_amdgcn_readlane(__float_as_int(v), l));
}

// column-partial reduce over g (masks 8/16/32) + 8x8 wave transpose
__device__ __forceinline__ float colRT(float a0, float a1, float a2, float a3,
                                       float a4, float a5, float a6, float a7,
                                       int g, int part) {
#define RED3(x) x += __shfl_xor(x, 8); x += __shfl_xor(x, 16); x += __shfl_xor(x, 32);
  RED3(a0) RED3(a1) RED3(a2) RED3(a3) RED3(a4) RED3(a5) RED3(a6) RED3(a7)
#undef RED3
  float t0 = __shfl(a0, g), t1 = __shfl(a1, g), t2 = __shfl(a2, g), t3 = __shfl(a3, g);
  float t4 = __shfl(a4, g), t5 = __shfl(a5, g), t6 = __shfl(a6, g), t7 = __shfl(a7, g);
  float r = t0;
  r = (part == 1) ? t1 : r;
  r = (part == 2) ? t2 : r;
  r = (part == 3) ? t3 : r;
  r = (part == 4) ? t4 : r;
  r = (part == 5) ? t5 : r;
  r = (part == 6) ? t6 : r;
  r = (part == 7) ? t7 : r;
  return r;
}

// ============ K1: bf16 convert | coarse-hist count (8/thr) | prep | sc(user) ============
__global__ void k_pre(const float* __restrict__ ent0, ushort_t* __restrict__ ent0bf,
                      const int* __restrict__ head, const int* __restrict__ uir,
                      int* __restrict__ ccnt_kg, int* __restrict__ ccnt_ui,
                      const float* __restrict__ weight, const float* __restrict__ kgW,
                      const float* __restrict__ disen,
                      float* __restrict__ V, float* __restrict__ wsq,
                      float* __restrict__ dw, float* __restrict__ cor_out,
                      const float* __restrict__ user_emb, const float* __restrict__ latent,
                      float4* __restrict__ sc4a) {
  int bid = blockIdx.x;
  if (bid < TB_BLOCKS) {
    int i = bid * 256 + threadIdx.x;
    if (i < N_ENT * 16) {
      float4 v = ((const float4*)ent0)[i];
      ushort4 o;
      o.x = f2bf(v.x); o.y = f2bf(v.y); o.z = f2bf(v.z); o.w = f2bf(v.w);
      ((ushort4*)ent0bf)[i] = o;
    }
  } else if (bid < TB_BLOCKS + CNT_BLOCKS) {
    // coarse counting: per-block LDS histogram, then ~600 fire-and-forget
    // global adds per block (287K total, vs 2M scattered fine-grained before)
    __shared__ int histK[NCK], histU[NCU];
    int tid = threadIdx.x;
    for (int i = tid; i < NCK; i += 256) histK[i] = 0;
    for (int i = tid; i < NCU; i += 256) histU[i] = 0;
    __syncthreads();
    int i0 = ((bid - TB_BLOCKS) * 256 + tid) * 8;
    if (i0 < N_EDGE) {
      int4 ha = *(const int4*)(head + i0), hb = *(const int4*)(head + i0 + 4);
      int4 ua = *(const int4*)(uir + i0), ub = *(const int4*)(uir + i0 + 4);
      atomicAdd(&histK[ha.x >> 8], 1);
      atomicAdd(&histK[ha.y >> 8], 1);
      atomicAdd(&histK[ha.z >> 8], 1);
      atomicAdd(&histK[ha.w >> 8], 1);
      atomicAdd(&histK[hb.x >> 8], 1);
      atomicAdd(&histK[hb.y >> 8], 1);
      atomicAdd(&histK[hb.z >> 8], 1);
      atomicAdd(&histK[hb.w >> 8], 1);
      atomicAdd(&histU[ua.x >> 8], 1);
      atomicAdd(&histU[ua.y >> 8], 1);
      atomicAdd(&histU[ua.z >> 8], 1);
      atomicAdd(&histU[ua.w >> 8], 1);
      atomicAdd(&histU[ub.x >> 8], 1);
      atomicAdd(&histU[ub.y >> 8], 1);
      atomicAdd(&histU[ub.z >> 8], 1);
      atomicAdd(&histU[ub.w >> 8], 1);
    }
    __syncthreads();
    for (int i = tid; i < NCK; i += 256)
      if (histK[i] > 0) atomicAdd(&ccnt_kg[i], histK[i]);
    for (int i = tid; i < NCU; i += 256)
      if (histU[i] > 0) atomicAdd(&ccnt_ui[i], histU[i]);
  } else if (bid == TB_BLOCKS + CNT_BLOCKS) {
    // ---- prep: V=(W W^T)w_r via T-factorization, wsq, dw, cor ----
    __shared__ float T[9 * 64];
    __shared__ float sm[4 * 9];
    int tid = threadIdx.x;
    for (int e = tid; e < 9 * 64; e += 256) {
      int r = e >> 6, d = e & 63;
      float s = 0.f;
      for (int k = 0; k < 64; ++k) s += kgW[k * 64 + d] * weight[r * 64 + k];
      T[e] = s;
    }
    if (tid < 4) {
      float m = -INFINITY;
      for (int r = 0; r < 9; ++r) m = fmaxf(m, disen[tid * 9 + r]);
      float den = 0.f;
      float ex[9];
      for (int r = 0; r < 9; ++r) { ex[r] = expf(disen[tid * 9 + r] - m); den += ex[r]; }
      for (int r = 0; r < 9; ++r) sm[tid * 9 + r] = ex[r] / den;
    }
    __syncthreads();
    for (int e = tid; e < 9 * 64; e += 256) {
      int r = e >> 6, i = e & 63;
      float s = 0.f;
      for (int d = 0; d < 64; ++d) s += kgW[i * 64 + d] * T[r * 64 + d];
      V[e] = s;
    }
    if (tid < 9) {
      float s = 0.f;
      for (int c = 0; c < 64; ++c) { float w = weight[tid * 64 + c]; s += w * w; }
      wsq[tid] = s;
    }
    for (int e = tid; e < 4 * 64; e += 256) {
      int f = e >> 6, c = e & 63;
      float s = 0.f;
      for (int r = 0; r < 9; ++r) s += sm[f * 9 + r] * weight[r * 64 + c];
      dw[e] = s;
    }
    if (tid == 0) {
      float rowsum[4];
      for (int f = 0; f < 4; ++f) {
        float s = 0.f;
        for (int j = 0; j < 9; ++j) s += disen[f * 9 + j];
        rowsum[f] = s;
      }
      float cor = 0.f;
      for (int i = 0; i < 9; ++i) {
        float n2 = 0.f, ttl = 0.f;
        for (int f = 0; f < 4; ++f) {
          float v = disen[f * 9 + i];
          n2 += v * v;
          ttl += v * rowsum[f];
        }
        float nrm = sqrtf(n2);
        float pos = 0.f;
        for (int f = 0; f < 4; ++f) {
          float v = disen[f * 9 + i] / nrm;
          pos += v * v;
        }
        cor += (ttl - pos) / TEMPC;
      }
      *cor_out = cor;
    }
  } else {
    // ---- sc on user_emb -> sc4a ----
    __shared__ __align__(16) float lat[256];
    if (threadIdx.x < 256) lat[threadIdx.x] = latent[threadIdx.x];
    __syncthreads();
    int u = (bid - TB_BLOCKS - CNT_BLOCKS - 1) * 256 + threadIdx.x;
    if (u >= N_USR) return;
    float a0 = 0.f, a1 = 0.f, a2 = 0.f, a3 = 0.f;
    const float4* row = (const float4*)(user_emb + (size_t)u * 64);
#pragma unroll
    for (int q = 0; q < 16; ++q) {
      float4 v = row[q];
      float4 l0 = *(const float4*)(lat + 0 * 64 + q * 4);
      float4 l1 = *(const float4*)(lat + 1 * 64 + q * 4);
      float4 l2 = *(const float4*)(lat + 2 * 64 + q * 4);
      float4 l3 = *(const float4*)(lat + 3 * 64 + q * 4);
      a0 = fmaf(v.x, l0.x, a0); a0 = fmaf(v.y, l0.y, a0); a0 = fmaf(v.z, l0.z, a0); a0 = fmaf(v.w, l0.w, a0);
      a1 = fmaf(v.x, l1.x, a1); a1 = fmaf(v.y, l1.y, a1); a1 = fmaf(v.z, l1.z, a1); a1 = fmaf(v.w, l1.w, a1);
      a2 = fmaf(v.x, l2.x, a2); a2 = fmaf(v.y, l2.y, a2); a2 = fmaf(v.z, l2.z, a2); a2 = fmaf(v.w, l2.w, a2);
      a3 = fmaf(v.x, l3.x, a3); a3 = fmaf(v.y, l3.y, a3); a3 = fmaf(v.z, l3.z, a3); a3 = fmaf(v.w, l3.w, a3);
    }
    sc4a[u] = make_float4(a0, a1, a2, a3);
  }
}

// ============ K2: scan coarse counts -> coarse bases + bin cursors + sentinels ============
__global__ void __launch_bounds__(1024) k_scan_coarse(
    const int* __restrict__ ccnt_kg, const int* __restrict__ ccnt_ui,
    int* __restrict__ cbase_kg, int* __restrict__ cbase_ui,
    int* __restrict__ cur_kg, int* __restrict__ cur_ui,
    int* __restrict__ head_ptr, int* __restrict__ ui_ptr) {
  __shared__ int wsum[16];
  int tid = threadIdx.x, lane = tid & 63, wid = tid >> 6;
  // ---- KG (NCK <= 1024) ----
  int v = (tid < NCK) ? ccnt_kg[tid] : 0;
  int x = v;
#pragma unroll
  for (int d = 1; d < 64; d <<= 1) {
    int y = __shfl_up(x, d);
    if (lane >= d) x += y;
  }
  if (lane == 63) wsum[wid] = x;
  __syncthreads();
  if (tid == 0) {
    int a = 0;
    for (int w = 0; w < 16; ++w) { int t = wsum[w]; wsum[w] = a; a += t; }
  }
  __syncthreads();
  int base = x - v + wsum[wid];
  if (tid < NCK) { cbase_kg[tid] = base; cur_kg[tid] = base; }
  if (tid == 0) { cbase_kg[NCK] = N_EDGE; head_ptr[N_ENT] = N_EDGE; }
  __syncthreads();
  // ---- UI (NCU <= 1024) ----
  int vu = (tid < NCU) ? ccnt_ui[tid] : 0;
  int xu = vu;
#pragma unroll
  for (int d = 1; d < 64; d <<= 1) {
    int y = __shfl_up(xu, d);
    if (lane >= d) xu += y;
  }
  if (lane == 63) wsum[wid] = xu;
  __syncthreads();
  if (tid == 0) {
    int a = 0;
    for (int w = 0; w < 16; ++w) { int t = wsum[w]; wsum[w] = a; a += t; }
  }
  __syncthreads();
  int bu = xu - vu + wsum[wid];
  if (tid < NCU) { cbase_ui[tid] = bu; cur_ui[tid] = bu; }
  if (tid == 0) { cbase_ui[NCU] = N_EDGE; ui_ptr[N_USR] = N_EDGE; }
}

// ============ K3: coarse binning (block-level reservations, NO per-edge return-atomics) ============
__global__ void __launch_bounds__(1024) k_bin(
    const int* __restrict__ head, const int* __restrict__ tail,
    const int* __restrict__ etype,
    const int* __restrict__ uir, const int* __restrict__ uic,
    const float* __restrict__ uival,
    int* __restrict__ coarse_kg_cur, int* __restrict__ coarse_ui_cur,
    unsigned int* __restrict__ stage_kg, int2* __restrict__ stage_ui) {
  __shared__ int histK[NCK], histU[NCU];
  int tid = threadIdx.x;
  for (int i = tid; i < NCK; i += 1024) histK[i] = 0;
  for (int i = tid; i < NCU; i += 1024) histU[i] = 0;
  __syncthreads();
  int i0 = (blockIdx.x * 1024 + tid) * 4;
  bool valid = (i0 < N_EDGE);
  int4 h4, t4v, e4, r4, c4;
  float4 v4;
  int k0 = 0, k1 = 0, k2 = 0, k3 = 0, u0 = 0, u1 = 0, u2 = 0, u3 = 0;
  if (valid) {
    h4 = *(const int4*)(head + i0);
    t4v = *(const int4*)(tail + i0);
    e4 = *(const int4*)(etype + i0);
    r4 = *(const int4*)(uir + i0);
    c4 = *(const int4*)(uic + i0);
    v4 = *(const float4*)(uival + i0);
    k0 = atomicAdd(&histK[h4.x >> 8], 1);
    k1 = atomicAdd(&histK[h4.y >> 8], 1);
    k2 = atomicAdd(&histK[h4.z >> 8], 1);
    k3 = atomicAdd(&histK[h4.w >> 8], 1);
    u0 = atomicAdd(&histU[r4.x >> 8], 1);
    u1 = atomicAdd(&histU[r4.y >> 8], 1);
    u2 = atomicAdd(&histU[r4.z >> 8], 1);
    u3 = atomicAdd(&histU[r4.w >> 8], 1);
  }
  __syncthreads();
  // block-level reservation: ONE global return-atomic per (block, nonempty bucket)
  if (tid < NCK) {
    int c = histK[tid];
    histK[tid] = (c > 0) ? atomicAdd(&coarse_kg_cur[tid], c) : 0;
  } else if (tid >= 512 && tid < 512 + NCU) {
    int bu = tid - 512;
    int c = histU[bu];
    histU[bu] = (c > 0) ? atomicAdd(&coarse_ui_cur[bu], c) : 0;
  }
  __syncthreads();
  if (valid) {
    // staged KG word: tail(0:19) | rel(20:23) | head&255(24:31)
    stage_kg[histK[h4.x >> 8] + k0] =
        (unsigned int)(t4v.x | ((e4.x - 1) << 20) | ((h4.x & 255) << 24));
    stage_kg[histK[h4.y >> 8] + k1] =
        (unsigned int)(t4v.y | ((e4.y - 1) << 20) | ((h4.y & 255) << 24));
    stage_kg[histK[h4.z >> 8] + k2] =
        (unsigned int)(t4v.z | ((e4.z - 1) << 20) | ((h4.z & 255) << 24));
    stage_kg[histK[h4.w >> 8] + k3] =
        (unsigned int)(t4v.w | ((e4.w - 1) << 20) | ((h4.w & 255) << 24));
    // staged UI: {col(0:23) | user&255(24:31), val}
    stage_ui[histU[r4.x >> 8] + u0] = make_int2(c4.x | ((r4.x & 255) << 24), __float_as_int(v4.x));
    stage_ui[histU[r4.y >> 8] + u1] = make_int2(c4.y | ((r4.y & 255) << 24), __float_as_int(v4.y));
    stage_ui[histU[r4.z >> 8] + u2] = make_int2(c4.z | ((r4.z & 255) << 24), __float_as_int(v4.z));
    stage_ui[histU[r4.w >> 8] + u3] = make_int2(c4.w | ((r4.w & 255) << 24), __float_as_int(v4.w));
  }
}

// ============ K4: fine placement, fully self-contained per coarse bucket:
//   LDS histogram -> per-entity rel prefix + block scan -> head_ptr/ui_ptr ->
//   place pass -> rel2 (counts already in LDS). No global cnt9/base9 at all. ============
__global__ void k_fine_rel2(const unsigned int* __restrict__ stage_kg,
                            const int2* __restrict__ stage_ui,
                            const int* __restrict__ cbase_kg, const int* __restrict__ cbase_ui,
                            int* __restrict__ packed, int2* __restrict__ cv,
                            int* __restrict__ head_ptr, int* __restrict__ ui_ptr,
                            const ushort_t* __restrict__ ent0bf, const float* __restrict__ V,
                            const float* __restrict__ wsq, float* __restrict__ rel2t) {
  int tid = threadIdx.x;
  int lane = tid & 63, wid = tid >> 6;
  if (blockIdx.x < FINEK_BLOCKS) {
    int b = blockIdx.x;
    __shared__ int lbase[2304];  // 256 heads x 9 rels
    __shared__ int lcnt[2304];
    __shared__ __align__(16) float Vl[576];
    __shared__ float wsql[9];
    __shared__ int woff[4];
    for (int i = tid; i < 2304; i += 256) lcnt[i] = 0;
    for (int i = tid; i < 576; i += 256) Vl[i] = V[i];
    if (tid < 9) wsql[tid] = wsq[tid];
    int cs = cbase_kg[b], ce = cbase_kg[b + 1];
    int gb = b << 8;
    int ne = min(256, N_ENT - gb);
    __syncthreads();
    // pass 1: histogram of this bucket's staged edges
    for (int i = cs + tid; i < ce; i += 256) {
      unsigned int w = stage_kg[i];
      int key = (int)((w >> 24) & 255u) * 9 + (int)((w >> 20) & 15u);
      atomicAdd(&lcnt[key], 1);
    }
    __syncthreads();
    // pass 2: per-entity rel prefix (regs) + block exclusive scan of entity degrees
    int pre9[9];
    int deg = 0;
    if (tid < ne) {
#pragma unroll
      for (int r = 0; r < 9; ++r) { pre9[r] = deg; deg += lcnt[tid * 9 + r]; }
    }
    int x = deg;
#pragma unroll
    for (int d = 1; d < 64; d <<= 1) {
      int y = __shfl_up(x, d);
      if (lane >= d) x += y;
    }
    if (lane == 63) woff[wid] = x;
    __syncthreads();
    if (tid == 0) {
      int a = 0;
      for (int w2 = 0; w2 < 4; ++w2) { int t = woff[w2]; woff[w2] = a; a += t; }
    }
    __syncthreads();
    int ebase = cs + (x - deg) + woff[wid];
    if (tid < ne) {
      head_ptr[gb + tid] = ebase;
#pragma unroll
      for (int r = 0; r < 9; ++r) lbase[tid * 9 + r] = ebase + pre9[r];
    }
    __syncthreads();
    // reset counters for rank pass
    for (int i = tid; i < 2304; i += 256) lcnt[i] = 0;
    __syncthreads();
    // pass 3: place (stores land in this block's contiguous CSR region)
    for (int i = cs + tid; i < ce; i += 256) {
      unsigned int w = stage_kg[i];
      int key = (int)((w >> 24) & 255u) * 9 + (int)((w >> 20) & 15u);
      int r = atomicAdd(&lcnt[key], 1);
      packed[lbase[key] + r] = (int)(w & 0xFFFFFFu);  // tail | rel<<20
    }
    __syncthreads();
    // pass 4: rel2 for this block's entities (lcnt holds per-(ent,rel) counts again)
    if (tid < ne) {
      int ent = gb + tid;
      float a[9] = {0, 0, 0, 0, 0, 0, 0, 0, 0};
      const uint4* row = (const uint4*)(ent0bf + ((size_t)ent << 6));
#pragma unroll
      for (int q = 0; q < 8; ++q) {
        uint4 bq = row[q];
        float ch0 = bf2f(bq.x & 0xFFFFu), ch1 = bf2f(bq.x >> 16);
        float ch2 = bf2f(bq.y & 0xFFFFu), ch3 = bf2f(bq.y >> 16);
        float ch4 = bf2f(bq.z & 0xFFFFu), ch5 = bf2f(bq.z >> 16);
        float ch6 = bf2f(bq.w & 0xFFFFu), ch7 = bf2f(bq.w >> 16);
#pragma unroll
        for (int r = 0; r < 9; ++r) {
          const float4* vp = (const float4*)(Vl + r * 64 + q * 8);
          float4 v0 = vp[0], v1 = vp[1];
          float t = a[r];
          t = fmaf(ch0, v0.x, t); t = fmaf(ch1, v0.y, t);
          t = fmaf(ch2, v0.z, t); t = fmaf(ch3, v0.w, t);
          t = fmaf(ch4, v1.x, t); t = fmaf(ch5, v1.y, t);
          t = fmaf(ch6, v1.z, t); t = fmaf(ch7, v1.w, t);
          a[r] = t;
        }
      }
      const float inv2s = 0.08838834764831845f;  // 1/(2*sqrt(32))
      int cnt[9];
#pragma unroll
      for (int r = 0; r < 9; ++r) cnt[r] = lcnt[tid * 9 + r];
      float m1 = -INFINITY;
#pragma unroll
      for (int r = 0; r < 9; ++r)
        if (cnt[r] > 0) m1 = fmaxf(m1, a[r] * inv2s);
      if (m1 == -INFINITY) {
#pragma unroll
        for (int r = 0; r < 9; ++r) rel2t[ent * 9 + r] = 0.f;
      } else {
        float den1 = 1e-16f;
#pragma unroll
        for (int r = 0; r < 9; ++r)
          if (cnt[r] > 0) den1 += (float)cnt[r] * expf(a[r] * inv2s - m1);
#pragma unroll
        for (int r = 0; r < 9; ++r) {
          float rs = expf(a[r] * inv2s - m1) / den1;
          rel2t[ent * 9 + r] = rs * rs * wsql[r];
        }
      }
    }
  } else {
    // ---- UI fine placement ----
    int b = blockIdx.x - FINEK_BLOCKS;
    __shared__ int lbu[256];
    __shared__ int lcu[256];
    __shared__ int woff2[4];
    lcu[tid] = 0;
    int cs = cbase_ui[b], ce = cbase_ui[b + 1];
    int gb = b << 8;
    int nu = min(256, N_USR - gb);
    __syncthreads();
    for (int i = cs + tid; i < ce; i += 256) {
      int2 d = stage_ui[i];
      atomicAdd(&lcu[(d.x >> 24) & 255], 1);
    }
    __syncthreads();
    int deg = (tid < nu) ? lcu[tid] : 0;
    int x = deg;
#pragma unroll
    for (int d = 1; d < 64; d <<= 1) {
      int y = __shfl_up(x, d);
      if (lane >= d) x += y;
    }
    if (lane == 63) woff2[wid] = x;
    __syncthreads();
    if (tid == 0) {
      int a = 0;
      for (int w2 = 0; w2 < 4; ++w2) { int t = woff2[w2]; woff2[w2] = a; a += t; }
    }
    __syncthreads();
    int ubase = cs + (x - deg) + woff2[wid];
    __syncthreads();
    if (tid < nu) {
      ui_ptr[gb + tid] = ubase;
      lbu[tid] = ubase;
    }
    lcu[tid] = 0;
    __syncthreads();
    for (int i = cs + tid; i < ce; i += 256) {
      int2 d = stage_ui[i];
      int key = (d.x >> 24) & 255;
      int r = atomicAdd(&lcu[key], 1);
      cv[lbu[key] + r] = make_int2(d.x & 0xFFFFFF, d.y);
    }
  }
}

// KG aggregation inner (readlane broadcasts, 4 acc chains) — generic fallback
__device__ __forceinline__ float kg_agg64(int deg, int lane, int pk, float mk,
                                          const ushort_t* __restrict__ srcbf,
                                          const float* __restrict__ wl) {
  float a0 = 0.f, a1 = 0.f, a2 = 0.f, a3 = 0.f;
  int j = 0;
  for (; j + 4 <= deg; j += 4) {
    int p0 = rl(pk, j), p1 = rl(pk, j + 1), p2 = rl(pk, j + 2), p3 = rl(pk, j + 3);
    float k0 = rlf(mk, j), k1 = rlf(mk, j + 1), k2 = rlf(mk, j + 2), k3 = rlf(mk, j + 3);
    float r0 = bf2f(srcbf[((p0 & 0xFFFFF) << 6) + lane]);
    float r1 = bf2f(srcbf[((p1 & 0xFFFFF) << 6) + lane]);
    float r2 = bf2f(srcbf[((p2 & 0xFFFFF) << 6) + lane]);
    float r3 = bf2f(srcbf[((p3 & 0xFFFFF) << 6) + lane]);
    a0 = fmaf(r0 * wl[((p0 >> 20) & 15) * WLS + lane], k0, a0);
    a1 = fmaf(r1 * wl[((p1 >> 20) & 15) * WLS + lane], k1, a1);
    a2 = fmaf(r2 * wl[((p2 >> 20) & 15) * WLS + lane], k2, a2);
    a3 = fmaf(r3 * wl[((p3 >> 20) & 15) * WLS + lane], k3, a3);
  }
  for (; j < deg; ++j) {
    int pj = rl(pk, j);
    float kj = rlf(mk, j);
    a0 = fmaf(bf2f(srcbf[((pj & 0xFFFFF) << 6) + lane]) * wl[((pj >> 20) & 15) * WLS + lane], kj, a0);
  }
  return (a0 + a1) + (a2 + a3);
}

// ---------------- UI aggregation body (group-layout single-pass) ----------------
__device__ __forceinline__ void ui_body(int usr, int lane,
                                        const ushort_t* __restrict__ srcbf,
                                        const float4* __restrict__ sc4,
                                        const float* __restrict__ addb,
                                        float* __restrict__ outp, float* __restrict__ nxt,
                                        const int* __restrict__ uptr,
                                        const int2* __restrict__ cv,
                                        const float* __restrict__ dwl,
                                        const float* __restrict__ latl,
                                        float4* __restrict__ sc4out) {
  float4 s4 = sc4[usr];
  float m = fmaxf(fmaxf(s4.x, s4.y), fmaxf(s4.z, s4.w));
  float e0 = expf(s4.x - m), e1 = expf(s4.y - m), e2 = expf(s4.z - m), e3 = expf(s4.w - m);
  float den = e0 + e1 + e2 + e3;
  float mix = (e0 * dwl[lane] + e1 * dwl[64 + lane] + e2 * dwl[128 + lane] + e3 * dwl[192 + lane]) / den;
  int s = uptr[usr], e = uptr[usr + 1];
  int g = lane >> 3, part = lane & 7;
  float a0 = 0.f, a1 = 0.f, a2 = 0.f, a3 = 0.f;
  float a4 = 0.f, a5 = 0.f, a6 = 0.f, a7 = 0.f;
  for (int base = s; base < e; base += 64) {
    int c = min(64, e - base);
    int2 cvl = (lane < c) ? cv[base + lane] : make_int2(0, 0);
    int cl = cvl.x;
    float vl = __int_as_float(cvl.y);
    int nch = (c + 7) >> 3;
#pragma unroll
    for (int cc = 0; cc < 8; ++cc) {
      if (cc < nch) {
        int j = (cc << 3) + g;
        int cj = __shfl(cl, j);       // inactive rows broadcast 0 -> row 0, vj=0
        float vj = __shfl(vl, j);
        uint4 b = *((const uint4*)(srcbf + ((size_t)cj << 6)) + part);
        a0 = fmaf(bf2f(b.x & 0xFFFFu), vj, a0);
        a1 = fmaf(bf2f(b.x >> 16), vj, a1);
        a2 = fmaf(bf2f(b.y & 0xFFFFu), vj, a2);
        a3 = fmaf(bf2f(b.y >> 16), vj, a3);
        a4 = fmaf(bf2f(b.z & 0xFFFFu), vj, a4);
        a5 = fmaf(bf2f(b.z >> 16), vj, a5);
        a6 = fmaf(bf2f(b.w & 0xFFFFu), vj, a6);
        a7 = fmaf(bf2f(b.w >> 16), vj, a7);
      }
    }
  }
  float acc = colRT(a0, a1, a2, a3, a4, a5, a6, a7, g, part);
  float ua = acc * mix + acc;
  float nrm = sqrtf(waveReduceSum(ua * ua));
  float val = ua / fmaxf(nrm, 1e-12f);
  size_t o = (size_t)usr * 64 + lane;
  if (nxt) nxt[o] = val;
  outp[o] = addb[o] + val;
  if (sc4out) {
    // fused hop-2 factor scores: sc4b[usr] = val @ latent^T
    float s0 = waveReduceSum(val * latl[lane]);
    float s1 = waveReduceSum(val * latl[64 + lane]);
    float s2 = waveReduceSum(val * latl[128 + lane]);
    float s3 = waveReduceSum(val * latl[192 + lane]);
    if (lane == 0) sc4out[usr] = make_float4(s0, s1, s2, s3);
  }
}

// ---------------- D1: mask + fused KG hop-1  |  UI hop-1 (+sc4b) ----------------
__global__ void k_mask_kg_ui(const float* __restrict__ ent0,
                             const ushort_t* __restrict__ ent0bf,
                             const int* __restrict__ hptr, const int* __restrict__ packed,
                             const float* __restrict__ rel2t,
                             float* __restrict__ mask_s, const float* __restrict__ weight,
                             float* __restrict__ out_ent, ushort_t* __restrict__ ent1bf,
                             const float4* __restrict__ sc4,
                             float* __restrict__ out_usr,
                             float* __restrict__ usr1, const int* __restrict__ uptr,
                             const int2* __restrict__ cv,
                             const float* __restrict__ user_emb, const float* __restrict__ dw,
                             const float* __restrict__ latent, float4* __restrict__ sc4b) {
  int lane = threadIdx.x & 63, wid = threadIdx.x >> 6;
  if (blockIdx.x < KG_BLOCKS) {
    __shared__ __align__(16) float sh_eh[4][64];
    __shared__ __align__(16) float wl[9 * WLS];
    for (int i = threadIdx.x; i < 576; i += 256) wl[(i >> 6) * WLS + (i & 63)] = weight[i];
    int ent = blockIdx.x * 4 + wid;  // always < N_ENT
    int s = hptr[ent], e = hptr[ent + 1];
    float eh = ent0[(size_t)ent * 64 + lane];
    sh_eh[wid][lane] = eh;
    __syncthreads();
    size_t o = (size_t)ent * 64 + lane;
    int deg = e - s;
    if (deg == 0) {
      ent1bf[o] = f2bf(0.f);
      out_ent[o] = eh;
      return;
    }
    if (deg <= 64) {
      // ---- single-pass hot path: group-layout dot + DIRECT-EXP softmax. ----
      int pk = (lane < deg) ? packed[s + lane] : 0;
      int tb = (pk >> 20) & 15;
      float r2sel = rel2t[ent * 9 + ((lane < deg) ? tb : 0)];
      int g = lane >> 3, part = lane & 7;
      const float4* ehq = (const float4*)(sh_eh[wid] + (part << 3));
      float4 ef0 = ehq[0], ef1 = ehq[1];
      int nch = (deg + 7) >> 3;
      float den = 0.f;
      float acc0 = 0.f, acc1 = 0.f, acc2 = 0.f, acc3 = 0.f;
      float acc4 = 0.f, acc5 = 0.f, acc6 = 0.f, acc7 = 0.f;
      float ws8[8];
#pragma unroll
      for (int cc = 0; cc < 8; ++cc) {
        ws8[cc] = 0.f;
        if (cc < nch) {
          int j = (cc << 3) + g;  // row handled by this lane's group slot
          int pkj = __shfl(pk, j);  // inactive rows broadcast pk=0 -> row 0 (safe)
          uint4 b = *((const uint4*)(ent0bf + ((size_t)(pkj & 0xFFFFF) << 6)) + part);
          float r0 = bf2f(b.x & 0xFFFFu), r1 = bf2f(b.x >> 16);
          float r2 = bf2f(b.y & 0xFFFFu), r3 = bf2f(b.y >> 16);
          float r4 = bf2f(b.z & 0xFFFFu), r5 = bf2f(b.z >> 16);
          float r6 = bf2f(b.w & 0xFFFFu), r7 = bf2f(b.w >> 16);
          // partial dot over this lane's 8 columns, reduce over part (masks 1,2,4)
          float s0 = r0 * ef0.x, s1 = r2 * ef0.z, s2 = r4 * ef1.x, s3 = r6 * ef1.z;
          s0 = fmaf(r1, ef0.y, s0); s1 = fmaf(r3, ef0.w, s1);
          s2 = fmaf(r5, ef1.y, s2); s3 = fmaf(r7, ef1.w, s3);
          float sv = (s0 + s1) + (s2 + s3);
          sv += __shfl_xor(sv, 1);
          sv += __shfl_xor(sv, 2);
          sv += __shfl_xor(sv, 4);
          float r2j = __shfl(r2sel, j);
          float w = (j < deg) ? expf(sv + r2j) : 0.f;
          ws8[cc] = w;
          den += w;
          // weighted row accumulate into this lane's 8 columns
          const float4* wp = (const float4*)(wl + ((pkj >> 20) & 15) * WLS + (part << 3));
          float4 w0 = wp[0], w1 = wp[1];
          acc0 = fmaf(w * r0, w0.x, acc0);
          acc1 = fmaf(w * r1, w0.y, acc1);
          acc2 = fmaf(w * r2, w0.z, acc2);
          acc3 = fmaf(w * r3, w0.w, acc3);
          acc4 = fmaf(w * r4, w1.x, acc4);
          acc5 = fmaf(w * r5, w1.y, acc5);
          acc6 = fmaf(w * r6, w1.z, acc6);
          acc7 = fmaf(w * r7, w1.w, acc7);
        }
      }
      // full softmax denominator (sum over g: each row counted once per part-octet)
      float den2 = den;
      den2 += __shfl_xor(den2, 8);
      den2 += __shfl_xor(den2, 16);
      den2 += __shfl_xor(den2, 32);
      den2 += 1e-16f;
      float invden = 1.0f / den2;
      // write mask_s (per-chunk: lanes with part==0 write their group's row)
#pragma unroll
      for (int cc = 0; cc < 8; ++cc) {
        if (cc < nch) {
          int j = (cc << 3) + g;
          if (part == 0 && j < deg) mask_s[s + j] = ws8[cc] * invden;
        }
      }
      float aggv = colRT(acc0, acc1, acc2, acc3, acc4, acc5, acc6, acc7, g, part);
      float agg = aggv * invden / (float)deg;
      float nrm = sqrtf(waveReduceSum(agg * agg));
      float val = agg / fmaxf(nrm, 1e-12f);
      ent1bf[o] = f2bf(val);
      out_ent[o] = eh + val;
    } else {
      // ---- generic multi-chunk path (deg>64) ----
      float m2l = -INFINITY;
      for (int base = s; base < e; base += 64) {
        int c = min(64, e - base);
        int pk = (lane < c) ? packed[base + lane] : 0;
        int tb = (pk >> 20) & 15;
        float r2 = rel2t[ent * 9 + ((lane < c) ? tb : 0)];
        int tl = pk & 0xFFFFF;
        const uint4* row = (const uint4*)(ent0bf + (tl << 6));
        const float* ehp = sh_eh[wid];
        float d = 0.f;
#pragma unroll
        for (int q = 0; q < 8; ++q) {
          uint4 a = row[q];
          d += bf2f(a.x & 0xFFFF) * ehp[q * 8 + 0] + bf2f(a.x >> 16) * ehp[q * 8 + 1];
          d += bf2f(a.y & 0xFFFF) * ehp[q * 8 + 2] + bf2f(a.y >> 16) * ehp[q * 8 + 3];
          d += bf2f(a.z & 0xFFFF) * ehp[q * 8 + 4] + bf2f(a.z >> 16) * ehp[q * 8 + 5];
          d += bf2f(a.w & 0xFFFF) * ehp[q * 8 + 6] + bf2f(a.w >> 16) * ehp[q * 8 + 7];
        }
        float trip = d + r2;
        if (lane < c) {
          mask_s[base + lane] = trip;
          m2l = fmaxf(m2l, trip);
        }
      }
      float m2 = waveReduceMax(m2l);
      float denl = 0.f;
      for (int base = s; base < e; base += 64) {
        int c = min(64, e - base);
        denl += (lane < c) ? expf(mask_s[base + lane] - m2) : 0.f;
      }
      float den2 = waveReduceSum(denl) + 1e-16f;
      float acc = 0.f;
      for (int base = s; base < e; base += 64) {
        int c = min(64, e - base);
        int pk = (lane < c) ? packed[base + lane] : 0;
        float mk = 0.f;
        if (lane < c) {
          mk = expf(mask_s[base + lane] - m2) / den2;
          mask_s[base + lane] = mk;
        }
        acc += kg_agg64(c, lane, pk, mk, ent0bf, wl);
      }
      float agg = acc / (float)deg;
      float nrm = sqrtf(waveReduceSum(agg * agg));
      float val = agg / fmaxf(nrm, 1e-12f);
      ent1bf[o] = f2bf(val);
      out_ent[o] = eh + val;
    }
  } else {
    __shared__ float dwl[256];
    __shared__ float latl[256];
    if (threadIdx.x < 256) {
      dwl[threadIdx.x] = dw[threadIdx.x];
      latl[threadIdx.x] = latent[threadIdx.x];
    }
    __syncthreads();
    int usr = (blockIdx.x - KG_BLOCKS) * 4 + wid;  // always < N_USR
    ui_body(usr, lane, ent0bf, sc4, user_emb, out_usr, usr1,
            uptr, cv, dwl, latl, sc4b);
  }
}

// ---------------- D2: KG hop-2 + UI hop-2 (group-layout single-pass) ----------------
__global__ void k_hop2(const ushort_t* __restrict__ srcbf,
                       float* __restrict__ out_ent,
                       const int* __restrict__ hptr, const int* __restrict__ packed,
                       const float* __restrict__ mask_s, const float* __restrict__ weight,
                       const float* __restrict__ usr1, float* __restrict__ out_usr,
                       const int* __restrict__ uptr, const int2* __restrict__ cv,
                       const float4* __restrict__ sc4,
                       const float* __restrict__ dw) {
  int lane = threadIdx.x & 63, wid = threadIdx.x >> 6;
  if (blockIdx.x < KG_BLOCKS) {
    __shared__ __align__(16) float wl[9 * WLS];
    for (int i = threadIdx.x; i < 576; i += 256) wl[(i >> 6) * WLS + (i & 63)] = weight[i];
    __syncthreads();
    int ent = blockIdx.x * 4 + wid;
    int s = hptr[ent], e = hptr[ent + 1];
    int g = lane >> 3, part = lane & 7;
    float a0 = 0.f, a1 = 0.f, a2 = 0.f, a3 = 0.f;
    float a4 = 0.f, a5 = 0.f, a6 = 0.f, a7 = 0.f;
    for (int base = s; base < e; base += 64) {
      int c = min(64, e - base);
      int pk = (lane < c) ? packed[base + lane] : 0;
      float mk = (lane < c) ? mask_s[base + lane] : 0.f;
      int nch = (c + 7) >> 3;
#pragma unroll
      for (int cc = 0; cc < 8; ++cc) {
        if (cc < nch) {
          int j = (cc << 3) + g;
          int pkj = __shfl(pk, j);    // inactive rows: pk=0 -> row 0, mkj=0
          float mkj = __shfl(mk, j);
          uint4 b = *((const uint4*)(srcbf + ((size_t)(pkj & 0xFFFFF) << 6)) + part);
          float r0 = bf2f(b.x & 0xFFFFu), r1 = bf2f(b.x >> 16);
          float r2 = bf2f(b.y & 0xFFFFu), r3 = bf2f(b.y >> 16);
          float r4 = bf2f(b.z & 0xFFFFu), r5 = bf2f(b.z >> 16);
          float r6 = bf2f(b.w & 0xFFFFu), r7 = bf2f(b.w >> 16);
          const float4* wp = (const float4*)(wl + ((pkj >> 20) & 15) * WLS + (part << 3));
          float4 w0 = wp[0], w1 = wp[1];
          a0 = fmaf(mkj * r0, w0.x, a0);
          a1 = fmaf(mkj * r1, w0.y, a1);
          a2 = fmaf(mkj * r2, w0.z, a2);
          a3 = fmaf(mkj * r3, w0.w, a3);
          a4 = fmaf(mkj * r4, w1.x, a4);
          a5 = fmaf(mkj * r5, w1.y, a5);
          a6 = fmaf(mkj * r6, w1.z, a6);
          a7 = fmaf(mkj * r7, w1.w, a7);
        }
      }
    }
    float aggv = colRT(a0, a1, a2, a3, a4, a5, a6, a7, g, part);
    float n = (float)(e - s);
    float agg = aggv / fmaxf(n, 1.0f);
    float nrm = sqrtf(waveReduceSum(agg * agg));
    float val = agg / fmaxf(nrm, 1e-12f);
    size_t o = (size_t)ent * 64 + lane;
    out_ent[o] = out_ent[o] + val;
  } else {
    __shared__ float dwl[256];
    if (threadIdx.x < 256) dwl[threadIdx.x] = dw[threadIdx.x];
    __syncthreads();
    int usr = (blockIdx.x - KG_BLOCKS) * 4 + wid;
    ui_body(usr, lane, srcbf, sc4, out_usr, out_usr, nullptr,
            uptr, cv, dwl, nullptr, nullptr);
  }
}

extern "C" void kernel_launch(void* const* d_in, const int* in_sizes, int n_in,
                              void* d_out, int out_size, void* d_ws, size_t ws_size,
                              hipStream_t stream) {
  const float* user_emb = (const float*)d_in[0];
  const float* entity_emb = (const float*)d_in[1];
  const float* latent = (const float*)d_in[2];
  const float* weight = (const float*)d_in[3];
  const float* disen = (const float*)d_in[4];
  const float* kgW = (const float*)d_in[5];
  const float* ui_vals = (const float*)d_in[6];
  const int* edge_index = (const int*)d_in[7];
  const int* edge_type = (const int*)d_in[8];
  const int* ui_rows = (const int*)d_in[9];
  const int* ui_cols = (const int*)d_in[10];
  const int* head = edge_index;
  const int* tail = edge_index + N_EDGE;

  char* ws = (char*)d_ws;
  size_t o = 0;
  auto alloc = [&](size_t bytes) -> char* {
    char* p = ws + o;
    o += (bytes + 255) & ~(size_t)255;
    return p;
  };
  int* head_ptr = (int*)alloc((N_ENT + 1) * 4);
  int* ui_ptr = (int*)alloc((N_USR + 1) * 4);
  int* packed = (int*)alloc((size_t)N_EDGE * 4);
  int2* cv = (int2*)alloc((size_t)N_EDGE * 8);
  float* mask_s = (float*)alloc((size_t)N_EDGE * 4);
  ushort_t* ent0bf = (ushort_t*)alloc((size_t)N_ENT * 64 * 2);
  ushort_t* ent1bf = (ushort_t*)alloc((size_t)N_ENT * 64 * 2);
  float* usr1 = (float*)alloc((size_t)N_USR * 64 * 4);
  unsigned int* stage_kg = (unsigned int*)alloc((size_t)N_EDGE * 4);
  int2* stage_ui = (int2*)alloc((size_t)N_EDGE * 8);
  int* ccnt = (int*)alloc((NCK + NCU) * 4);        // zeroed coarse counts
  int* ccnt_kg = ccnt;
  int* ccnt_ui = ccnt + NCK;
  int* cbase_kg = (int*)alloc((NCK + 1) * 4);
  int* cbase_ui = (int*)alloc((NCU + 1) * 4);
  int* cur_kg = (int*)alloc(NCK * 4);
  int* cur_ui = (int*)alloc(NCU * 4);
  float* rel2t = (float*)alloc((size_t)N_ENT * 9 * 4);
  float4* sc4a = (float4*)alloc((size_t)N_USR * 16);
  float4* sc4b = (float4*)alloc((size_t)N_USR * 16);
  float* V = (float*)alloc(9 * 64 * 4);
  float* wsq = (float*)alloc(16 * 4);
  float* dw = (float*)alloc(4 * 64 * 4);
  if (o > ws_size) return;

  float* out_ent = (float*)d_out;
  float* out_usr = out_ent + (size_t)N_ENT * 64;
  float* out_cor = out_ent + (size_t)N_ENT * 64 + (size_t)N_USR * 64;

  hipMemsetAsync(ccnt, 0, (NCK + NCU) * 4, stream);

  // K1: bf16 convert + coarse-hist count + prep + sc(user)
  k_pre<<<TB_BLOCKS + CNT_BLOCKS + 1 + SC_BLOCKS, 256, 0, stream>>>(
      entity_emb, ent0bf, head, ui_rows, ccnt_kg, ccnt_ui,
      weight, kgW, disen, V, wsq, dw, out_cor, user_emb, latent, sc4a);

  // K2: scan coarse counts -> bases + cursors + sentinels
  k_scan_coarse<<<1, 1024, 0, stream>>>(ccnt_kg, ccnt_ui, cbase_kg, cbase_ui,
                                        cur_kg, cur_ui, head_ptr, ui_ptr);

  // K3: coarse binning (block-level reservations)
  k_bin<<<BIN_BLOCKS, 1024, 0, stream>>>(
      head, tail, edge_type, ui_rows, ui_cols, ui_vals,
      cur_kg, cur_ui, stage_kg, stage_ui);

  // K4: self-contained fine placement (LDS hist+scan -> head_ptr/ui_ptr -> place) + rel2
  k_fine_rel2<<<FINEK_BLOCKS + FINEU_BLOCKS, 256, 0, stream>>>(
      stage_kg, stage_ui, cbase_kg, cbase_ui, packed, cv,
      head_ptr, ui_ptr, ent0bf, V, wsq, rel2t);

  // D1: mask + fused KG hop-1 + UI hop-1 (+ sc4b epilogue)
  k_mask_kg_ui<<<KG_BLOCKS + UI_BLOCKS, 256, 0, stream>>>(
      entity_emb, ent0bf, head_ptr, packed, rel2t, mask_s, weight,
      out_ent, ent1bf, sc4a, out_usr, usr1, ui_ptr, cv, user_emb, dw, latent, sc4b);

  // D2: KG hop-2 + UI hop-2
  k_hop2<<<KG_BLOCKS + UI_BLOCKS, 256, 0, stream>>>(
      ent1bf, out_ent, head_ptr, packed, mask_s, weight,
      usr1, out_usr, ui_ptr, cv, sc4b, dw);
}

// Round 10
// 393.430 us; speedup vs baseline: 1.4777x; 1.0305x over previous
//
#include <hip/hip_runtime.h>
#include <math.h>

#define N_ENT 100000
#define N_USR 50000
#define N_EDGE 1000000
#define TEMPC 0.2f
#define KG_BLOCKS 6250   // N_ENT/16 : 4 waves x 4 entities per wave
#define UI_BLOCKS 3125   // N_USR/16

// fused-kernel block ranges
#define TB_BLOCKS 6250   // ceil(N_ENT*64/4 / 256) : bf16 convert (float4 granules)
#define CNT_BLOCKS 489   // ceil(N_EDGE/8 / 256) : coarse LDS-hist count, 8 edges/thread
#define SC_BLOCKS 196    // ceil(N_USR / 256)

// counting-sort phases
#define BIN_BLOCKS 245   // ceil(N_EDGE / (1024*4))
#define NCK 391          // KG coarse buckets: head >> 8
#define NCU 196          // UI coarse buckets: user >> 8
#define FINEK_BLOCKS NCK
#define FINEU_BLOCKS NCU

#define WLS 68   // padded stride for weight rows in LDS

typedef unsigned short ushort_t;

__device__ __forceinline__ float waveReduceSum(float x) {
#pragma unroll
  for (int d = 32; d > 0; d >>= 1) x += __shfl_xor(x, d);
  return x;
}
__device__ __forceinline__ float waveReduceMax(float x) {
#pragma unroll
  for (int d = 32; d > 0; d >>= 1) x = fmaxf(x, __shfl_xor(x, d));
  return x;
}
__device__ __forceinline__ int waveReduceSumI(int x) {
#pragma unroll
  for (int d = 32; d > 0; d >>= 1) x += __shfl_xor(x, d);
  return x;
}
__device__ __forceinline__ float bf2f(unsigned int u16) {
  union { unsigned int i; float f; } v;
  v.i = u16 << 16;
  return v.f;
}
__device__ __forceinline__ ushort_t f2bf(float f) {
  union { unsigned int i; float f; } v;
  v.f = f;
  unsigned int u = v.i;
  u = (u + 0x7FFFu + ((u >> 16) & 1u)) >> 16;
  return (ushort_t)u;
}
// wave-uniform broadcast via v_readlane -> SGPR
__device__ __forceinline__ int rl(int v, int l) { return __builtin_amdgcn_readlane(v, l); }
__device__ __forceinline__ float rlf(float v, int l) {
  return __int_as_float(__builtin_amdgcn_readlane(__float_as_int(v), l));
}

// column-partial reduce over g (masks 8/16/32) + 8x8 wave transpose
__device__ __forceinline__ float colRT(float a0, float a1, float a2, float a3,
                                       float a4, float a5, float a6, float a7,
                                       int g, int part) {
#define RED3(x) x += __shfl_xor(x, 8); x += __shfl_xor(x, 16); x += __shfl_xor(x, 32);
  RED3(a0) RED3(a1) RED3(a2) RED3(a3) RED3(a4) RED3(a5) RED3(a6) RED3(a7)
#undef RED3
  float t0 = __shfl(a0, g), t1 = __shfl(a1, g), t2 = __shfl(a2, g), t3 = __shfl(a3, g);
  float t4 = __shfl(a4, g), t5 = __shfl(a5, g), t6 = __shfl(a6, g), t7 = __shfl(a7, g);
  float r = t0;
  r = (part == 1) ? t1 : r;
  r = (part == 2) ? t2 : r;
  r = (part == 3) ? t3 : r;
  r = (part == 4) ? t4 : r;
  r = (part == 5) ? t5 : r;
  r = (part == 6) ? t6 : r;
  r = (part == 7) ? t7 : r;
  return r;
}

// ============ K1: bf16 convert | coarse-hist count (8/thr) | prep | sc(user) ============
__global__ void k_pre(const float* __restrict__ ent0, ushort_t* __restrict__ ent0bf,
                      const int* __restrict__ head, const int* __restrict__ uir,
                      int* __restrict__ ccnt_kg, int* __restrict__ ccnt_ui,
                      const float* __restrict__ weight, const float* __restrict__ kgW,
                      const float* __restrict__ disen,
                      float* __restrict__ V, float* __restrict__ wsq,
                      float* __restrict__ dw, float* __restrict__ cor_out,
                      const float* __restrict__ user_emb, const float* __restrict__ latent,
                      float4* __restrict__ sc4a) {
  int bid = blockIdx.x;
  if (bid < TB_BLOCKS) {
    int i = bid * 256 + threadIdx.x;
    if (i < N_ENT * 16) {
      float4 v = ((const float4*)ent0)[i];
      ushort4 o;
      o.x = f2bf(v.x); o.y = f2bf(v.y); o.z = f2bf(v.z); o.w = f2bf(v.w);
      ((ushort4*)ent0bf)[i] = o;
    }
  } else if (bid < TB_BLOCKS + CNT_BLOCKS) {
    // coarse counting: per-block LDS histogram, then fire-and-forget global adds
    __shared__ int histK[NCK], histU[NCU];
    int tid = threadIdx.x;
    for (int i = tid; i < NCK; i += 256) histK[i] = 0;
    for (int i = tid; i < NCU; i += 256) histU[i] = 0;
    __syncthreads();
    int i0 = ((bid - TB_BLOCKS) * 256 + tid) * 8;
    if (i0 < N_EDGE) {
      int4 ha = *(const int4*)(head + i0), hb = *(const int4*)(head + i0 + 4);
      int4 ua = *(const int4*)(uir + i0), ub = *(const int4*)(uir + i0 + 4);
      atomicAdd(&histK[ha.x >> 8], 1);
      atomicAdd(&histK[ha.y >> 8], 1);
      atomicAdd(&histK[ha.z >> 8], 1);
      atomicAdd(&histK[ha.w >> 8], 1);
      atomicAdd(&histK[hb.x >> 8], 1);
      atomicAdd(&histK[hb.y >> 8], 1);
      atomicAdd(&histK[hb.z >> 8], 1);
      atomicAdd(&histK[hb.w >> 8], 1);
      atomicAdd(&histU[ua.x >> 8], 1);
      atomicAdd(&histU[ua.y >> 8], 1);
      atomicAdd(&histU[ua.z >> 8], 1);
      atomicAdd(&histU[ua.w >> 8], 1);
      atomicAdd(&histU[ub.x >> 8], 1);
      atomicAdd(&histU[ub.y >> 8], 1);
      atomicAdd(&histU[ub.z >> 8], 1);
      atomicAdd(&histU[ub.w >> 8], 1);
    }
    __syncthreads();
    for (int i = tid; i < NCK; i += 256)
      if (histK[i] > 0) atomicAdd(&ccnt_kg[i], histK[i]);
    for (int i = tid; i < NCU; i += 256)
      if (histU[i] > 0) atomicAdd(&ccnt_ui[i], histU[i]);
  } else if (bid == TB_BLOCKS + CNT_BLOCKS) {
    // ---- prep: V=(W W^T)w_r via T-factorization, wsq, dw, cor ----
    __shared__ float T[9 * 64];
    __shared__ float sm[4 * 9];
    int tid = threadIdx.x;
    for (int e = tid; e < 9 * 64; e += 256) {
      int r = e >> 6, d = e & 63;
      float s = 0.f;
      for (int k = 0; k < 64; ++k) s += kgW[k * 64 + d] * weight[r * 64 + k];
      T[e] = s;
    }
    if (tid < 4) {
      float m = -INFINITY;
      for (int r = 0; r < 9; ++r) m = fmaxf(m, disen[tid * 9 + r]);
      float den = 0.f;
      float ex[9];
      for (int r = 0; r < 9; ++r) { ex[r] = expf(disen[tid * 9 + r] - m); den += ex[r]; }
      for (int r = 0; r < 9; ++r) sm[tid * 9 + r] = ex[r] / den;
    }
    __syncthreads();
    for (int e = tid; e < 9 * 64; e += 256) {
      int r = e >> 6, i = e & 63;
      float s = 0.f;
      for (int d = 0; d < 64; ++d) s += kgW[i * 64 + d] * T[r * 64 + d];
      V[e] = s;
    }
    if (tid < 9) {
      float s = 0.f;
      for (int c = 0; c < 64; ++c) { float w = weight[tid * 64 + c]; s += w * w; }
      wsq[tid] = s;
    }
    for (int e = tid; e < 4 * 64; e += 256) {
      int f = e >> 6, c = e & 63;
      float s = 0.f;
      for (int r = 0; r < 9; ++r) s += sm[f * 9 + r] * weight[r * 64 + c];
      dw[e] = s;
    }
    if (tid == 0) {
      float rowsum[4];
      for (int f = 0; f < 4; ++f) {
        float s = 0.f;
        for (int j = 0; j < 9; ++j) s += disen[f * 9 + j];
        rowsum[f] = s;
      }
      float cor = 0.f;
      for (int i = 0; i < 9; ++i) {
        float n2 = 0.f, ttl = 0.f;
        for (int f = 0; f < 4; ++f) {
          float v = disen[f * 9 + i];
          n2 += v * v;
          ttl += v * rowsum[f];
        }
        float nrm = sqrtf(n2);
        float pos = 0.f;
        for (int f = 0; f < 4; ++f) {
          float v = disen[f * 9 + i] / nrm;
          pos += v * v;
        }
        cor += (ttl - pos) / TEMPC;
      }
      *cor_out = cor;
    }
  } else {
    // ---- sc on user_emb -> sc4a ----
    __shared__ __align__(16) float lat[256];
    if (threadIdx.x < 256) lat[threadIdx.x] = latent[threadIdx.x];
    __syncthreads();
    int u = (bid - TB_BLOCKS - CNT_BLOCKS - 1) * 256 + threadIdx.x;
    if (u >= N_USR) return;
    float a0 = 0.f, a1 = 0.f, a2 = 0.f, a3 = 0.f;
    const float4* row = (const float4*)(user_emb + (size_t)u * 64);
#pragma unroll
    for (int q = 0; q < 16; ++q) {
      float4 v = row[q];
      float4 l0 = *(const float4*)(lat + 0 * 64 + q * 4);
      float4 l1 = *(const float4*)(lat + 1 * 64 + q * 4);
      float4 l2 = *(const float4*)(lat + 2 * 64 + q * 4);
      float4 l3 = *(const float4*)(lat + 3 * 64 + q * 4);
      a0 = fmaf(v.x, l0.x, a0); a0 = fmaf(v.y, l0.y, a0); a0 = fmaf(v.z, l0.z, a0); a0 = fmaf(v.w, l0.w, a0);
      a1 = fmaf(v.x, l1.x, a1); a1 = fmaf(v.y, l1.y, a1); a1 = fmaf(v.z, l1.z, a1); a1 = fmaf(v.w, l1.w, a1);
      a2 = fmaf(v.x, l2.x, a2); a2 = fmaf(v.y, l2.y, a2); a2 = fmaf(v.z, l2.z, a2); a2 = fmaf(v.w, l2.w, a2);
      a3 = fmaf(v.x, l3.x, a3); a3 = fmaf(v.y, l3.y, a3); a3 = fmaf(v.z, l3.z, a3); a3 = fmaf(v.w, l3.w, a3);
    }
    sc4a[u] = make_float4(a0, a1, a2, a3);
  }
}

// ============ K2: scan coarse counts -> coarse bases + bin cursors + sentinels ============
__global__ void __launch_bounds__(1024) k_scan_coarse(
    const int* __restrict__ ccnt_kg, const int* __restrict__ ccnt_ui,
    int* __restrict__ cbase_kg, int* __restrict__ cbase_ui,
    int* __restrict__ cur_kg, int* __restrict__ cur_ui,
    int* __restrict__ head_ptr, int* __restrict__ ui_ptr) {
  __shared__ int wsum[16];
  int tid = threadIdx.x, lane = tid & 63, wid = tid >> 6;
  // ---- KG (NCK <= 1024) ----
  int v = (tid < NCK) ? ccnt_kg[tid] : 0;
  int x = v;
#pragma unroll
  for (int d = 1; d < 64; d <<= 1) {
    int y = __shfl_up(x, d);
    if (lane >= d) x += y;
  }
  if (lane == 63) wsum[wid] = x;
  __syncthreads();
  if (tid == 0) {
    int a = 0;
    for (int w = 0; w < 16; ++w) { int t = wsum[w]; wsum[w] = a; a += t; }
  }
  __syncthreads();
  int base = x - v + wsum[wid];
  if (tid < NCK) { cbase_kg[tid] = base; cur_kg[tid] = base; }
  if (tid == 0) { cbase_kg[NCK] = N_EDGE; head_ptr[N_ENT] = N_EDGE; }
  __syncthreads();
  // ---- UI (NCU <= 1024) ----
  int vu = (tid < NCU) ? ccnt_ui[tid] : 0;
  int xu = vu;
#pragma unroll
  for (int d = 1; d < 64; d <<= 1) {
    int y = __shfl_up(xu, d);
    if (lane >= d) xu += y;
  }
  if (lane == 63) wsum[wid] = xu;
  __syncthreads();
  if (tid == 0) {
    int a = 0;
    for (int w = 0; w < 16; ++w) { int t = wsum[w]; wsum[w] = a; a += t; }
  }
  __syncthreads();
  int bu = xu - vu + wsum[wid];
  if (tid < NCU) { cbase_ui[tid] = bu; cur_ui[tid] = bu; }
  if (tid == 0) { cbase_ui[NCU] = N_EDGE; ui_ptr[N_USR] = N_EDGE; }
}

// ============ K3: coarse binning (block-level reservations, NO per-edge return-atomics) ============
__global__ void __launch_bounds__(1024) k_bin(
    const int* __restrict__ head, const int* __restrict__ tail,
    const int* __restrict__ etype,
    const int* __restrict__ uir, const int* __restrict__ uic,
    const float* __restrict__ uival,
    int* __restrict__ coarse_kg_cur, int* __restrict__ coarse_ui_cur,
    unsigned int* __restrict__ stage_kg, int2* __restrict__ stage_ui) {
  __shared__ int histK[NCK], histU[NCU];
  int tid = threadIdx.x;
  for (int i = tid; i < NCK; i += 1024) histK[i] = 0;
  for (int i = tid; i < NCU; i += 1024) histU[i] = 0;
  __syncthreads();
  int i0 = (blockIdx.x * 1024 + tid) * 4;
  bool valid = (i0 < N_EDGE);
  int4 h4, t4v, e4, r4, c4;
  float4 v4;
  int k0 = 0, k1 = 0, k2 = 0, k3 = 0, u0 = 0, u1 = 0, u2 = 0, u3 = 0;
  if (valid) {
    h4 = *(const int4*)(head + i0);
    t4v = *(const int4*)(tail + i0);
    e4 = *(const int4*)(etype + i0);
    r4 = *(const int4*)(uir + i0);
    c4 = *(const int4*)(uic + i0);
    v4 = *(const float4*)(uival + i0);
    k0 = atomicAdd(&histK[h4.x >> 8], 1);
    k1 = atomicAdd(&histK[h4.y >> 8], 1);
    k2 = atomicAdd(&histK[h4.z >> 8], 1);
    k3 = atomicAdd(&histK[h4.w >> 8], 1);
    u0 = atomicAdd(&histU[r4.x >> 8], 1);
    u1 = atomicAdd(&histU[r4.y >> 8], 1);
    u2 = atomicAdd(&histU[r4.z >> 8], 1);
    u3 = atomicAdd(&histU[r4.w >> 8], 1);
  }
  __syncthreads();
  // block-level reservation: ONE global return-atomic per (block, nonempty bucket)
  if (tid < NCK) {
    int c = histK[tid];
    histK[tid] = (c > 0) ? atomicAdd(&coarse_kg_cur[tid], c) : 0;
  } else if (tid >= 512 && tid < 512 + NCU) {
    int bu = tid - 512;
    int c = histU[bu];
    histU[bu] = (c > 0) ? atomicAdd(&coarse_ui_cur[bu], c) : 0;
  }
  __syncthreads();
  if (valid) {
    // staged KG word: tail(0:19) | rel(20:23) | head&255(24:31)
    stage_kg[histK[h4.x >> 8] + k0] =
        (unsigned int)(t4v.x | ((e4.x - 1) << 20) | ((h4.x & 255) << 24));
    stage_kg[histK[h4.y >> 8] + k1] =
        (unsigned int)(t4v.y | ((e4.y - 1) << 20) | ((h4.y & 255) << 24));
    stage_kg[histK[h4.z >> 8] + k2] =
        (unsigned int)(t4v.z | ((e4.z - 1) << 20) | ((h4.z & 255) << 24));
    stage_kg[histK[h4.w >> 8] + k3] =
        (unsigned int)(t4v.w | ((e4.w - 1) << 20) | ((h4.w & 255) << 24));
    // staged UI: {col(0:23) | user&255(24:31), val}
    stage_ui[histU[r4.x >> 8] + u0] = make_int2(c4.x | ((r4.x & 255) << 24), __float_as_int(v4.x));
    stage_ui[histU[r4.y >> 8] + u1] = make_int2(c4.y | ((r4.y & 255) << 24), __float_as_int(v4.y));
    stage_ui[histU[r4.z >> 8] + u2] = make_int2(c4.z | ((r4.z & 255) << 24), __float_as_int(v4.z));
    stage_ui[histU[r4.w >> 8] + u3] = make_int2(c4.w | ((r4.w & 255) << 24), __float_as_int(v4.w));
  }
}

// ============ K4: fine placement, fully self-contained per coarse bucket ============
__global__ void k_fine_rel2(const unsigned int* __restrict__ stage_kg,
                            const int2* __restrict__ stage_ui,
                            const int* __restrict__ cbase_kg, const int* __restrict__ cbase_ui,
                            int* __restrict__ packed, int2* __restrict__ cv,
                            int* __restrict__ head_ptr, int* __restrict__ ui_ptr,
                            const ushort_t* __restrict__ ent0bf, const float* __restrict__ V,
                            const float* __restrict__ wsq, float* __restrict__ rel2t) {
  int tid = threadIdx.x;
  int lane = tid & 63, wid = tid >> 6;
  if (blockIdx.x < FINEK_BLOCKS) {
    int b = blockIdx.x;
    __shared__ int lbase[2304];  // 256 heads x 9 rels
    __shared__ int lcnt[2304];
    __shared__ __align__(16) float Vl[576];
    __shared__ float wsql[9];
    __shared__ int woff[4];
    for (int i = tid; i < 2304; i += 256) lcnt[i] = 0;
    for (int i = tid; i < 576; i += 256) Vl[i] = V[i];
    if (tid < 9) wsql[tid] = wsq[tid];
    int cs = cbase_kg[b], ce = cbase_kg[b + 1];
    int gb = b << 8;
    int ne = min(256, N_ENT - gb);
    __syncthreads();
    // pass 1: histogram of this bucket's staged edges
    for (int i = cs + tid; i < ce; i += 256) {
      unsigned int w = stage_kg[i];
      int key = (int)((w >> 24) & 255u) * 9 + (int)((w >> 20) & 15u);
      atomicAdd(&lcnt[key], 1);
    }
    __syncthreads();
    // pass 2: per-entity rel prefix (regs) + block exclusive scan of entity degrees
    int pre9[9];
    int deg = 0;
    if (tid < ne) {
#pragma unroll
      for (int r = 0; r < 9; ++r) { pre9[r] = deg; deg += lcnt[tid * 9 + r]; }
    }
    int x = deg;
#pragma unroll
    for (int d = 1; d < 64; d <<= 1) {
      int y = __shfl_up(x, d);
      if (lane >= d) x += y;
    }
    if (lane == 63) woff[wid] = x;
    __syncthreads();
    if (tid == 0) {
      int a = 0;
      for (int w2 = 0; w2 < 4; ++w2) { int t = woff[w2]; woff[w2] = a; a += t; }
    }
    __syncthreads();
    int ebase = cs + (x - deg) + woff[wid];
    if (tid < ne) {
      head_ptr[gb + tid] = ebase;
#pragma unroll
      for (int r = 0; r < 9; ++r) lbase[tid * 9 + r] = ebase + pre9[r];
    }
    __syncthreads();
    // reset counters for rank pass
    for (int i = tid; i < 2304; i += 256) lcnt[i] = 0;
    __syncthreads();
    // pass 3: place (stores land in this block's contiguous CSR region)
    for (int i = cs + tid; i < ce; i += 256) {
      unsigned int w = stage_kg[i];
      int key = (int)((w >> 24) & 255u) * 9 + (int)((w >> 20) & 15u);
      int r = atomicAdd(&lcnt[key], 1);
      packed[lbase[key] + r] = (int)(w & 0xFFFFFFu);  // tail | rel<<20
    }
    __syncthreads();
    // pass 4: rel2 for this block's entities (lcnt holds per-(ent,rel) counts again)
    if (tid < ne) {
      int ent = gb + tid;
      float a[9] = {0, 0, 0, 0, 0, 0, 0, 0, 0};
      const uint4* row = (const uint4*)(ent0bf + ((size_t)ent << 6));
#pragma unroll
      for (int q = 0; q < 8; ++q) {
        uint4 bq = row[q];
        float ch0 = bf2f(bq.x & 0xFFFFu), ch1 = bf2f(bq.x >> 16);
        float ch2 = bf2f(bq.y & 0xFFFFu), ch3 = bf2f(bq.y >> 16);
        float ch4 = bf2f(bq.z & 0xFFFFu), ch5 = bf2f(bq.z >> 16);
        float ch6 = bf2f(bq.w & 0xFFFFu), ch7 = bf2f(bq.w >> 16);
#pragma unroll
        for (int r = 0; r < 9; ++r) {
          const float4* vp = (const float4*)(Vl + r * 64 + q * 8);
          float4 v0 = vp[0], v1 = vp[1];
          float t = a[r];
          t = fmaf(ch0, v0.x, t); t = fmaf(ch1, v0.y, t);
          t = fmaf(ch2, v0.z, t); t = fmaf(ch3, v0.w, t);
          t = fmaf(ch4, v1.x, t); t = fmaf(ch5, v1.y, t);
          t = fmaf(ch6, v1.z, t); t = fmaf(ch7, v1.w, t);
          a[r] = t;
        }
      }
      const float inv2s = 0.08838834764831845f;  // 1/(2*sqrt(32))
      int cnt[9];
#pragma unroll
      for (int r = 0; r < 9; ++r) cnt[r] = lcnt[tid * 9 + r];
      float m1 = -INFINITY;
#pragma unroll
      for (int r = 0; r < 9; ++r)
        if (cnt[r] > 0) m1 = fmaxf(m1, a[r] * inv2s);
      if (m1 == -INFINITY) {
#pragma unroll
        for (int r = 0; r < 9; ++r) rel2t[ent * 9 + r] = 0.f;
      } else {
        float den1 = 1e-16f;
#pragma unroll
        for (int r = 0; r < 9; ++r)
          if (cnt[r] > 0) den1 += (float)cnt[r] * expf(a[r] * inv2s - m1);
#pragma unroll
        for (int r = 0; r < 9; ++r) {
          float rs = expf(a[r] * inv2s - m1) / den1;
          rel2t[ent * 9 + r] = rs * rs * wsql[r];
        }
      }
    }
  } else {
    // ---- UI fine placement ----
    int b = blockIdx.x - FINEK_BLOCKS;
    __shared__ int lbu[256];
    __shared__ int lcu[256];
    __shared__ int woff2[4];
    lcu[tid] = 0;
    int cs = cbase_ui[b], ce = cbase_ui[b + 1];
    int gb = b << 8;
    int nu = min(256, N_USR - gb);
    __syncthreads();
    for (int i = cs + tid; i < ce; i += 256) {
      int2 d = stage_ui[i];
      atomicAdd(&lcu[(d.x >> 24) & 255], 1);
    }
    __syncthreads();
    int deg = (tid < nu) ? lcu[tid] : 0;
    int x = deg;
#pragma unroll
    for (int d = 1; d < 64; d <<= 1) {
      int y = __shfl_up(x, d);
      if (lane >= d) x += y;
    }
    if (lane == 63) woff2[wid] = x;
    __syncthreads();
    if (tid == 0) {
      int a = 0;
      for (int w2 = 0; w2 < 4; ++w2) { int t = woff2[w2]; woff2[w2] = a; a += t; }
    }
    __syncthreads();
    int ubase = cs + (x - deg) + woff2[wid];
    __syncthreads();
    if (tid < nu) {
      ui_ptr[gb + tid] = ubase;
      lbu[tid] = ubase;
    }
    lcu[tid] = 0;
    __syncthreads();
    for (int i = cs + tid; i < ce; i += 256) {
      int2 d = stage_ui[i];
      int key = (d.x >> 24) & 255;
      int r = atomicAdd(&lcu[key], 1);
      cv[lbu[key] + r] = make_int2(d.x & 0xFFFFFF, d.y);
    }
  }
}

// KG aggregation inner (readlane broadcasts, 4 acc chains) — generic fallback
__device__ __forceinline__ float kg_agg64(int deg, int lane, int pk, float mk,
                                          const ushort_t* __restrict__ srcbf,
                                          const float* __restrict__ wl) {
  float a0 = 0.f, a1 = 0.f, a2 = 0.f, a3 = 0.f;
  int j = 0;
  for (; j + 4 <= deg; j += 4) {
    int p0 = rl(pk, j), p1 = rl(pk, j + 1), p2 = rl(pk, j + 2), p3 = rl(pk, j + 3);
    float k0 = rlf(mk, j), k1 = rlf(mk, j + 1), k2 = rlf(mk, j + 2), k3 = rlf(mk, j + 3);
    float r0 = bf2f(srcbf[((p0 & 0xFFFFF) << 6) + lane]);
    float r1 = bf2f(srcbf[((p1 & 0xFFFFF) << 6) + lane]);
    float r2 = bf2f(srcbf[((p2 & 0xFFFFF) << 6) + lane]);
    float r3 = bf2f(srcbf[((p3 & 0xFFFFF) << 6) + lane]);
    a0 = fmaf(r0 * wl[((p0 >> 20) & 15) * WLS + lane], k0, a0);
    a1 = fmaf(r1 * wl[((p1 >> 20) & 15) * WLS + lane], k1, a1);
    a2 = fmaf(r2 * wl[((p2 >> 20) & 15) * WLS + lane], k2, a2);
    a3 = fmaf(r3 * wl[((p3 >> 20) & 15) * WLS + lane], k3, a3);
  }
  for (; j < deg; ++j) {
    int pj = rl(pk, j);
    float kj = rlf(mk, j);
    a0 = fmaf(bf2f(srcbf[((pj & 0xFFFFF) << 6) + lane]) * wl[((pj >> 20) & 15) * WLS + lane], kj, a0);
  }
  return (a0 + a1) + (a2 + a3);
}

// ---------------- one KG hop-1 entity (hot: group-layout single-pass) ----------------
__device__ __forceinline__ void kg_one(
    int ent, int s, int deg, int pk_pre, float eh, int lane, int wid,
    float (*sh_eh)[64], const float* __restrict__ wl,
    const ushort_t* __restrict__ ent0bf, const int* __restrict__ packed,
    const float* __restrict__ rel2t, float* __restrict__ mask_s,
    float* __restrict__ out_ent, ushort_t* __restrict__ ent1bf) {
  size_t o = (size_t)ent * 64 + lane;
  if (deg == 0) {
    ent1bf[o] = f2bf(0.f);
    out_ent[o] = eh;
    return;
  }
  sh_eh[wid][lane] = eh;
  int e = s + deg;
  if (deg <= 64) {
    int pk = pk_pre;
    int tb = (pk >> 20) & 15;
    float r2sel = rel2t[ent * 9 + ((lane < deg) ? tb : 0)];
    int g = lane >> 3, part = lane & 7;
    const float4* ehq = (const float4*)(sh_eh[wid] + (part << 3));
    float4 ef0 = ehq[0], ef1 = ehq[1];
    int nch = (deg + 7) >> 3;
    float den = 0.f;
    float acc0 = 0.f, acc1 = 0.f, acc2 = 0.f, acc3 = 0.f;
    float acc4 = 0.f, acc5 = 0.f, acc6 = 0.f, acc7 = 0.f;
    float ws8[8];
#pragma unroll
    for (int cc = 0; cc < 8; ++cc) {
      ws8[cc] = 0.f;
      if (cc < nch) {
        int j = (cc << 3) + g;
        int pkj = __shfl(pk, j);  // inactive rows broadcast pk=0 -> row 0 (safe)
        uint4 b = *((const uint4*)(ent0bf + ((size_t)(pkj & 0xFFFFF) << 6)) + part);
        float r0 = bf2f(b.x & 0xFFFFu), r1 = bf2f(b.x >> 16);
        float r2 = bf2f(b.y & 0xFFFFu), r3 = bf2f(b.y >> 16);
        float r4 = bf2f(b.z & 0xFFFFu), r5 = bf2f(b.z >> 16);
        float r6 = bf2f(b.w & 0xFFFFu), r7 = bf2f(b.w >> 16);
        float s0 = r0 * ef0.x, s1 = r2 * ef0.z, s2 = r4 * ef1.x, s3 = r6 * ef1.z;
        s0 = fmaf(r1, ef0.y, s0); s1 = fmaf(r3, ef0.w, s1);
        s2 = fmaf(r5, ef1.y, s2); s3 = fmaf(r7, ef1.w, s3);
        float sv = (s0 + s1) + (s2 + s3);
        sv += __shfl_xor(sv, 1);
        sv += __shfl_xor(sv, 2);
        sv += __shfl_xor(sv, 4);
        float r2j = __shfl(r2sel, j);
        float w = (j < deg) ? expf(sv + r2j) : 0.f;
        ws8[cc] = w;
        den += w;
        const float4* wp = (const float4*)(wl + ((pkj >> 20) & 15) * WLS + (part << 3));
        float4 w0 = wp[0], w1 = wp[1];
        acc0 = fmaf(w * r0, w0.x, acc0);
        acc1 = fmaf(w * r1, w0.y, acc1);
        acc2 = fmaf(w * r2, w0.z, acc2);
        acc3 = fmaf(w * r3, w0.w, acc3);
        acc4 = fmaf(w * r4, w1.x, acc4);
        acc5 = fmaf(w * r5, w1.y, acc5);
        acc6 = fmaf(w * r6, w1.z, acc6);
        acc7 = fmaf(w * r7, w1.w, acc7);
      }
    }
    float den2 = den;
    den2 += __shfl_xor(den2, 8);
    den2 += __shfl_xor(den2, 16);
    den2 += __shfl_xor(den2, 32);
    den2 += 1e-16f;
    float invden = 1.0f / den2;
#pragma unroll
    for (int cc = 0; cc < 8; ++cc) {
      if (cc < nch) {
        int j = (cc << 3) + (lane >> 3);
        if ((lane & 7) == 0 && j < deg) mask_s[s + j] = ws8[cc] * invden;
      }
    }
    float aggv = colRT(acc0, acc1, acc2, acc3, acc4, acc5, acc6, acc7, g, part);
    float agg = aggv * invden / (float)deg;
    float nrm = sqrtf(waveReduceSum(agg * agg));
    float val = agg / fmaxf(nrm, 1e-12f);
    ent1bf[o] = f2bf(val);
    out_ent[o] = eh + val;
  } else {
    // ---- generic multi-chunk path (deg>64) ----
    float m2l = -INFINITY;
    for (int base = s; base < e; base += 64) {
      int c = min(64, e - base);
      int pk = (lane < c) ? packed[base + lane] : 0;
      int tb = (pk >> 20) & 15;
      float r2 = rel2t[ent * 9 + ((lane < c) ? tb : 0)];
      int tl = pk & 0xFFFFF;
      const uint4* row = (const uint4*)(ent0bf + (tl << 6));
      const float* ehp = sh_eh[wid];
      float d = 0.f;
#pragma unroll
      for (int q = 0; q < 8; ++q) {
        uint4 a = row[q];
        d += bf2f(a.x & 0xFFFF) * ehp[q * 8 + 0] + bf2f(a.x >> 16) * ehp[q * 8 + 1];
        d += bf2f(a.y & 0xFFFF) * ehp[q * 8 + 2] + bf2f(a.y >> 16) * ehp[q * 8 + 3];
        d += bf2f(a.z & 0xFFFF) * ehp[q * 8 + 4] + bf2f(a.z >> 16) * ehp[q * 8 + 5];
        d += bf2f(a.w & 0xFFFF) * ehp[q * 8 + 6] + bf2f(a.w >> 16) * ehp[q * 8 + 7];
      }
      float trip = d + r2;
      if (lane < c) {
        mask_s[base + lane] = trip;
        m2l = fmaxf(m2l, trip);
      }
    }
    float m2 = waveReduceMax(m2l);
    float denl = 0.f;
    for (int base = s; base < e; base += 64) {
      int c = min(64, e - base);
      denl += (lane < c) ? expf(mask_s[base + lane] - m2) : 0.f;
    }
    float den2 = waveReduceSum(denl) + 1e-16f;
    float acc = 0.f;
    for (int base = s; base < e; base += 64) {
      int c = min(64, e - base);
      int pk = (lane < c) ? packed[base + lane] : 0;
      float mk = 0.f;
      if (lane < c) {
        mk = expf(mask_s[base + lane] - m2) / den2;
        mask_s[base + lane] = mk;
      }
      acc += kg_agg64(c, lane, pk, mk, ent0bf, wl);
    }
    float agg = acc / (float)deg;
    float nrm = sqrtf(waveReduceSum(agg * agg));
    float val = agg / fmaxf(nrm, 1e-12f);
    ent1bf[o] = f2bf(val);
    out_ent[o] = eh + val;
  }
}

// ---------------- one UI user (group-layout single-pass, peeled first chunk) ----------------
__device__ __forceinline__ void ui_one(
    int usr, int lane, int s, int e, int2 cvl0,
    const ushort_t* __restrict__ srcbf, const float4* __restrict__ sc4,
    const float* __restrict__ addb, float* __restrict__ outp, float* __restrict__ nxt,
    const int2* __restrict__ cv, const float* __restrict__ dwl,
    const float* __restrict__ latl, float4* __restrict__ sc4out) {
  float4 s4 = sc4[usr];
  float m = fmaxf(fmaxf(s4.x, s4.y), fmaxf(s4.z, s4.w));
  float e0 = expf(s4.x - m), e1 = expf(s4.y - m), e2 = expf(s4.z - m), e3 = expf(s4.w - m);
  float den = e0 + e1 + e2 + e3;
  float mix = (e0 * dwl[lane] + e1 * dwl[64 + lane] + e2 * dwl[128 + lane] + e3 * dwl[192 + lane]) / den;
  int g = lane >> 3, part = lane & 7;
  float a0 = 0.f, a1 = 0.f, a2 = 0.f, a3 = 0.f;
  float a4 = 0.f, a5 = 0.f, a6 = 0.f, a7 = 0.f;
  // peeled first chunk (prefetched cv)
  {
    int c = min(64, e - s);
    int cl = cvl0.x;
    float vl = __int_as_float(cvl0.y);
    int nch = (c + 7) >> 3;
#pragma unroll
    for (int cc = 0; cc < 8; ++cc) {
      if (cc < nch) {
        int j = (cc << 3) + g;
        int cj = __shfl(cl, j);
        float vj = __shfl(vl, j);
        uint4 b = *((const uint4*)(srcbf + ((size_t)cj << 6)) + part);
        a0 = fmaf(bf2f(b.x & 0xFFFFu), vj, a0);
        a1 = fmaf(bf2f(b.x >> 16), vj, a1);
        a2 = fmaf(bf2f(b.y & 0xFFFFu), vj, a2);
        a3 = fmaf(bf2f(b.y >> 16), vj, a3);
        a4 = fmaf(bf2f(b.z & 0xFFFFu), vj, a4);
        a5 = fmaf(bf2f(b.z >> 16), vj, a5);
        a6 = fmaf(bf2f(b.w & 0xFFFFu), vj, a6);
        a7 = fmaf(bf2f(b.w >> 16), vj, a7);
      }
    }
  }
  for (int base = s + 64; base < e; base += 64) {
    int c = min(64, e - base);
    int2 cvl = (lane < c) ? cv[base + lane] : make_int2(0, 0);
    int cl = cvl.x;
    float vl = __int_as_float(cvl.y);
    int nch = (c + 7) >> 3;
#pragma unroll
    for (int cc = 0; cc < 8; ++cc) {
      if (cc < nch) {
        int j = (cc << 3) + g;
        int cj = __shfl(cl, j);
        float vj = __shfl(vl, j);
        uint4 b = *((const uint4*)(srcbf + ((size_t)cj << 6)) + part);
        a0 = fmaf(bf2f(b.x & 0xFFFFu), vj, a0);
        a1 = fmaf(bf2f(b.x >> 16), vj, a1);
        a2 = fmaf(bf2f(b.y & 0xFFFFu), vj, a2);
        a3 = fmaf(bf2f(b.y >> 16), vj, a3);
        a4 = fmaf(bf2f(b.z & 0xFFFFu), vj, a4);
        a5 = fmaf(bf2f(b.z >> 16), vj, a5);
        a6 = fmaf(bf2f(b.w & 0xFFFFu), vj, a6);
        a7 = fmaf(bf2f(b.w >> 16), vj, a7);
      }
    }
  }
  float acc = colRT(a0, a1, a2, a3, a4, a5, a6, a7, g, part);
  float ua = acc * mix + acc;
  float nrm = sqrtf(waveReduceSum(ua * ua));
  float val = ua / fmaxf(nrm, 1e-12f);
  size_t o = (size_t)usr * 64 + lane;
  if (nxt) nxt[o] = val;
  outp[o] = addb[o] + val;
  if (sc4out) {
    float s0 = waveReduceSum(val * latl[lane]);
    float s1 = waveReduceSum(val * latl[64 + lane]);
    float s2 = waveReduceSum(val * latl[128 + lane]);
    float s3 = waveReduceSum(val * latl[192 + lane]);
    if (lane == 0) sc4out[usr] = make_float4(s0, s1, s2, s3);
  }
}

// ---------------- one KG hop-2 entity (peeled first chunk) ----------------
__device__ __forceinline__ void kg2_one(
    int ent, int lane, int s, int e, int pk0, float mk0, float prev,
    const ushort_t* __restrict__ srcbf, const int* __restrict__ packed,
    const float* __restrict__ mask_s, const float* __restrict__ wl,
    float* __restrict__ out_ent) {
  int g = lane >> 3, part = lane & 7;
  float a0 = 0.f, a1 = 0.f, a2 = 0.f, a3 = 0.f;
  float a4 = 0.f, a5 = 0.f, a6 = 0.f, a7 = 0.f;
  {
    int c = min(64, e - s);
    int nch = (c + 7) >> 3;
#pragma unroll
    for (int cc = 0; cc < 8; ++cc) {
      if (cc < nch) {
        int j = (cc << 3) + g;
        int pkj = __shfl(pk0, j);
        float mkj = __shfl(mk0, j);
        uint4 b = *((const uint4*)(srcbf + ((size_t)(pkj & 0xFFFFF) << 6)) + part);
        float r0 = bf2f(b.x & 0xFFFFu), r1 = bf2f(b.x >> 16);
        float r2 = bf2f(b.y & 0xFFFFu), r3 = bf2f(b.y >> 16);
        float r4 = bf2f(b.z & 0xFFFFu), r5 = bf2f(b.z >> 16);
        float r6 = bf2f(b.w & 0xFFFFu), r7 = bf2f(b.w >> 16);
        const float4* wp = (const float4*)(wl + ((pkj >> 20) & 15) * WLS + (part << 3));
        float4 w0 = wp[0], w1 = wp[1];
        a0 = fmaf(mkj * r0, w0.x, a0);
        a1 = fmaf(mkj * r1, w0.y, a1);
        a2 = fmaf(mkj * r2, w0.z, a2);
        a3 = fmaf(mkj * r3, w0.w, a3);
        a4 = fmaf(mkj * r4, w1.x, a4);
        a5 = fmaf(mkj * r5, w1.y, a5);
        a6 = fmaf(mkj * r6, w1.z, a6);
        a7 = fmaf(mkj * r7, w1.w, a7);
      }
    }
  }
  for (int base = s + 64; base < e; base += 64) {
    int c = min(64, e - base);
    int pk = (lane < c) ? packed[base + lane] : 0;
    float mk = (lane < c) ? mask_s[base + lane] : 0.f;
    int nch = (c + 7) >> 3;
#pragma unroll
    for (int cc = 0; cc < 8; ++cc) {
      if (cc < nch) {
        int j = (cc << 3) + g;
        int pkj = __shfl(pk, j);
        float mkj = __shfl(mk, j);
        uint4 b = *((const uint4*)(srcbf + ((size_t)(pkj & 0xFFFFF) << 6)) + part);
        float r0 = bf2f(b.x & 0xFFFFu), r1 = bf2f(b.x >> 16);
        float r2 = bf2f(b.y & 0xFFFFu), r3 = bf2f(b.y >> 16);
        float r4 = bf2f(b.z & 0xFFFFu), r5 = bf2f(b.z >> 16);
        float r6 = bf2f(b.w & 0xFFFFu), r7 = bf2f(b.w >> 16);
        const float4* wp = (const float4*)(wl + ((pkj >> 20) & 15) * WLS + (part << 3));
        float4 w0 = wp[0], w1 = wp[1];
        a0 = fmaf(mkj * r0, w0.x, a0);
        a1 = fmaf(mkj * r1, w0.y, a1);
        a2 = fmaf(mkj * r2, w0.z, a2);
        a3 = fmaf(mkj * r3, w0.w, a3);
        a4 = fmaf(mkj * r4, w1.x, a4);
        a5 = fmaf(mkj * r5, w1.y, a5);
        a6 = fmaf(mkj * r6, w1.z, a6);
        a7 = fmaf(mkj * r7, w1.w, a7);
      }
    }
  }
  float aggv = colRT(a0, a1, a2, a3, a4, a5, a6, a7, g, part);
  float n = (float)(e - s);
  float agg = aggv / fmaxf(n, 1.0f);
  float nrm = sqrtf(waveReduceSum(agg * agg));
  float val = agg / fmaxf(nrm, 1e-12f);
  out_ent[(size_t)ent * 64 + lane] = prev + val;
}

// ---------------- D1: mask + fused KG hop-1  |  UI hop-1 (+sc4b) ----------------
// 4 entities/users per wave, one-ahead prefetch of packed/eh/cv; wl loaded once.
__global__ void k_mask_kg_ui(const float* __restrict__ ent0,
                             const ushort_t* __restrict__ ent0bf,
                             const int* __restrict__ hptr, const int* __restrict__ packed,
                             const float* __restrict__ rel2t,
                             float* __restrict__ mask_s, const float* __restrict__ weight,
                             float* __restrict__ out_ent, ushort_t* __restrict__ ent1bf,
                             const float4* __restrict__ sc4,
                             float* __restrict__ out_usr,
                             float* __restrict__ usr1, const int* __restrict__ uptr,
                             const int2* __restrict__ cv,
                             const float* __restrict__ user_emb, const float* __restrict__ dw,
                             const float* __restrict__ latent, float4* __restrict__ sc4b) {
  int lane = threadIdx.x & 63, wid = threadIdx.x >> 6;
  if (blockIdx.x < KG_BLOCKS) {
    __shared__ __align__(16) float sh_eh[4][64];
    __shared__ __align__(16) float wl[9 * WLS];
    for (int i = threadIdx.x; i < 576; i += 256) wl[(i >> 6) * WLS + (i & 63)] = weight[i];
    __syncthreads();
    int e0 = (blockIdx.x * 4 + wid) * 4;  // 4 entities per wave, e0+4 <= N_ENT
    int hp = (lane < 5) ? hptr[e0 + lane] : 0;
    int s0 = rl(hp, 0), s1 = rl(hp, 1), s2 = rl(hp, 2), s3 = rl(hp, 3), s4 = rl(hp, 4);
    int dA = s1 - s0, dB = s2 - s1, dC = s3 - s2, dD = s4 - s3;
    // prefetch entity A
    float ehA = ent0[(size_t)e0 * 64 + lane];
    int pkA = (dA <= 64 && lane < dA) ? packed[s0 + lane] : 0;
    // prefetch B, process A
    float ehB = ent0[(size_t)(e0 + 1) * 64 + lane];
    int pkB = (dB <= 64 && lane < dB) ? packed[s1 + lane] : 0;
    kg_one(e0 + 0, s0, dA, pkA, ehA, lane, wid, sh_eh, wl, ent0bf, packed,
           rel2t, mask_s, out_ent, ent1bf);
    // prefetch C, process B
    float ehC = ent0[(size_t)(e0 + 2) * 64 + lane];
    int pkC = (dC <= 64 && lane < dC) ? packed[s2 + lane] : 0;
    kg_one(e0 + 1, s1, dB, pkB, ehB, lane, wid, sh_eh, wl, ent0bf, packed,
           rel2t, mask_s, out_ent, ent1bf);
    // prefetch D, process C
    float ehD = ent0[(size_t)(e0 + 3) * 64 + lane];
    int pkD = (dD <= 64 && lane < dD) ? packed[s3 + lane] : 0;
    kg_one(e0 + 2, s2, dC, pkC, ehC, lane, wid, sh_eh, wl, ent0bf, packed,
           rel2t, mask_s, out_ent, ent1bf);
    kg_one(e0 + 3, s3, dD, pkD, ehD, lane, wid, sh_eh, wl, ent0bf, packed,
           rel2t, mask_s, out_ent, ent1bf);
  } else {
    __shared__ float dwl[256];
    __shared__ float latl[256];
    if (threadIdx.x < 256) {
      dwl[threadIdx.x] = dw[threadIdx.x];
      latl[threadIdx.x] = latent[threadIdx.x];
    }
    __syncthreads();
    int u0 = ((blockIdx.x - KG_BLOCKS) * 4 + wid) * 4;  // 4 users per wave
    int up = (lane < 5) ? uptr[u0 + lane] : 0;
    int t0 = rl(up, 0), t1 = rl(up, 1), t2 = rl(up, 2), t3 = rl(up, 3), t4 = rl(up, 4);
    int cA = min(64, t1 - t0);
    int2 cvA = (lane < cA) ? cv[t0 + lane] : make_int2(0, 0);
    int cB = min(64, t2 - t1);
    int2 cvB = (lane < cB) ? cv[t1 + lane] : make_int2(0, 0);
    ui_one(u0 + 0, lane, t0, t1, cvA, ent0bf, sc4, user_emb, out_usr, usr1,
           cv, dwl, latl, sc4b);
    int cC = min(64, t3 - t2);
    int2 cvC = (lane < cC) ? cv[t2 + lane] : make_int2(0, 0);
    ui_one(u0 + 1, lane, t1, t2, cvB, ent0bf, sc4, user_emb, out_usr, usr1,
           cv, dwl, latl, sc4b);
    int cD = min(64, t4 - t3);
    int2 cvD = (lane < cD) ? cv[t3 + lane] : make_int2(0, 0);
    ui_one(u0 + 2, lane, t2, t3, cvC, ent0bf, sc4, user_emb, out_usr, usr1,
           cv, dwl, latl, sc4b);
    ui_one(u0 + 3, lane, t3, t4, cvD, ent0bf, sc4, user_emb, out_usr, usr1,
           cv, dwl, latl, sc4b);
  }
}

// ---------------- D2: KG hop-2 + UI hop-2 (4 per wave + prefetch) ----------------
__global__ void k_hop2(const ushort_t* __restrict__ srcbf,
                       float* __restrict__ out_ent,
                       const int* __restrict__ hptr, const int* __restrict__ packed,
                       const float* __restrict__ mask_s, const float* __restrict__ weight,
                       const float* __restrict__ usr1, float* __restrict__ out_usr,
                       const int* __restrict__ uptr, const int2* __restrict__ cv,
                       const float4* __restrict__ sc4,
                       const float* __restrict__ dw) {
  int lane = threadIdx.x & 63, wid = threadIdx.x >> 6;
  if (blockIdx.x < KG_BLOCKS) {
    __shared__ __align__(16) float wl[9 * WLS];
    for (int i = threadIdx.x; i < 576; i += 256) wl[(i >> 6) * WLS + (i & 63)] = weight[i];
    __syncthreads();
    int e0 = (blockIdx.x * 4 + wid) * 4;
    int hp = (lane < 5) ? hptr[e0 + lane] : 0;
    int s0 = rl(hp, 0), s1 = rl(hp, 1), s2 = rl(hp, 2), s3 = rl(hp, 3), s4 = rl(hp, 4);
    // prefetch A
    int cA = min(64, s1 - s0);
    int pkA = (lane < cA) ? packed[s0 + lane] : 0;
    float mkA = (lane < cA) ? mask_s[s0 + lane] : 0.f;
    float pvA = out_ent[(size_t)e0 * 64 + lane];
    // prefetch B, process A
    int cB = min(64, s2 - s1);
    int pkB = (lane < cB) ? packed[s1 + lane] : 0;
    float mkB = (lane < cB) ? mask_s[s1 + lane] : 0.f;
    float pvB = out_ent[(size_t)(e0 + 1) * 64 + lane];
    kg2_one(e0 + 0, lane, s0, s1, pkA, mkA, pvA, srcbf, packed, mask_s, wl, out_ent);
    int cC = min(64, s3 - s2);
    int pkC = (lane < cC) ? packed[s2 + lane] : 0;
    float mkC = (lane < cC) ? mask_s[s2 + lane] : 0.f;
    float pvC = out_ent[(size_t)(e0 + 2) * 64 + lane];
    kg2_one(e0 + 1, lane, s1, s2, pkB, mkB, pvB, srcbf, packed, mask_s, wl, out_ent);
    int cD = min(64, s4 - s3);
    int pkD = (lane < cD) ? packed[s3 + lane] : 0;
    float mkD = (lane < cD) ? mask_s[s3 + lane] : 0.f;
    float pvD = out_ent[(size_t)(e0 + 3) * 64 + lane];
    kg2_one(e0 + 2, lane, s2, s3, pkC, mkC, pvC, srcbf, packed, mask_s, wl, out_ent);
    kg2_one(e0 + 3, lane, s3, s4, pkD, mkD, pvD, srcbf, packed, mask_s, wl, out_ent);
  } else {
    __shared__ float dwl[256];
    if (threadIdx.x < 256) dwl[threadIdx.x] = dw[threadIdx.x];
    __syncthreads();
    int u0 = ((blockIdx.x - KG_BLOCKS) * 4 + wid) * 4;
    int up = (lane < 5) ? uptr[u0 + lane] : 0;
    int t0 = rl(up, 0), t1 = rl(up, 1), t2 = rl(up, 2), t3 = rl(up, 3), t4 = rl(up, 4);
    int cA = min(64, t1 - t0);
    int2 cvA = (lane < cA) ? cv[t0 + lane] : make_int2(0, 0);
    int cB = min(64, t2 - t1);
    int2 cvB = (lane < cB) ? cv[t1 + lane] : make_int2(0, 0);
    ui_one(u0 + 0, lane, t0, t1, cvA, srcbf, sc4, out_usr, out_usr, nullptr,
           cv, dwl, nullptr, nullptr);
    int cC = min(64, t3 - t2);
    int2 cvC = (lane < cC) ? cv[t2 + lane] : make_int2(0, 0);
    ui_one(u0 + 1, lane, t1, t2, cvB, srcbf, sc4, out_usr, out_usr, nullptr,
           cv, dwl, nullptr, nullptr);
    int cD = min(64, t4 - t3);
    int2 cvD = (lane < cD) ? cv[t3 + lane] : make_int2(0, 0);
    ui_one(u0 + 2, lane, t2, t3, cvC, srcbf, sc4, out_usr, out_usr, nullptr,
           cv, dwl, nullptr, nullptr);
    ui_one(u0 + 3, lane, t3, t4, cvD, srcbf, sc4, out_usr, out_usr, nullptr,
           cv, dwl, nullptr, nullptr);
  }
}

extern "C" void kernel_launch(void* const* d_in, const int* in_sizes, int n_in,
                              void* d_out, int out_size, void* d_ws, size_t ws_size,
                              hipStream_t stream) {
  const float* user_emb = (const float*)d_in[0];
  const float* entity_emb = (const float*)d_in[1];
  const float* latent = (const float*)d_in[2];
  const float* weight = (const float*)d_in[3];
  const float* disen = (const float*)d_in[4];
  const float* kgW = (const float*)d_in[5];
  const float* ui_vals = (const float*)d_in[6];
  const int* edge_index = (const int*)d_in[7];
  const int* edge_type = (const int*)d_in[8];
  const int* ui_rows = (const int*)d_in[9];
  const int* ui_cols = (const int*)d_in[10];
  const int* head = edge_index;
  const int* tail = edge_index + N_EDGE;

  char* ws = (char*)d_ws;
  size_t o = 0;
  auto alloc = [&](size_t bytes) -> char* {
    char* p = ws + o;
    o += (bytes + 255) & ~(size_t)255;
    return p;
  };
  int* head_ptr = (int*)alloc((N_ENT + 1) * 4);
  int* ui_ptr = (int*)alloc((N_USR + 1) * 4);
  int* packed = (int*)alloc((size_t)N_EDGE * 4);
  int2* cv = (int2*)alloc((size_t)N_EDGE * 8);
  float* mask_s = (float*)alloc((size_t)N_EDGE * 4);
  ushort_t* ent0bf = (ushort_t*)alloc((size_t)N_ENT * 64 * 2);
  ushort_t* ent1bf = (ushort_t*)alloc((size_t)N_ENT * 64 * 2);
  float* usr1 = (float*)alloc((size_t)N_USR * 64 * 4);
  unsigned int* stage_kg = (unsigned int*)alloc((size_t)N_EDGE * 4);
  int2* stage_ui = (int2*)alloc((size_t)N_EDGE * 8);
  int* ccnt = (int*)alloc((NCK + NCU) * 4);        // zeroed coarse counts
  int* ccnt_kg = ccnt;
  int* ccnt_ui = ccnt + NCK;
  int* cbase_kg = (int*)alloc((NCK + 1) * 4);
  int* cbase_ui = (int*)alloc((NCU + 1) * 4);
  int* cur_kg = (int*)alloc(NCK * 4);
  int* cur_ui = (int*)alloc(NCU * 4);
  float* rel2t = (float*)alloc((size_t)N_ENT * 9 * 4);
  float4* sc4a = (float4*)alloc((size_t)N_USR * 16);
  float4* sc4b = (float4*)alloc((size_t)N_USR * 16);
  float* V = (float*)alloc(9 * 64 * 4);
  float* wsq = (float*)alloc(16 * 4);
  float* dw = (float*)alloc(4 * 64 * 4);
  if (o > ws_size) return;

  float* out_ent = (float*)d_out;
  float* out_usr = out_ent + (size_t)N_ENT * 64;
  float* out_cor = out_ent + (size_t)N_ENT * 64 + (size_t)N_USR * 64;

  hipMemsetAsync(ccnt, 0, (NCK + NCU) * 4, stream);

  // K1: bf16 convert + coarse-hist count + prep + sc(user)
  k_pre<<<TB_BLOCKS + CNT_BLOCKS + 1 + SC_BLOCKS, 256, 0, stream>>>(
      entity_emb, ent0bf, head, ui_rows, ccnt_kg, ccnt_ui,
      weight, kgW, disen, V, wsq, dw, out_cor, user_emb, latent, sc4a);

  // K2: scan coarse counts -> bases + cursors + sentinels
  k_scan_coarse<<<1, 1024, 0, stream>>>(ccnt_kg, ccnt_ui, cbase_kg, cbase_ui,
                                        cur_kg, cur_ui, head_ptr, ui_ptr);

  // K3: coarse binning (block-level reservations)
  k_bin<<<BIN_BLOCKS, 1024, 0, stream>>>(
      head, tail, edge_type, ui_rows, ui_cols, ui_vals,
      cur_kg, cur_ui, stage_kg, stage_ui);

  // K4: self-contained fine placement + rel2
  k_fine_rel2<<<FINEK_BLOCKS + FINEU_BLOCKS, 256, 0, stream>>>(
      stage_kg, stage_ui, cbase_kg, cbase_ui, packed, cv,
      head_ptr, ui_ptr, ent0bf, V, wsq, rel2t);

  // D1: mask + fused KG hop-1 + UI hop-1 (+ sc4b epilogue)
  k_mask_kg_ui<<<KG_BLOCKS + UI_BLOCKS, 256, 0, stream>>>(
      entity_emb, ent0bf, head_ptr, packed, rel2t, mask_s, weight,
      out_ent, ent1bf, sc4a, out_usr, usr1, ui_ptr, cv, user_emb, dw, latent, sc4b);

  // D2: KG hop-2 + UI hop-2
  k_hop2<<<KG_BLOCKS + UI_BLOCKS, 256, 0, stream>>>(
      ent1bf, out_ent, head_ptr, packed, mask_s, weight,
      usr1, out_usr, ui_ptr, cv, sc4b, dw);
}